// Round 7
// baseline (19460.289 us; speedup 1.0000x reference)
//
#include <hip/hip_runtime.h>

// ---------------------------------------------------------------------------
// GMPool: distance-MLP -> grouping_M -> eigh (LAPACK ssyevd-faithful port) ->
// tau=1e-5 softmax Group -> per-group FC features -> packed output.
//
// R1-R6: structural LAPACK fidelity (rotations, INDXP, dlamrg, scratch).
// R7: PRECISION-PATH fidelity. Eigenvector signs depend on the rotation PATH,
// which is set by eps-scale threshold tests. ssyevd is f32: ssteqr leaves and
// the slaed2 deflation scan now run in f32 arithmetic with f32 constants
// (eps32, eps32^2, safmin32), on f32-rounded scaled d/e (sstedc scaling +
// slaed0 tears in f32). Secular solve stays f64 (continuous) with f32-rounded
// lambdas for ordering. Output = new-slartg (LAPACK >=3.10); old kept as A/B.
// ---------------------------------------------------------------------------

#define T_    176
#define B_    16
#define ROI_  116
#define HID_  200
#define NPAIR_ 6670
#define MATN  (T_*T_)          // 30976
#define PAD_ELEMS (B_*T_*NPAIR_)   // 75.1 MB of floats
#define EPS32F 5.9604644775390625e-8f
#define SAFMIN32F 1.17549435e-38f

__device__ __forceinline__ double fsign(double a, double b){ return (b >= 0.0) ? fabs(a) : -fabs(a); }
__device__ __forceinline__ float fsignf_(float a, float b){ return (b >= 0.0f) ? fabsf(a) : -fabsf(a); }

__device__ __forceinline__ float slapy2f(float x, float y){
  float xa = fabsf(x), ya = fabsf(y);
  float w = fmaxf(xa, ya), z = fminf(xa, ya);
  if (z == 0.0f) return w;
  float q = z / w;
  return w * sqrtf(1.0f + q*q);
}

// LAPACK >=3.10 slartg, f32: c >= 0 always, r = sign(d, f)
__device__ __forceinline__ void lartgf_new(float f, float g, float* c, float* s, float* r){
  if (g == 0.0f){ *c = 1.0f; *s = 0.0f; *r = f; }
  else if (f == 0.0f){ *c = 0.0f; *s = (g >= 0.0f) ? 1.0f : -1.0f; *r = fabsf(g); }
  else {
    float d = sqrtf(f*f + g*g);
    *c = fabsf(f)/d;
    *r = fsignf_(d, f);
    *s = g/(*r);
  }
}

// LAPACK <3.10 slartg, f32
__device__ __forceinline__ void lartgf_old(float f, float g, float* c, float* s, float* r){
  if (g == 0.0f){ *c = 1.0f; *s = 0.0f; *r = f; }
  else if (f == 0.0f){ *c = 0.0f; *s = 1.0f; *r = g; }
  else {
    float d = sqrtf(f*f + g*g);
    float cs = f/d, sn = g/d, rr = d;
    if (fabsf(f) > fabsf(g) && cs < 0.0f){ cs = -cs; sn = -sn; rr = -rr; }
    *c = cs; *s = sn; *r = rr;
  }
}

// LAPACK slaev2, f32 port
__device__ void laev2f(float a, float b, float c, float* rt1, float* rt2, float* cs1, float* sn1){
  float sm = a + c, df = a - c, adf = fabsf(df), tb = b + b, ab = fabsf(tb);
  float acmx, acmn;
  if (fabsf(a) > fabsf(c)){ acmx = a; acmn = c; } else { acmx = c; acmn = a; }
  float rt;
  if (adf > ab) rt = adf*sqrtf(1.0f + (ab/adf)*(ab/adf));
  else if (adf < ab) rt = ab*sqrtf(1.0f + (adf/ab)*(adf/ab));
  else rt = ab*sqrtf(2.0f);
  int sgn1;
  if (sm < 0.0f){ *rt1 = 0.5f*(sm - rt); sgn1 = -1; *rt2 = (acmx / *rt1)*acmn - (b / *rt1)*b; }
  else if (sm > 0.0f){ *rt1 = 0.5f*(sm + rt); sgn1 = 1; *rt2 = (acmx / *rt1)*acmn - (b / *rt1)*b; }
  else { *rt1 = 0.5f*rt; *rt2 = -0.5f*rt; sgn1 = 1; }
  float cs; int sgn2;
  if (df >= 0.0f){ cs = df + rt; sgn2 = 1; } else { cs = df - rt; sgn2 = -1; }
  float acs = fabsf(cs);
  if (acs > ab){ float ct = -tb/cs; float sn = 1.0f/sqrtf(1.0f + ct*ct); *sn1 = sn; *cs1 = ct*sn; }
  else {
    if (ab == 0.0f){ *cs1 = 1.0f; *sn1 = 0.0f; }
    else { float tn = -cs/tb; float c1 = 1.0f/sqrtf(1.0f + tn*tn); *cs1 = c1; *sn1 = tn*c1; }
  }
  if (sgn1 == sgn2){ float tn = *cs1; *cs1 = -(*sn1); *sn1 = tn; }
}

// ---------------------------------------------------------------------------
// K1: grouping_M.  block=(t,b), 256 thr.
// ---------------------------------------------------------------------------
__global__ __launch_bounds__(256) void k_gm(const float* __restrict__ X, const float* __restrict__ W1,
                                            const float* __restrict__ b1, const float* __restrict__ W2,
                                            const float* __restrict__ b2, float* __restrict__ gm){
  const int t = blockIdx.x, b = blockIdx.y, tid = threadIdx.x;
  __shared__ float4 w1p[29*200];
  __shared__ __align__(16) float dist[116];
  __shared__ float xt[116];
  __shared__ float b1s[200];
  __shared__ float w2s[200];
  __shared__ float wred[4];
  for (int li = tid; li < 29*200; li += 256){
    int j = li % 200, r4 = li / 200;
    const float* src = W1 + j*ROI_ + r4*4;
    w1p[li] = make_float4(src[0], src[1], src[2], src[3]);
  }
  for (int j = tid; j < 200; j += 256){ b1s[j] = b1[j]; w2s[j] = W2[j]; }
  if (tid < ROI_) xt[tid] = X[(size_t)(b*T_ + t)*ROI_ + tid];
  float b2v = b2[0];
  if (tid == 0) gm[(size_t)(b*T_ + t)*T_ + t] = 1.0f + 1e-7f;
  __syncthreads();
  for (int s = t + 1; s < T_; ++s){
    if (tid < ROI_){
      float xs = X[(size_t)(b*T_ + s)*ROI_ + tid];
      float df = xt[tid] - xs;
      dist[tid] = sqrtf(df*df + 1e-9f);
    }
    __syncthreads();
    float part = 0.f;
    if (tid < HID_){
      float acc = 0.f;
      const float4* dv4 = reinterpret_cast<const float4*>(dist);
      #pragma unroll
      for (int r4 = 0; r4 < 29; ++r4){
        float4 w = w1p[r4*200 + tid];
        float4 d4 = dv4[r4];
        acc += w.x*d4.x; acc += w.y*d4.y; acc += w.z*d4.z; acc += w.w*d4.w;
      }
      acc += b1s[tid];
      float h = fmaxf(acc, 0.f);
      part = w2s[tid]*h;
    }
    for (int off = 32; off > 0; off >>= 1) part += __shfl_down(part, off, 64);
    if ((tid & 63) == 0) wred[tid >> 6] = part;
    __syncthreads();
    if (tid == 0){
      float logit = wred[0] + wred[1] + wred[2] + wred[3] + b2v;
      float c = 1.0f/(1.0f + expf(-logit));
      float v = c + 1e-7f;
      gm[(size_t)(b*T_ + t)*T_ + s] = v;
      gm[(size_t)(b*T_ + s)*T_ + t] = v;
    }
    __syncthreads();
  }
}

__global__ void k_maxabs(const float* __restrict__ X, float* __restrict__ mx){
  int t = blockIdx.x, b = blockIdx.y, tid = threadIdx.x;
  float m = 0.f;
  for (int r = tid; r < ROI_; r += 64) m = fmaxf(m, fabsf(X[(size_t)(b*T_ + t)*ROI_ + r]));
  for (int off = 32; off > 0; off >>= 1) m = fmaxf(m, __shfl_down(m, off, 64));
  if (tid == 0) mx[b*T_ + t] = m;
}

// ---------------------------------------------------------------------------
// K2a: ssytd2 (lower) in f64, then f32-round d/e, sstedc scaling (f32),
// slaed0 tears (f32). Split-test diagnostic (sstedc TINY test, eps32).
// ---------------------------------------------------------------------------
__global__ __launch_bounds__(256) void k_tridiag(const float* __restrict__ gm, double* __restrict__ Ab,
                                                 double* __restrict__ Zb, double* __restrict__ dar,
                                                 double* __restrict__ ear, double* __restrict__ tauar,
                                                 float* __restrict__ orgn){
  const int b = blockIdx.x, tid = threadIdx.x;
  double* A = Ab + (size_t)b*MATN;
  double* Z = Zb + (size_t)b*MATN;
  const float* gmb = gm + (size_t)b*MATN;
  __shared__ double vsh[T_], wsh[T_], red[256];
  for (int idx = tid; idx < MATN; idx += 256){ A[idx] = (double)gmb[idx]; Z[idx] = 0.0; }
  __syncthreads();
  for (int i = 0; i <= T_-2; ++i){
    int m = T_ - 1 - i;
    double alpha = A[(size_t)(i+1)*T_ + i];
    double part = 0.0;
    for (int r = i+2+tid; r < T_; r += 256){ double x = A[(size_t)r*T_ + i]; part += x*x; }
    red[tid] = part; __syncthreads();
    for (int o = 128; o > 0; o >>= 1){ if (tid < o) red[tid] += red[tid+o]; __syncthreads(); }
    double xnorm2 = red[0];
    __syncthreads();
    if (m == 1 || xnorm2 == 0.0){
      if (tid == 0){ tauar[b*T_ + i] = 0.0; ear[b*T_ + i] = alpha; }
      __syncthreads();
      continue;
    }
    double beta = -fsign(sqrt(alpha*alpha + xnorm2), alpha);
    double tau  = (beta - alpha)/beta;
    double sc   = 1.0/(alpha - beta);
    for (int r = i+2+tid; r < T_; r += 256) A[(size_t)r*T_ + i] *= sc;
    __syncthreads();
    for (int r = i+1+tid; r < T_; r += 256) vsh[r] = (r == i+1) ? 1.0 : A[(size_t)r*T_ + i];
    __syncthreads();
    for (int r = i+1+tid; r < T_; r += 256){
      double acc = 0.0;
      const double* Ar = A + (size_t)r*T_;
      for (int c = i+1; c < T_; ++c) acc += Ar[c]*vsh[c];
      wsh[r] = tau*acc;
    }
    __syncthreads();
    part = 0.0;
    for (int r = i+1+tid; r < T_; r += 256) part += wsh[r]*vsh[r];
    red[tid] = part; __syncthreads();
    for (int o = 128; o > 0; o >>= 1){ if (tid < o) red[tid] += red[tid+o]; __syncthreads(); }
    double a2 = -0.5*tau*red[0];
    __syncthreads();
    for (int r = i+1+tid; r < T_; r += 256) wsh[r] += a2*vsh[r];
    __syncthreads();
    for (int idx = tid; idx < m*m; idx += 256){
      int rr = i+1 + idx/m, cc = i+1 + idx%m;
      A[(size_t)rr*T_ + cc] -= vsh[rr]*wsh[cc] + wsh[rr]*vsh[cc];
    }
    if (tid == 0){ ear[b*T_ + i] = beta; tauar[b*T_ + i] = tau; }
    __syncthreads();
  }
  for (int j = tid; j < T_; j += 256) dar[b*T_ + j] = A[(size_t)j*T_ + j];
  __syncthreads();
  if (tid == 0){
    // round d/e to f32 + sstedc split diagnostic (on unscaled f32 values)
    float minratio = 3.4e38f;
    float dprev = (float)dar[b*T_];
    dar[b*T_] = (double)dprev;
    for (int j = 1; j < T_; ++j){
      float dj = (float)dar[b*T_ + j];
      float ej = (float)ear[b*T_ + j - 1];
      dar[b*T_ + j] = (double)dj;
      ear[b*T_ + j - 1] = (double)ej;
      float tiny = EPS32F*sqrtf(fabsf(dprev))*sqrtf(fabsf(dj));
      if (tiny > 0.0f) minratio = fminf(minratio, fabsf(ej)/tiny);
      dprev = dj;
    }
    // sstedc scaling by orgnrm (f32)
    float og = 0.0f;
    for (int j = 0; j < T_; ++j) og = fmaxf(og, fabsf((float)dar[b*T_ + j]));
    for (int j = 0; j < T_-1; ++j) og = fmaxf(og, fabsf((float)ear[b*T_ + j]));
    for (int j = 0; j < T_; ++j) dar[b*T_ + j] = (double)(float)((float)dar[b*T_ + j]/og);
    for (int j = 0; j < T_-1; ++j) ear[b*T_ + j] = (double)(float)((float)ear[b*T_ + j]/og);
    orgn[b] = og;
    // slaed0 tears in f32 on scaled values
    const int sp[7] = {21,43,65,87,109,131,153};
    for (int k = 0; k < 7; ++k){
      float ae = fabsf((float)ear[b*T_ + sp[k]]);
      dar[b*T_ + sp[k]]     = (double)((float)dar[b*T_ + sp[k]] - ae);
      dar[b*T_ + sp[k] + 1] = (double)((float)dar[b*T_ + sp[k] + 1] - ae);
    }
    if (b == 0) printf("[SPLIT] minratio=%.3e orgnrm=%.3e\n", minratio, og);
    if (minratio <= 1.0f) printf("[SPLIT-WARN] b=%d would split!\n", b);
  }
}

// ---------------------------------------------------------------------------
// K2b: ssteqr('I') on 22x22 leaves, FULL f32 arithmetic (LAPACK path-faithful).
// grid(8,16) x 64 thr. mode 0=new 1=old slartg.
// ---------------------------------------------------------------------------
__global__ __launch_bounds__(64) void k_leaf(double* __restrict__ Zb, double* __restrict__ dar,
                                             const double* __restrict__ ear, int mode){
  const int lf = blockIdx.x, b = blockIdx.y, tid = threadIdx.x;
  const int off = lf*22;
  double* Z = Zb + (size_t)b*MATN;
  __shared__ float ld_[22], le_[22];
  __shared__ float zl[22*22];
  __shared__ int perm_[22];
  for (int k = tid; k < 22; k += 64){
    ld_[k] = (float)dar[b*T_ + off + k];
    le_[k] = (k < 21) ? (float)ear[b*T_ + off + k] : 0.0f;
  }
  for (int idx = tid; idx < 484; idx += 64) zl[idx] = (idx/22 == idx%22) ? 1.0f : 0.0f;
  __syncthreads();
  const float eps = EPS32F, eps2 = EPS32F*EPS32F, safmin = SAFMIN32F;
  const int n = 22, nm1 = 21, nmaxit = 22*30;
  int jtot = 0, l1 = 0;
  while (l1 <= n-1){
    if (l1 > 0) le_[l1-1] = 0.0f;
    int msp = n-1;
    for (int mm2 = l1; mm2 < nm1; ++mm2){
      float tst = fabsf(le_[mm2]);
      if (tst == 0.0f){ msp = mm2; break; }
      if (tst <= (sqrtf(fabsf(ld_[mm2]))*sqrtf(fabsf(ld_[mm2+1])))*eps){
        le_[mm2] = 0.0f;
        msp = mm2; break;
      }
    }
    int l = l1, lend = msp;
    l1 = msp + 1;
    if (lend == l) continue;
    if (fabsf(ld_[lend]) < fabsf(ld_[l])){ int tmp = l; l = lend; lend = tmp; }
    if (lend > l){
      for (;;){ // QL
        int m2 = lend;
        if (l != lend){
          for (int k = l; k < lend; ++k){
            float tst = le_[k]*le_[k];
            if (tst <= (eps2*fabsf(ld_[k]))*fabsf(ld_[k+1]) + safmin){ m2 = k; break; }
          }
        }
        if (m2 < lend) le_[m2] = 0.0f;
        float p = ld_[l];
        if (m2 == l){ l++; if (l <= lend) continue; else break; }
        if (m2 == l+1){
          float rt1, rt2, c2, s2;
          laev2f(ld_[l], le_[l], ld_[l+1], &rt1, &rt2, &c2, &s2);
          if (tid < 22){
            float t0 = zl[tid*22 + l], t1 = zl[tid*22 + l+1];
            zl[tid*22 + l]   = c2*t0 + s2*t1;
            zl[tid*22 + l+1] = -s2*t0 + c2*t1;
          }
          ld_[l] = rt1; ld_[l+1] = rt2; le_[l] = 0.0f;
          l += 2;
          if (l <= lend) continue; else break;
        }
        if (jtot == nmaxit) break;
        jtot++;
        float g = (ld_[l+1] - p)/(2.0f*le_[l]);
        float r = slapy2f(g, 1.0f);
        g = ld_[m2] - p + le_[l]/(g + fsignf_(r, g));
        float s2 = 1.0f, c2 = 1.0f;
        p = 0.0f;
        for (int i = m2-1; i >= l; --i){
          float f2 = s2*le_[i];
          float bb = c2*le_[i];
          if (mode == 0) lartgf_new(g, f2, &c2, &s2, &r); else lartgf_old(g, f2, &c2, &s2, &r);
          if (i != m2-1) le_[i+1] = r;
          g = ld_[i+1] - p;
          r = (ld_[i] - g)*s2 + 2.0f*c2*bb;
          p = s2*r;
          ld_[i+1] = g + p;
          g = c2*r - bb;
          if (tid < 22){   // QL stores sn = -s
            float t0 = zl[tid*22 + i], t1 = zl[tid*22 + i+1];
            zl[tid*22 + i]   = c2*t0 - s2*t1;
            zl[tid*22 + i+1] = s2*t0 + c2*t1;
          }
        }
        ld_[l] -= p; le_[l] = g;
        if (l <= lend) continue; else break;
      }
    } else {
      for (;;){ // QR
        int m2 = lend;
        if (l != lend){
          for (int k = l; k > lend; --k){
            float tst = le_[k-1]*le_[k-1];
            if (tst <= (eps2*fabsf(ld_[k]))*fabsf(ld_[k-1]) + safmin){ m2 = k; break; }
          }
        }
        if (m2 > lend) le_[m2-1] = 0.0f;
        float p = ld_[l];
        if (m2 == l){ l--; if (l >= lend) continue; else break; }
        if (m2 == l-1){
          float rt1, rt2, c2, s2;
          laev2f(ld_[l-1], le_[l-1], ld_[l], &rt1, &rt2, &c2, &s2);
          if (tid < 22){
            float t0 = zl[tid*22 + l-1], t1 = zl[tid*22 + l];
            zl[tid*22 + l-1] = c2*t0 + s2*t1;
            zl[tid*22 + l]   = -s2*t0 + c2*t1;
          }
          ld_[l-1] = rt1; ld_[l] = rt2; le_[l-1] = 0.0f;
          l -= 2;
          if (l >= lend) continue; else break;
        }
        if (jtot == nmaxit) break;
        jtot++;
        float g = (ld_[l-1] - p)/(2.0f*le_[l-1]);
        float r = slapy2f(g, 1.0f);
        g = ld_[m2] - p + le_[l-1]/(g + fsignf_(r, g));
        float s2 = 1.0f, c2 = 1.0f;
        p = 0.0f;
        for (int i = m2; i <= l-1; ++i){
          float f2 = s2*le_[i];
          float bb = c2*le_[i];
          if (mode == 0) lartgf_new(g, f2, &c2, &s2, &r); else lartgf_old(g, f2, &c2, &s2, &r);
          if (i != m2) le_[i-1] = r;
          g = ld_[i] - p;
          r = (ld_[i+1] - g)*s2 + 2.0f*c2*bb;
          p = s2*r;
          ld_[i] = g + p;
          g = c2*r - bb;
          if (tid < 22){   // QR stores sn = +s
            float t0 = zl[tid*22 + i], t1 = zl[tid*22 + i+1];
            zl[tid*22 + i]   = c2*t0 + s2*t1;
            zl[tid*22 + i+1] = -s2*t0 + c2*t1;
          }
        }
        ld_[l] -= p; le_[l-1] = g;
        if (l >= lend) continue; else break;
      }
    }
  }
  __syncthreads();
  if (tid == 0){   // selection sort (strict <, LAPACK ssteqr)
    bool used[22]; for (int k = 0; k < 22; ++k) used[k] = false;
    for (int c = 0; c < 22; ++c){
      int best = -1; float bv = 0.0f;
      for (int k = 0; k < 22; ++k) if (!used[k] && (best < 0 || ld_[k] < bv)){ best = k; bv = ld_[k]; }
      used[best] = true; perm_[c] = best;
    }
  }
  __syncthreads();
  if (tid < 22){
    int r = tid;
    for (int c = 0; c < 22; ++c) Z[(size_t)(off + c)*T_ + (off + r)] = (double)zl[r*22 + perm_[c]];
  }
  for (int c = tid; c < 22; c += 64) dar[b*T_ + off + c] = (double)ld_[perm_[c]];
}

// ---------------------------------------------------------------------------
// K2c/d/e: one D&C merge (slaed1/2/3).  grid(nmerge,16) x 256.
// Deflation scan in f32 (LAPACK-faithful); secular/z-hat/GEMM in f64;
// lambdas rounded to f32 for the dlamrg ordering and the d output.
// ---------------------------------------------------------------------------
__global__ __launch_bounds__(256) void k_merge(double* __restrict__ Zb, double* __restrict__ QNDb,
                                               double* __restrict__ DELb, double* __restrict__ GOb,
                                               double* __restrict__ dar, const double* __restrict__ ear,
                                               int n1, int vb){
  const int b = blockIdx.y, mg = blockIdx.x, tid = threadIdx.x;
  const int lo = mg*2*n1, n = 2*n1;
  double* Z   = Zb   + (size_t)b*MATN;
  double* Qnd = QNDb + (size_t)b*MATN;
  double* DEL = DELb + (size_t)b*MATN;
  double* GO  = GOb  + (size_t)b*MATN;
  double* dv  = dar + b*T_;
  __shared__ float frd[T_], frz[T_], fmd[T_], fmz[T_], fkd[T_], fkw[T_], fddf[T_], flam[T_], foval[T_];
  __shared__ double lam[T_], zh[T_], nrm[T_];
  __shared__ int mcol[T_], kcol[T_], dcol[T_], osrc[T_], indxp_[T_];
  __shared__ int sK, sND;
  __shared__ double s_sumw2;
  __shared__ float s_rho;

  float rho0 = (float)ear[b*T_ + lo + n1 - 1];
  const float rs2f = 0.70710678118654752440f;
  for (int k = tid; k < n; k += 256){
    frd[k] = (float)dv[lo + k];
    int row = (k < n1) ? (lo + n1 - 1) : (lo + n1);
    float zv = (float)Z[(size_t)(lo + k)*T_ + row];
    if (k >= n1 && rho0 < 0.0f) zv = -zv;
    frz[k] = zv*rs2f;
  }
  __syncthreads();
  if (tid == 0){
    float rho = fabsf(2.0f*rho0);
    s_rho = rho;
    // slamrg merge of two sorted halves (tie -> first half)
    int i1 = 0, i2 = n1, p = 0;
    while (i1 < n1 || i2 < n){
      bool t1;
      if (i1 >= n1) t1 = false;
      else if (i2 >= n) t1 = true;
      else t1 = (frd[i1] <= frd[i2]);
      int src = t1 ? i1++ : i2++;
      fmd[p] = frd[src]; fmz[p] = frz[src]; mcol[p] = src; p++;
    }
    float dmax = 0.0f, zmax = 0.0f;
    for (int k = 0; k < n; ++k){ dmax = fmaxf(dmax, fabsf(fmd[k])); zmax = fmaxf(zmax, fabsf(fmz[k])); }
    float tol = 8.0f*EPS32F*fmaxf(dmax, zmax);
    int K = 0, ND = 0;
    if (rho*zmax <= tol){               // full deflation
      for (int k = 0; k < n; ++k){ fddf[k] = fmd[k]; dcol[k] = mcol[k]; }
      ND = n; K = 0;
    } else {                            // slaed2 deflation scan (f32, INDXP port)
      int k2 = n;
      int j = 0, pj = -1;
      for (; j < n; ++j){
        if (rho*fabsf(fmz[j]) <= tol){ k2--; indxp_[k2] = j; }
        else { pj = j; break; }
      }
      if (pj >= 0){
        for (;;){
          j++;
          if (j >= n) break;
          int nj = j;
          if (rho*fabsf(fmz[nj]) <= tol){
            k2--; indxp_[k2] = nj;
          } else {
            float s_ = fmz[pj], c_ = fmz[nj];
            float tau_ = slapy2f(c_, s_);
            float t_ = fmd[nj] - fmd[pj];
            c_ = c_/tau_; s_ = -s_/tau_;
            if (fabsf((t_*c_)*s_) <= tol){
              fmz[nj] = tau_; fmz[pj] = 0.0f;
              double cd = (double)c_, sd = (double)s_;
              double* qx = Z + (size_t)(lo + mcol[pj])*T_ + lo;
              double* qy = Z + (size_t)(lo + mcol[nj])*T_ + lo;
              for (int r = 0; r < n; ++r){            // SROT(x=pj, y=nj)
                double x = qx[r], y = qy[r];
                qx[r] = cd*x + sd*y;
                qy[r] = cd*y - sd*x;
              }
              float dt = fmd[pj]*(c_*c_) + fmd[nj]*(s_*s_);
              fmd[nj] = fmd[pj]*(s_*s_) + fmd[nj]*(c_*c_);
              fmd[pj] = dt;
              k2--;
              int i3 = 1;               // loop 90 insertion (descending storage)
              for (;;){
                if (k2 + i3 <= n - 1){
                  if (fmd[pj] < fmd[indxp_[k2 + i3]]){
                    indxp_[k2 + i3 - 1] = indxp_[k2 + i3];
                    indxp_[k2 + i3]     = pj;
                    i3++;
                  } else { indxp_[k2 + i3 - 1] = pj; break; }
                } else { indxp_[k2 + i3 - 1] = pj; break; }
              }
              pj = nj;
            } else {
              fkd[K] = fmd[pj]; fkw[K] = fmz[pj]; kcol[K] = mcol[pj]; K++;
              pj = nj;
            }
          }
        }
        fkd[K] = fmd[pj]; fkw[K] = fmz[pj]; kcol[K] = mcol[pj]; K++;
      }
      ND = n - K;
      for (int m2 = 0; m2 < ND; ++m2){   // consume backward: ascending by value
        int mi = indxp_[n - 1 - m2];
        fddf[m2] = fmd[mi]; dcol[m2] = mcol[mi];
      }
    }
    sK = K; sND = ND;
    double sw = 0.0; for (int k = 0; k < K; ++k) sw += (double)fkw[k]*(double)fkw[k];
    s_sumw2 = sw;
    if (vb == 0 && b == 0) printf("[MRG] n=%d K=%d ND=%d\n", n, K, ND);
  }
  __syncthreads();
  int K = sK, ND = sND;
  double rho_d = (double)s_rho;
  if (K > 0){
    // secular roots: guarded f64 bisection, delta relative to left pole
    for (int j = tid; j < K; j += 256){
      double dj = (double)fkd[j];
      double hi = (j < K-1) ? ((double)fkd[j+1] - dj) : (rho_d*s_sumw2 + 1e-300);
      if (hi < 0.0) hi = 0.0;
      double lo_t = 0.0, hi_t = hi;
      for (int it = 0; it < 70; ++it){
        double mid = 0.5*(lo_t + hi_t);
        if (mid == lo_t || mid == hi_t) break;
        double f = 1.0;
        for (int i2 = 0; i2 < K; ++i2){
          double dd2 = ((double)fkd[i2] - dj) - mid;
          f += rho_d*(double)fkw[i2]*(double)fkw[i2]/dd2;
        }
        if (f < 0.0) lo_t = mid; else hi_t = mid;
      }
      double tauj = 0.5*(lo_t + hi_t);
      if (tauj <= 0.0) tauj = (hi_t > 0.0) ? hi_t*0.5 : 1e-300;
      if (j < K-1){
        double hib = (double)fkd[j+1] - dj;
        if (tauj >= hib) tauj = nextafter(hib, 0.0);
      }
      lam[j] = dj + tauj;
      flam[j] = (float)lam[j];
      double* Dj = DEL + (size_t)(lo + j)*T_;
      for (int i2 = 0; i2 < K; ++i2) Dj[i2] = ((double)fkd[i2] - dj) - tauj;
    }
    __syncthreads();
    // Gu z-hat
    for (int i2 = tid; i2 < K; i2 += 256){
      double p = DEL[(size_t)(lo + i2)*T_ + i2];
      for (int j = 0; j < K; ++j){
        if (j == i2) continue;
        p *= DEL[(size_t)(lo + j)*T_ + i2]/((double)fkd[i2] - (double)fkd[j]);
      }
      zh[i2] = copysign(sqrt(fabs(p)), (double)fkw[i2]);
    }
    __syncthreads();
    for (int idx = tid; idx < K*K; idx += 256){
      int j = idx/K, i2 = idx%K;
      double* pj = DEL + (size_t)(lo + j)*T_ + i2;
      *pj = zh[i2]/(*pj);
    }
    __syncthreads();
    for (int j = tid; j < K; j += 256){
      double ss = 0.0;
      const double* Dj = DEL + (size_t)(lo + j)*T_;
      for (int i2 = 0; i2 < K; ++i2) ss += Dj[i2]*Dj[i2];
      nrm[j] = sqrt(ss);
    }
    __syncthreads();
    for (int idx = tid; idx < K*n; idx += 256){
      int k2 = idx/n, rr = idx%n;
      Qnd[(size_t)(lo + k2)*T_ + rr] = Z[(size_t)(lo + kcol[k2])*T_ + (lo + rr)];
    }
  }
  for (int idx = tid; idx < ND*n; idx += 256){
    int m2 = idx/n, rr = idx%n;
    GO[(size_t)(lo + K + m2)*T_ + rr] = Z[(size_t)(lo + dcol[m2])*T_ + (lo + rr)];
  }
  __syncthreads();
  if (K > 0){
    for (int idx = tid; idx < K*n; idx += 256){
      int j = idx/n, rr = idx%n;
      double acc = 0.0;
      const double* Dj = DEL + (size_t)(lo + j)*T_;
      for (int i2 = 0; i2 < K; ++i2) acc += Qnd[(size_t)(lo + i2)*T_ + rr]*Dj[i2];
      GO[(size_t)(lo + j)*T_ + rr] = acc/nrm[j];
    }
  }
  __syncthreads();
  if (tid == 0){   // dlamrg(K, ND, stride -1): f32 comparisons, tie -> lam
    int i1 = 0, i2 = 0, p = 0;
    while (i1 < K || i2 < ND){
      bool t1;
      if (i1 >= K) t1 = false;
      else if (i2 >= ND) t1 = true;
      else t1 = (flam[i1] <= fddf[i2]);
      if (t1){ foval[p] = flam[i1]; osrc[p] = i1; i1++; }
      else { foval[p] = fddf[i2]; osrc[p] = K + i2; i2++; }
      p++;
    }
  }
  __syncthreads();
  for (int idx = tid; idx < n*n; idx += 256){
    int p2 = idx/n, rr = idx%n;
    Z[(size_t)(lo + p2)*T_ + (lo + rr)] = GO[(size_t)(lo + osrc[p2])*T_ + rr];
  }
  for (int p2 = tid; p2 < n; p2 += 256) dv[lo + p2] = (double)foval[p2];
}

// ---------------------------------------------------------------------------
// K2f: back-transform Z <- Q*Z + val32 = f32(lambda * orgnrm)
// ---------------------------------------------------------------------------
__global__ __launch_bounds__(256) void k_backt(const double* __restrict__ Ab, double* __restrict__ Zb,
                                               const double* __restrict__ dar, const double* __restrict__ tauar,
                                               const float* __restrict__ orgn, float* __restrict__ val32){
  const int b = blockIdx.x, tid = threadIdx.x;
  const double* A = Ab + (size_t)b*MATN;
  double* Z = Zb + (size_t)b*MATN;
  __shared__ double vsh[T_];
  for (int i = T_-2; i >= 0; --i){
    double tau = tauar[b*T_ + i];
    if (tau != 0.0){
      for (int r = i+1+tid; r < T_; r += 256) vsh[r] = (r == i+1) ? 1.0 : A[(size_t)r*T_ + i];
      __syncthreads();
      for (int c = tid; c < T_; c += 256){
        double* Zc = Z + (size_t)c*T_;
        double w = 0.0;
        for (int r = i+1; r < T_; ++r) w += vsh[r]*Zc[r];
        w *= tau;
        for (int r = i+1; r < T_; ++r) Zc[r] -= w*vsh[r];
      }
      __syncthreads();
    }
  }
  float og = orgn[b];
  for (int j = tid; j < T_; j += 256) val32[b*T_ + j] = (float)dar[b*T_ + j] * og;
}

// residual diagnostic (batch 0, unscaled eigenvalues)
__global__ void k_chk(const float* __restrict__ gm, const double* __restrict__ Zb,
                      const float* __restrict__ val32, int tag){
  const int tid = threadIdx.x;
  const double* Z = Zb;
  __shared__ double red[256];
  double res[2]; const int cols[2] = {0, 175};
  for (int k = 0; k < 2; ++k){
    int j = cols[k];
    double lamj = (double)val32[j];
    double mxv = 0.0;
    for (int t2 = tid; t2 < T_; t2 += 256){
      double y = 0.0;
      for (int r = 0; r < T_; ++r) y += (double)gm[(size_t)t2*T_ + r]*Z[(size_t)j*T_ + r];
      mxv = fmax(mxv, fabs(y - lamj*Z[(size_t)j*T_ + t2]));
    }
    red[tid] = mxv; __syncthreads();
    for (int o = 128; o > 0; o >>= 1){ if (tid < o) red[tid] = fmax(red[tid], red[tid+o]); __syncthreads(); }
    res[k] = red[0]; __syncthreads();
  }
  if (tid == 0)
    printf("[EIGH%d] l0=%.8e l175=%.8e res=%.2e/%.2e\n", tag, (double)val32[0], (double)val32[175], res[0], res[1]);
}

__global__ __launch_bounds__(256) void k_argmax(const double* __restrict__ Zb, const float* __restrict__ val,
                                                const float* __restrict__ gum, int* __restrict__ am,
                                                float* __restrict__ marg){
  const int t = blockIdx.x, b = blockIdx.y, tid = threadIdx.x;
  const double* Z = Zb + (size_t)b*MATN;
  __shared__ float ys[T_];
  if (tid < T_){
    float vd = val[b*T_ + (T_-1 - tid)];
    float dc = (vd <= 0.f) ? 1e-7f : vd;
    float S = (float)Z[(size_t)tid*T_ + t]*sqrtf(dc);
    ys[tid] = (S + gum[((size_t)b*T_ + t)*T_ + tid])/1e-5f;
  }
  __syncthreads();
  if (tid == 0){
    int bi = 0; float bv = ys[0], sv = -3.4e38f;
    for (int j = 1; j < T_; ++j){
      float y = ys[j];
      if (y > bv){ sv = bv; bv = y; bi = j; } else if (y > sv) sv = y;
    }
    am[b*T_ + t] = bi;
    if (marg != 0) marg[b*T_ + t] = bv - sv;
  }
}

__global__ void k_cmp(const int* __restrict__ am0, const int* __restrict__ am1,
                      const float* __restrict__ marg){
  if (threadIdx.x != 0 || blockIdx.x != 0) return;
  int f01 = 0; float mn = 3.4e38f;
  for (int i = 0; i < B_*T_; ++i){
    if (am0[i] != am1[i]) f01++;
    mn = fminf(mn, marg[i]);
  }
  printf("[AB] flips(new-vs-old)=%d minmarg_y=%.3e (S %.3e)\n", f01, mn, mn*1e-5f);
}

// ---------------------------------------------------------------------------
// K3: Group softmax (f32 op order as ref).
// ---------------------------------------------------------------------------
__global__ __launch_bounds__(256) void k_group(const double* __restrict__ Zb, const float* __restrict__ val32,
                                               const float* __restrict__ gum, float* __restrict__ grp){
  const int t = blockIdx.x, b = blockIdx.y, tid = threadIdx.x;
  const double* Z = Zb + (size_t)b*MATN;
  __shared__ float sred[256];
  float y = -3.4e38f;
  if (tid < T_){
    float vd = val32[b*T_ + (T_-1 - tid)];
    float dc = (vd <= 0.f) ? 1e-7f : vd;
    float dj = sqrtf(dc);
    float v = (float)Z[(size_t)tid*T_ + t];
    float S = v*dj;
    y = (S + gum[((size_t)b*T_ + t)*T_ + tid])/1e-5f;
  }
  sred[tid] = y; __syncthreads();
  for (int o = 128; o > 0; o >>= 1){ if (tid < o) sred[tid] = fmaxf(sred[tid], sred[tid+o]); __syncthreads(); }
  float ym = sred[0]; __syncthreads();
  float e = (tid < T_) ? expf(y - ym) : 0.f;
  sred[tid] = e; __syncthreads();
  for (int o = 128; o > 0; o >>= 1){ if (tid < o) sred[tid] += sred[tid+o]; __syncthreads(); }
  float se = sred[0];
  if (tid < T_) grp[((size_t)b*T_ + t)*T_ + tid] = e/se;
}

__global__ void k_iszero(const float* __restrict__ grp, const float* __restrict__ mx, int* __restrict__ iz){
  int g = blockIdx.x, b = blockIdx.y, tid = threadIdx.x;
  bool nz = false;
  for (int t2 = tid; t2 < T_; t2 += 64){
    float w = grp[((size_t)b*T_ + t2)*T_ + g];
    if (w != 0.f){
      double p = fabs((double)w)*(double)mx[b*T_ + t2];
      if (p > 0x1.0p-150) nz = true;
    }
  }
  unsigned long long bal = __ballot(nz);
  if (tid == 0) iz[b*T_ + g] = (bal == 0ull) ? 1 : 0;
}

__global__ void k_slots(const int* __restrict__ iz, int* __restrict__ slot, int* __restrict__ nkeep){
  int b = blockIdx.x;
  if (threadIdx.x == 0){
    int c = 0;
    for (int g = 0; g < T_; ++g){
      if (!iz[b*T_ + g]) slot[b*T_ + g] = c++;
      else slot[b*T_ + g] = -1;
    }
    nkeep[b] = c;
  }
}

__global__ __launch_bounds__(256) void k_zero(const int* __restrict__ nkeep, float* __restrict__ padded){
  int k = blockIdx.x, b = blockIdx.y, tid = threadIdx.x;
  if (k < nkeep[b]) return;
  float* dst = padded + ((size_t)b*T_ + k)*NPAIR_;
  for (int p = tid; p < NPAIR_; p += 256) dst[p] = 0.f;
}

__global__ __launch_bounds__(256) void k_fc(const float* __restrict__ grp, const float* __restrict__ X,
                                            const int* __restrict__ iz, const int* __restrict__ slot,
                                            float* __restrict__ padded){
  const int g = blockIdx.x, b = blockIdx.y, tid = threadIdx.x;
  if (iz[b*T_ + g]) return;
  __shared__ float wcol[T_];
  __shared__ int tl[T_];
  __shared__ int scnt;
  __shared__ double mm[ROI_], inv[ROI_];
  for (int t2 = tid; t2 < T_; t2 += 256) wcol[t2] = grp[((size_t)b*T_ + t2)*T_ + g];
  __syncthreads();
  if (tid == 0){
    int c = 0;
    for (int t2 = 0; t2 < T_; ++t2) if (wcol[t2] != 0.f) tl[c++] = t2;
    scnt = c;
  }
  __syncthreads();
  int cnt = scnt;
  for (int i = tid; i < ROI_; i += 256){
    double A = 0.0, Q = 0.0;
    for (int k = 0; k < cnt; ++k){
      int t2 = tl[k];
      double wx = (double)wcol[t2]*(double)X[((size_t)b*T_ + t2)*ROI_ + i];
      A += wx; Q += wx*wx;
    }
    double m2 = A/176.0;
    double var = (Q - 176.0*m2*m2)/175.0;
    double sd = sqrt(fmax(var, 0.0));
    mm[i] = m2; inv[i] = 1.0/(sd + 1e-7);
  }
  __syncthreads();
  int outrow = slot[b*T_ + g];
  float* dst = padded + ((size_t)b*T_ + outrow)*NPAIR_;
  for (int p = tid; p < NPAIR_; p += 256){
    int i = (int)(115.5 - sqrt(115.5*115.5 - 2.0*(double)p));
    if (i < 0) i = 0;
    while ((i+1)*115 - ((i+1)*i)/2 <= p) ++i;
    while (i*115 - (i*(i-1))/2 > p) --i;
    int off = i*115 - (i*(i-1))/2;
    int j = i + 1 + (p - off);
    double q = 0.0;
    for (int k = 0; k < cnt; ++k){
      int t2 = tl[k];
      double w = (double)wcol[t2];
      const float* Xr = X + ((size_t)b*T_ + t2)*ROI_;
      q += (w*(double)Xr[i])*(w*(double)Xr[j]);
    }
    double fc = (q - 176.0*mm[i]*mm[j])*inv[i]*inv[j]/175.0;
    dst[p] = (float)fc;
  }
}

// ---------------------------------------------------------------------------
extern "C" void kernel_launch(void* const* d_in, const int* in_sizes, int n_in,
                              void* d_out, int out_size, void* d_ws, size_t ws_size,
                              hipStream_t stream){
  (void)in_sizes; (void)n_in; (void)out_size; (void)ws_size;
  const float* X   = (const float*)d_in[0];
  const float* W1  = (const float*)d_in[1];
  const float* b1  = (const float*)d_in[2];
  const float* W2  = (const float*)d_in[3];
  const float* b2  = (const float*)d_in[4];
  const float* gum = (const float*)d_in[5];

  float* out    = (float*)d_out;
  float* padded = out;                          // [B, 176, 6670]
  float* gm     = out + (size_t)PAD_ELEMS;      // [B, 176, 176]
  float* grp    = gm  + (size_t)B_*T_*T_;       // [B, 176, 176]

  // Eigh scratch in the padded region (consumed BEFORE padded is written).
  double* MATS = (double*)d_out;
  const size_t MS = (size_t)MATN;
  double* A    = MATS;            // 16 mats
  double* Zv   = MATS + 16*MS;    // 16
  double* QND  = MATS + 32*MS;    // 16
  double* DELm = MATS + 48*MS;    // 16
  double* GOm  = MATS + 64*MS;    // 16
  double* aux  = MATS + 80*MS;
  const int NBT = B_*T_;
  double* dar   = aux;            double* ear = dar + NBT;  double* tauar = ear + NBT;
  float* fs     = (float*)(tauar + NBT);
  float* val32  = fs;             float* mx = val32 + NBT;  float* marg = mx + NBT;
  float* orgn   = marg + NBT;
  int* am0      = (int*)(orgn + NBT);
  int* am1      = am0 + NBT;
  // Arrays read DURING padded writes live in d_ws (survive k_zero/k_fc).
  int* iz    = (int*)d_ws;
  int* slot  = iz + NBT;
  int* nkeep = slot + NBT;

  k_gm     <<<dim3(T_, B_), 256, 0, stream>>>(X, W1, b1, W2, b2, gm);
  k_maxabs <<<dim3(T_, B_),  64, 0, stream>>>(X, mx);

  // V1: old slartg (diagnostic)
  k_tridiag<<<B_, 256, 0, stream>>>(gm, A, Zv, dar, ear, tauar, orgn);
  k_leaf   <<<dim3(8, B_), 64, 0, stream>>>(Zv, dar, ear, 1);
  k_merge  <<<dim3(4, B_), 256, 0, stream>>>(Zv, QND, DELm, GOm, dar, ear, 22, 1);
  k_merge  <<<dim3(2, B_), 256, 0, stream>>>(Zv, QND, DELm, GOm, dar, ear, 44, 1);
  k_merge  <<<dim3(1, B_), 256, 0, stream>>>(Zv, QND, DELm, GOm, dar, ear, 88, 1);
  k_backt  <<<B_, 256, 0, stream>>>(A, Zv, dar, tauar, orgn, val32);
  k_chk    <<<1, 256, 0, stream>>>(gm, Zv, val32, 1);
  k_argmax <<<dim3(T_, B_), 256, 0, stream>>>(Zv, val32, gum, am1, (float*)0);

  // V0: new slartg (OUTPUT variant; runs last so Zv/val32 stay live)
  k_tridiag<<<B_, 256, 0, stream>>>(gm, A, Zv, dar, ear, tauar, orgn);
  k_leaf   <<<dim3(8, B_), 64, 0, stream>>>(Zv, dar, ear, 0);
  k_merge  <<<dim3(4, B_), 256, 0, stream>>>(Zv, QND, DELm, GOm, dar, ear, 22, 0);
  k_merge  <<<dim3(2, B_), 256, 0, stream>>>(Zv, QND, DELm, GOm, dar, ear, 44, 0);
  k_merge  <<<dim3(1, B_), 256, 0, stream>>>(Zv, QND, DELm, GOm, dar, ear, 88, 0);
  k_backt  <<<B_, 256, 0, stream>>>(A, Zv, dar, tauar, orgn, val32);
  k_chk    <<<1, 256, 0, stream>>>(gm, Zv, val32, 0);
  k_argmax <<<dim3(T_, B_), 256, 0, stream>>>(Zv, val32, gum, am0, marg);
  k_cmp    <<<1, 64, 0, stream>>>(am0, am1, marg);

  // Output pipeline from V0 (new slartg). k_group consumes Zv/val32 BEFORE
  // k_zero/k_fc overwrite the padded (= scratch) region.
  k_group  <<<dim3(T_, B_), 256, 0, stream>>>(Zv, val32, gum, grp);
  k_iszero <<<dim3(T_, B_),  64, 0, stream>>>(grp, mx, iz);
  k_slots  <<<B_,            64, 0, stream>>>(iz, slot, nkeep);
  k_zero   <<<dim3(T_, B_), 256, 0, stream>>>(nkeep, padded);
  k_fc     <<<dim3(T_, B_), 256, 0, stream>>>(grp, X, iz, slot, padded);
}

// Round 8
// 9916.750 us; speedup vs baseline: 1.9624x; 1.9624x over previous
//
#include <hip/hip_runtime.h>

// ---------------------------------------------------------------------------
// GMPool: distance-MLP -> grouping_M -> eigh (LAPACK ssyevd-faithful port) ->
// tau=1e-5 softmax Group -> per-group FC features -> packed output.
//
// R7 (PASS, absmax 3.9e-3): f32 precision-path fidelity in ssteqr leaves +
// slaed2 deflation scan reproduces numpy's eigenvector signs.
// R8 (perf, bit-identical output):
//  - dropped V1 diagnostic chain + all diagnostics/printfs (eigh runs once)
//  - k_merge: Givens DROTs recorded during the serial scan, applied
//    row-parallel afterwards (scan never reads Z -> exact same result)
// ---------------------------------------------------------------------------

#define T_    176
#define B_    16
#define ROI_  116
#define HID_  200
#define NPAIR_ 6670
#define MATN  (T_*T_)          // 30976
#define PAD_ELEMS (B_*T_*NPAIR_)   // 75.1 MB of floats
#define EPS32F 5.9604644775390625e-8f
#define SAFMIN32F 1.17549435e-38f

__device__ __forceinline__ double fsign(double a, double b){ return (b >= 0.0) ? fabs(a) : -fabs(a); }
__device__ __forceinline__ float fsignf_(float a, float b){ return (b >= 0.0f) ? fabsf(a) : -fabsf(a); }

__device__ __forceinline__ float slapy2f(float x, float y){
  float xa = fabsf(x), ya = fabsf(y);
  float w = fmaxf(xa, ya), z = fminf(xa, ya);
  if (z == 0.0f) return w;
  float q = z / w;
  return w * sqrtf(1.0f + q*q);
}

// LAPACK >=3.10 slartg, f32: c >= 0 always, r = sign(d, f)
__device__ __forceinline__ void lartgf_new(float f, float g, float* c, float* s, float* r){
  if (g == 0.0f){ *c = 1.0f; *s = 0.0f; *r = f; }
  else if (f == 0.0f){ *c = 0.0f; *s = (g >= 0.0f) ? 1.0f : -1.0f; *r = fabsf(g); }
  else {
    float d = sqrtf(f*f + g*g);
    *c = fabsf(f)/d;
    *r = fsignf_(d, f);
    *s = g/(*r);
  }
}

// LAPACK slaev2, f32 port
__device__ void laev2f(float a, float b, float c, float* rt1, float* rt2, float* cs1, float* sn1){
  float sm = a + c, df = a - c, adf = fabsf(df), tb = b + b, ab = fabsf(tb);
  float acmx, acmn;
  if (fabsf(a) > fabsf(c)){ acmx = a; acmn = c; } else { acmx = c; acmn = a; }
  float rt;
  if (adf > ab) rt = adf*sqrtf(1.0f + (ab/adf)*(ab/adf));
  else if (adf < ab) rt = ab*sqrtf(1.0f + (adf/ab)*(adf/ab));
  else rt = ab*sqrtf(2.0f);
  int sgn1;
  if (sm < 0.0f){ *rt1 = 0.5f*(sm - rt); sgn1 = -1; *rt2 = (acmx / *rt1)*acmn - (b / *rt1)*b; }
  else if (sm > 0.0f){ *rt1 = 0.5f*(sm + rt); sgn1 = 1; *rt2 = (acmx / *rt1)*acmn - (b / *rt1)*b; }
  else { *rt1 = 0.5f*rt; *rt2 = -0.5f*rt; sgn1 = 1; }
  float cs; int sgn2;
  if (df >= 0.0f){ cs = df + rt; sgn2 = 1; } else { cs = df - rt; sgn2 = -1; }
  float acs = fabsf(cs);
  if (acs > ab){ float ct = -tb/cs; float sn = 1.0f/sqrtf(1.0f + ct*ct); *sn1 = sn; *cs1 = ct*sn; }
  else {
    if (ab == 0.0f){ *cs1 = 1.0f; *sn1 = 0.0f; }
    else { float tn = -cs/tb; float c1 = 1.0f/sqrtf(1.0f + tn*tn); *cs1 = c1; *sn1 = tn*c1; }
  }
  if (sgn1 == sgn2){ float tn = *cs1; *cs1 = -(*sn1); *sn1 = tn; }
}

// ---------------------------------------------------------------------------
// K1: grouping_M.  block=(t,b), 256 thr.
// ---------------------------------------------------------------------------
__global__ __launch_bounds__(256) void k_gm(const float* __restrict__ X, const float* __restrict__ W1,
                                            const float* __restrict__ b1, const float* __restrict__ W2,
                                            const float* __restrict__ b2, float* __restrict__ gm){
  const int t = blockIdx.x, b = blockIdx.y, tid = threadIdx.x;
  __shared__ float4 w1p[29*200];
  __shared__ __align__(16) float dist[116];
  __shared__ float xt[116];
  __shared__ float b1s[200];
  __shared__ float w2s[200];
  __shared__ float wred[4];
  for (int li = tid; li < 29*200; li += 256){
    int j = li % 200, r4 = li / 200;
    const float* src = W1 + j*ROI_ + r4*4;
    w1p[li] = make_float4(src[0], src[1], src[2], src[3]);
  }
  for (int j = tid; j < 200; j += 256){ b1s[j] = b1[j]; w2s[j] = W2[j]; }
  if (tid < ROI_) xt[tid] = X[(size_t)(b*T_ + t)*ROI_ + tid];
  float b2v = b2[0];
  if (tid == 0) gm[(size_t)(b*T_ + t)*T_ + t] = 1.0f + 1e-7f;
  __syncthreads();
  for (int s = t + 1; s < T_; ++s){
    if (tid < ROI_){
      float xs = X[(size_t)(b*T_ + s)*ROI_ + tid];
      float df = xt[tid] - xs;
      dist[tid] = sqrtf(df*df + 1e-9f);
    }
    __syncthreads();
    float part = 0.f;
    if (tid < HID_){
      float acc = 0.f;
      const float4* dv4 = reinterpret_cast<const float4*>(dist);
      #pragma unroll
      for (int r4 = 0; r4 < 29; ++r4){
        float4 w = w1p[r4*200 + tid];
        float4 d4 = dv4[r4];
        acc += w.x*d4.x; acc += w.y*d4.y; acc += w.z*d4.z; acc += w.w*d4.w;
      }
      acc += b1s[tid];
      float h = fmaxf(acc, 0.f);
      part = w2s[tid]*h;
    }
    for (int off = 32; off > 0; off >>= 1) part += __shfl_down(part, off, 64);
    if ((tid & 63) == 0) wred[tid >> 6] = part;
    __syncthreads();
    if (tid == 0){
      float logit = wred[0] + wred[1] + wred[2] + wred[3] + b2v;
      float c = 1.0f/(1.0f + expf(-logit));
      float v = c + 1e-7f;
      gm[(size_t)(b*T_ + t)*T_ + s] = v;
      gm[(size_t)(b*T_ + s)*T_ + t] = v;
    }
    __syncthreads();
  }
}

__global__ void k_maxabs(const float* __restrict__ X, float* __restrict__ mx){
  int t = blockIdx.x, b = blockIdx.y, tid = threadIdx.x;
  float m = 0.f;
  for (int r = tid; r < ROI_; r += 64) m = fmaxf(m, fabsf(X[(size_t)(b*T_ + t)*ROI_ + r]));
  for (int off = 32; off > 0; off >>= 1) m = fmaxf(m, __shfl_down(m, off, 64));
  if (tid == 0) mx[b*T_ + t] = m;
}

// ---------------------------------------------------------------------------
// K2a: ssytd2 (lower) in f64, then f32-round d/e, sstedc scaling (f32),
// slaed0 tears (f32).
// ---------------------------------------------------------------------------
__global__ __launch_bounds__(256) void k_tridiag(const float* __restrict__ gm, double* __restrict__ Ab,
                                                 double* __restrict__ Zb, double* __restrict__ dar,
                                                 double* __restrict__ ear, double* __restrict__ tauar,
                                                 float* __restrict__ orgn){
  const int b = blockIdx.x, tid = threadIdx.x;
  double* A = Ab + (size_t)b*MATN;
  double* Z = Zb + (size_t)b*MATN;
  const float* gmb = gm + (size_t)b*MATN;
  __shared__ double vsh[T_], wsh[T_], red[256];
  for (int idx = tid; idx < MATN; idx += 256){ A[idx] = (double)gmb[idx]; Z[idx] = 0.0; }
  __syncthreads();
  for (int i = 0; i <= T_-2; ++i){
    int m = T_ - 1 - i;
    double alpha = A[(size_t)(i+1)*T_ + i];
    double part = 0.0;
    for (int r = i+2+tid; r < T_; r += 256){ double x = A[(size_t)r*T_ + i]; part += x*x; }
    red[tid] = part; __syncthreads();
    for (int o = 128; o > 0; o >>= 1){ if (tid < o) red[tid] += red[tid+o]; __syncthreads(); }
    double xnorm2 = red[0];
    __syncthreads();
    if (m == 1 || xnorm2 == 0.0){
      if (tid == 0){ tauar[b*T_ + i] = 0.0; ear[b*T_ + i] = alpha; }
      __syncthreads();
      continue;
    }
    double beta = -fsign(sqrt(alpha*alpha + xnorm2), alpha);
    double tau  = (beta - alpha)/beta;
    double sc   = 1.0/(alpha - beta);
    for (int r = i+2+tid; r < T_; r += 256) A[(size_t)r*T_ + i] *= sc;
    __syncthreads();
    for (int r = i+1+tid; r < T_; r += 256) vsh[r] = (r == i+1) ? 1.0 : A[(size_t)r*T_ + i];
    __syncthreads();
    for (int r = i+1+tid; r < T_; r += 256){
      double acc = 0.0;
      const double* Ar = A + (size_t)r*T_;
      for (int c = i+1; c < T_; ++c) acc += Ar[c]*vsh[c];
      wsh[r] = tau*acc;
    }
    __syncthreads();
    part = 0.0;
    for (int r = i+1+tid; r < T_; r += 256) part += wsh[r]*vsh[r];
    red[tid] = part; __syncthreads();
    for (int o = 128; o > 0; o >>= 1){ if (tid < o) red[tid] += red[tid+o]; __syncthreads(); }
    double a2 = -0.5*tau*red[0];
    __syncthreads();
    for (int r = i+1+tid; r < T_; r += 256) wsh[r] += a2*vsh[r];
    __syncthreads();
    for (int idx = tid; idx < m*m; idx += 256){
      int rr = i+1 + idx/m, cc = i+1 + idx%m;
      A[(size_t)rr*T_ + cc] -= vsh[rr]*wsh[cc] + wsh[rr]*vsh[cc];
    }
    if (tid == 0){ ear[b*T_ + i] = beta; tauar[b*T_ + i] = tau; }
    __syncthreads();
  }
  for (int j = tid; j < T_; j += 256) dar[b*T_ + j] = A[(size_t)j*T_ + j];
  __syncthreads();
  if (tid == 0){
    // round d/e to f32
    for (int j = 0; j < T_; ++j) dar[b*T_ + j] = (double)(float)dar[b*T_ + j];
    for (int j = 0; j < T_-1; ++j) ear[b*T_ + j] = (double)(float)ear[b*T_ + j];
    // sstedc scaling by orgnrm (f32)
    float og = 0.0f;
    for (int j = 0; j < T_; ++j) og = fmaxf(og, fabsf((float)dar[b*T_ + j]));
    for (int j = 0; j < T_-1; ++j) og = fmaxf(og, fabsf((float)ear[b*T_ + j]));
    for (int j = 0; j < T_; ++j) dar[b*T_ + j] = (double)(float)((float)dar[b*T_ + j]/og);
    for (int j = 0; j < T_-1; ++j) ear[b*T_ + j] = (double)(float)((float)ear[b*T_ + j]/og);
    orgn[b] = og;
    // slaed0 tears in f32 on scaled values
    const int sp[7] = {21,43,65,87,109,131,153};
    for (int k = 0; k < 7; ++k){
      float ae = fabsf((float)ear[b*T_ + sp[k]]);
      dar[b*T_ + sp[k]]     = (double)((float)dar[b*T_ + sp[k]] - ae);
      dar[b*T_ + sp[k] + 1] = (double)((float)dar[b*T_ + sp[k] + 1] - ae);
    }
  }
}

// ---------------------------------------------------------------------------
// K2b: ssteqr('I') on 22x22 leaves, FULL f32 arithmetic (LAPACK path-faithful).
// grid(8,16) x 64 thr.
// ---------------------------------------------------------------------------
__global__ __launch_bounds__(64) void k_leaf(double* __restrict__ Zb, double* __restrict__ dar,
                                             const double* __restrict__ ear){
  const int lf = blockIdx.x, b = blockIdx.y, tid = threadIdx.x;
  const int off = lf*22;
  double* Z = Zb + (size_t)b*MATN;
  __shared__ float ld_[22], le_[22];
  __shared__ float zl[22*22];
  __shared__ int perm_[22];
  for (int k = tid; k < 22; k += 64){
    ld_[k] = (float)dar[b*T_ + off + k];
    le_[k] = (k < 21) ? (float)ear[b*T_ + off + k] : 0.0f;
  }
  for (int idx = tid; idx < 484; idx += 64) zl[idx] = (idx/22 == idx%22) ? 1.0f : 0.0f;
  __syncthreads();
  const float eps = EPS32F, eps2 = EPS32F*EPS32F, safmin = SAFMIN32F;
  const int n = 22, nm1 = 21, nmaxit = 22*30;
  int jtot = 0, l1 = 0;
  while (l1 <= n-1){
    if (l1 > 0) le_[l1-1] = 0.0f;
    int msp = n-1;
    for (int mm2 = l1; mm2 < nm1; ++mm2){
      float tst = fabsf(le_[mm2]);
      if (tst == 0.0f){ msp = mm2; break; }
      if (tst <= (sqrtf(fabsf(ld_[mm2]))*sqrtf(fabsf(ld_[mm2+1])))*eps){
        le_[mm2] = 0.0f;
        msp = mm2; break;
      }
    }
    int l = l1, lend = msp;
    l1 = msp + 1;
    if (lend == l) continue;
    if (fabsf(ld_[lend]) < fabsf(ld_[l])){ int tmp = l; l = lend; lend = tmp; }
    if (lend > l){
      for (;;){ // QL
        int m2 = lend;
        if (l != lend){
          for (int k = l; k < lend; ++k){
            float tst = le_[k]*le_[k];
            if (tst <= (eps2*fabsf(ld_[k]))*fabsf(ld_[k+1]) + safmin){ m2 = k; break; }
          }
        }
        if (m2 < lend) le_[m2] = 0.0f;
        float p = ld_[l];
        if (m2 == l){ l++; if (l <= lend) continue; else break; }
        if (m2 == l+1){
          float rt1, rt2, c2, s2;
          laev2f(ld_[l], le_[l], ld_[l+1], &rt1, &rt2, &c2, &s2);
          if (tid < 22){
            float t0 = zl[tid*22 + l], t1 = zl[tid*22 + l+1];
            zl[tid*22 + l]   = c2*t0 + s2*t1;
            zl[tid*22 + l+1] = -s2*t0 + c2*t1;
          }
          ld_[l] = rt1; ld_[l+1] = rt2; le_[l] = 0.0f;
          l += 2;
          if (l <= lend) continue; else break;
        }
        if (jtot == nmaxit) break;
        jtot++;
        float g = (ld_[l+1] - p)/(2.0f*le_[l]);
        float r = slapy2f(g, 1.0f);
        g = ld_[m2] - p + le_[l]/(g + fsignf_(r, g));
        float s2 = 1.0f, c2 = 1.0f;
        p = 0.0f;
        for (int i = m2-1; i >= l; --i){
          float f2 = s2*le_[i];
          float bb = c2*le_[i];
          lartgf_new(g, f2, &c2, &s2, &r);
          if (i != m2-1) le_[i+1] = r;
          g = ld_[i+1] - p;
          r = (ld_[i] - g)*s2 + 2.0f*c2*bb;
          p = s2*r;
          ld_[i+1] = g + p;
          g = c2*r - bb;
          if (tid < 22){   // QL stores sn = -s
            float t0 = zl[tid*22 + i], t1 = zl[tid*22 + i+1];
            zl[tid*22 + i]   = c2*t0 - s2*t1;
            zl[tid*22 + i+1] = s2*t0 + c2*t1;
          }
        }
        ld_[l] -= p; le_[l] = g;
        if (l <= lend) continue; else break;
      }
    } else {
      for (;;){ // QR
        int m2 = lend;
        if (l != lend){
          for (int k = l; k > lend; --k){
            float tst = le_[k-1]*le_[k-1];
            if (tst <= (eps2*fabsf(ld_[k]))*fabsf(ld_[k-1]) + safmin){ m2 = k; break; }
          }
        }
        if (m2 > lend) le_[m2-1] = 0.0f;
        float p = ld_[l];
        if (m2 == l){ l--; if (l >= lend) continue; else break; }
        if (m2 == l-1){
          float rt1, rt2, c2, s2;
          laev2f(ld_[l-1], le_[l-1], ld_[l], &rt1, &rt2, &c2, &s2);
          if (tid < 22){
            float t0 = zl[tid*22 + l-1], t1 = zl[tid*22 + l];
            zl[tid*22 + l-1] = c2*t0 + s2*t1;
            zl[tid*22 + l]   = -s2*t0 + c2*t1;
          }
          ld_[l-1] = rt1; ld_[l] = rt2; le_[l-1] = 0.0f;
          l -= 2;
          if (l >= lend) continue; else break;
        }
        if (jtot == nmaxit) break;
        jtot++;
        float g = (ld_[l-1] - p)/(2.0f*le_[l-1]);
        float r = slapy2f(g, 1.0f);
        g = ld_[m2] - p + le_[l-1]/(g + fsignf_(r, g));
        float s2 = 1.0f, c2 = 1.0f;
        p = 0.0f;
        for (int i = m2; i <= l-1; ++i){
          float f2 = s2*le_[i];
          float bb = c2*le_[i];
          lartgf_new(g, f2, &c2, &s2, &r);
          if (i != m2) le_[i-1] = r;
          g = ld_[i] - p;
          r = (ld_[i+1] - g)*s2 + 2.0f*c2*bb;
          p = s2*r;
          ld_[i] = g + p;
          g = c2*r - bb;
          if (tid < 22){   // QR stores sn = +s
            float t0 = zl[tid*22 + i], t1 = zl[tid*22 + i+1];
            zl[tid*22 + i]   = c2*t0 + s2*t1;
            zl[tid*22 + i+1] = -s2*t0 + c2*t1;
          }
        }
        ld_[l] -= p; le_[l-1] = g;
        if (l >= lend) continue; else break;
      }
    }
  }
  __syncthreads();
  if (tid == 0){   // selection sort (strict <, LAPACK ssteqr)
    bool used[22]; for (int k = 0; k < 22; ++k) used[k] = false;
    for (int c = 0; c < 22; ++c){
      int best = -1; float bv = 0.0f;
      for (int k = 0; k < 22; ++k) if (!used[k] && (best < 0 || ld_[k] < bv)){ best = k; bv = ld_[k]; }
      used[best] = true; perm_[c] = best;
    }
  }
  __syncthreads();
  if (tid < 22){
    int r = tid;
    for (int c = 0; c < 22; ++c) Z[(size_t)(off + c)*T_ + (off + r)] = (double)zl[r*22 + perm_[c]];
  }
  for (int c = tid; c < 22; c += 64) dar[b*T_ + off + c] = (double)ld_[perm_[c]];
}

// ---------------------------------------------------------------------------
// K2c/d/e: one D&C merge (slaed1/2/3).  grid(nmerge,16) x 256.
// f32 deflation scan records Givens rotations (scan never reads Z);
// rotations applied ROW-PARALLEL afterwards (bit-identical to serial order).
// Secular/z-hat/GEMM in f64; lambdas f32-rounded for dlamrg ordering.
// ---------------------------------------------------------------------------
__global__ __launch_bounds__(256) void k_merge(double* __restrict__ Zb, double* __restrict__ QNDb,
                                               double* __restrict__ DELb, double* __restrict__ GOb,
                                               double* __restrict__ dar, const double* __restrict__ ear,
                                               int n1){
  const int b = blockIdx.y, mg = blockIdx.x, tid = threadIdx.x;
  const int lo = mg*2*n1, n = 2*n1;
  double* Z   = Zb   + (size_t)b*MATN;
  double* Qnd = QNDb + (size_t)b*MATN;
  double* DEL = DELb + (size_t)b*MATN;
  double* GO  = GOb  + (size_t)b*MATN;
  double* dv  = dar + b*T_;
  __shared__ float frd[T_], frz[T_], fmd[T_], fmz[T_], fkd[T_], fkw[T_], fddf[T_], flam[T_], foval[T_];
  __shared__ double lam[T_], zh[T_], nrm[T_];
  __shared__ double rotc[T_], rots[T_];
  __shared__ int rotx[T_], roty[T_];
  __shared__ int mcol[T_], kcol[T_], dcol[T_], osrc[T_], indxp_[T_];
  __shared__ int sK, sND, sNROT;
  __shared__ double s_sumw2;
  __shared__ float s_rho;

  float rho0 = (float)ear[b*T_ + lo + n1 - 1];
  const float rs2f = 0.70710678118654752440f;
  for (int k = tid; k < n; k += 256){
    frd[k] = (float)dv[lo + k];
    int row = (k < n1) ? (lo + n1 - 1) : (lo + n1);
    float zv = (float)Z[(size_t)(lo + k)*T_ + row];
    if (k >= n1 && rho0 < 0.0f) zv = -zv;
    frz[k] = zv*rs2f;
  }
  __syncthreads();
  if (tid == 0){
    float rho = fabsf(2.0f*rho0);
    s_rho = rho;
    int nrot = 0;
    // slamrg merge of two sorted halves (tie -> first half)
    int i1 = 0, i2 = n1, p = 0;
    while (i1 < n1 || i2 < n){
      bool t1;
      if (i1 >= n1) t1 = false;
      else if (i2 >= n) t1 = true;
      else t1 = (frd[i1] <= frd[i2]);
      int src = t1 ? i1++ : i2++;
      fmd[p] = frd[src]; fmz[p] = frz[src]; mcol[p] = src; p++;
    }
    float dmax = 0.0f, zmax = 0.0f;
    for (int k = 0; k < n; ++k){ dmax = fmaxf(dmax, fabsf(fmd[k])); zmax = fmaxf(zmax, fabsf(fmz[k])); }
    float tol = 8.0f*EPS32F*fmaxf(dmax, zmax);
    int K = 0, ND = 0;
    if (rho*zmax <= tol){               // full deflation
      for (int k = 0; k < n; ++k){ fddf[k] = fmd[k]; dcol[k] = mcol[k]; }
      ND = n; K = 0;
    } else {                            // slaed2 deflation scan (f32, INDXP port)
      int k2 = n;
      int j = 0, pj = -1;
      for (; j < n; ++j){
        if (rho*fabsf(fmz[j]) <= tol){ k2--; indxp_[k2] = j; }
        else { pj = j; break; }
      }
      if (pj >= 0){
        for (;;){
          j++;
          if (j >= n) break;
          int nj = j;
          if (rho*fabsf(fmz[nj]) <= tol){
            k2--; indxp_[k2] = nj;
          } else {
            float s_ = fmz[pj], c_ = fmz[nj];
            float tau_ = slapy2f(c_, s_);
            float t_ = fmd[nj] - fmd[pj];
            c_ = c_/tau_; s_ = -s_/tau_;
            if (fabsf((t_*c_)*s_) <= tol){
              fmz[nj] = tau_; fmz[pj] = 0.0f;
              rotx[nrot] = mcol[pj]; roty[nrot] = mcol[nj];
              rotc[nrot] = (double)c_; rots[nrot] = (double)s_;
              nrot++;
              float dt = fmd[pj]*(c_*c_) + fmd[nj]*(s_*s_);
              fmd[nj] = fmd[pj]*(s_*s_) + fmd[nj]*(c_*c_);
              fmd[pj] = dt;
              k2--;
              int i3 = 1;               // loop 90 insertion (descending storage)
              for (;;){
                if (k2 + i3 <= n - 1){
                  if (fmd[pj] < fmd[indxp_[k2 + i3]]){
                    indxp_[k2 + i3 - 1] = indxp_[k2 + i3];
                    indxp_[k2 + i3]     = pj;
                    i3++;
                  } else { indxp_[k2 + i3 - 1] = pj; break; }
                } else { indxp_[k2 + i3 - 1] = pj; break; }
              }
              pj = nj;
            } else {
              fkd[K] = fmd[pj]; fkw[K] = fmz[pj]; kcol[K] = mcol[pj]; K++;
              pj = nj;
            }
          }
        }
        fkd[K] = fmd[pj]; fkw[K] = fmz[pj]; kcol[K] = mcol[pj]; K++;
      }
      ND = n - K;
      for (int m2 = 0; m2 < ND; ++m2){   // consume backward: ascending by value
        int mi = indxp_[n - 1 - m2];
        fddf[m2] = fmd[mi]; dcol[m2] = mcol[mi];
      }
    }
    sK = K; sND = ND; sNROT = nrot;
    double sw = 0.0; for (int k = 0; k < K; ++k) sw += (double)fkw[k]*(double)fkw[k];
    s_sumw2 = sw;
  }
  __syncthreads();
  // apply recorded Givens rotations row-parallel (per-row order == serial order)
  {
    int nrot = sNROT;
    for (int r = tid; r < n; r += 256){
      for (int q = 0; q < nrot; ++q){
        double* qx = Z + (size_t)(lo + rotx[q])*T_ + lo;
        double* qy = Z + (size_t)(lo + roty[q])*T_ + lo;
        double x = qx[r], y = qy[r];
        qx[r] = rotc[q]*x + rots[q]*y;
        qy[r] = rotc[q]*y - rots[q]*x;
      }
    }
  }
  __syncthreads();
  int K = sK, ND = sND;
  double rho_d = (double)s_rho;
  if (K > 0){
    // secular roots: guarded f64 bisection, delta relative to left pole
    for (int j = tid; j < K; j += 256){
      double dj = (double)fkd[j];
      double hi = (j < K-1) ? ((double)fkd[j+1] - dj) : (rho_d*s_sumw2 + 1e-300);
      if (hi < 0.0) hi = 0.0;
      double lo_t = 0.0, hi_t = hi;
      for (int it = 0; it < 70; ++it){
        double mid = 0.5*(lo_t + hi_t);
        if (mid == lo_t || mid == hi_t) break;
        double f = 1.0;
        for (int i2 = 0; i2 < K; ++i2){
          double dd2 = ((double)fkd[i2] - dj) - mid;
          f += rho_d*(double)fkw[i2]*(double)fkw[i2]/dd2;
        }
        if (f < 0.0) lo_t = mid; else hi_t = mid;
      }
      double tauj = 0.5*(lo_t + hi_t);
      if (tauj <= 0.0) tauj = (hi_t > 0.0) ? hi_t*0.5 : 1e-300;
      if (j < K-1){
        double hib = (double)fkd[j+1] - dj;
        if (tauj >= hib) tauj = nextafter(hib, 0.0);
      }
      lam[j] = dj + tauj;
      flam[j] = (float)lam[j];
      double* Dj = DEL + (size_t)(lo + j)*T_;
      for (int i2 = 0; i2 < K; ++i2) Dj[i2] = ((double)fkd[i2] - dj) - tauj;
    }
    __syncthreads();
    // Gu z-hat
    for (int i2 = tid; i2 < K; i2 += 256){
      double p = DEL[(size_t)(lo + i2)*T_ + i2];
      for (int j = 0; j < K; ++j){
        if (j == i2) continue;
        p *= DEL[(size_t)(lo + j)*T_ + i2]/((double)fkd[i2] - (double)fkd[j]);
      }
      zh[i2] = copysign(sqrt(fabs(p)), (double)fkw[i2]);
    }
    __syncthreads();
    for (int idx = tid; idx < K*K; idx += 256){
      int j = idx/K, i2 = idx%K;
      double* pj = DEL + (size_t)(lo + j)*T_ + i2;
      *pj = zh[i2]/(*pj);
    }
    __syncthreads();
    for (int j = tid; j < K; j += 256){
      double ss = 0.0;
      const double* Dj = DEL + (size_t)(lo + j)*T_;
      for (int i2 = 0; i2 < K; ++i2) ss += Dj[i2]*Dj[i2];
      nrm[j] = sqrt(ss);
    }
    __syncthreads();
    for (int idx = tid; idx < K*n; idx += 256){
      int k2 = idx/n, rr = idx%n;
      Qnd[(size_t)(lo + k2)*T_ + rr] = Z[(size_t)(lo + kcol[k2])*T_ + (lo + rr)];
    }
  }
  for (int idx = tid; idx < ND*n; idx += 256){
    int m2 = idx/n, rr = idx%n;
    GO[(size_t)(lo + K + m2)*T_ + rr] = Z[(size_t)(lo + dcol[m2])*T_ + (lo + rr)];
  }
  __syncthreads();
  if (K > 0){
    for (int idx = tid; idx < K*n; idx += 256){
      int j = idx/n, rr = idx%n;
      double acc = 0.0;
      const double* Dj = DEL + (size_t)(lo + j)*T_;
      for (int i2 = 0; i2 < K; ++i2) acc += Qnd[(size_t)(lo + i2)*T_ + rr]*Dj[i2];
      GO[(size_t)(lo + j)*T_ + rr] = acc/nrm[j];
    }
  }
  __syncthreads();
  if (tid == 0){   // dlamrg(K, ND, stride -1): f32 comparisons, tie -> lam
    int i1 = 0, i2 = 0, p = 0;
    while (i1 < K || i2 < ND){
      bool t1;
      if (i1 >= K) t1 = false;
      else if (i2 >= ND) t1 = true;
      else t1 = (flam[i1] <= fddf[i2]);
      if (t1){ foval[p] = flam[i1]; osrc[p] = i1; i1++; }
      else { foval[p] = fddf[i2]; osrc[p] = K + i2; i2++; }
      p++;
    }
  }
  __syncthreads();
  for (int idx = tid; idx < n*n; idx += 256){
    int p2 = idx/n, rr = idx%n;
    Z[(size_t)(lo + p2)*T_ + (lo + rr)] = GO[(size_t)(lo + osrc[p2])*T_ + rr];
  }
  for (int p2 = tid; p2 < n; p2 += 256) dv[lo + p2] = (double)foval[p2];
}

// ---------------------------------------------------------------------------
// K2f: back-transform Z <- Q*Z + val32 = f32(lambda) * orgnrm
// ---------------------------------------------------------------------------
__global__ __launch_bounds__(256) void k_backt(const double* __restrict__ Ab, double* __restrict__ Zb,
                                               const double* __restrict__ dar, const double* __restrict__ tauar,
                                               const float* __restrict__ orgn, float* __restrict__ val32){
  const int b = blockIdx.x, tid = threadIdx.x;
  const double* A = Ab + (size_t)b*MATN;
  double* Z = Zb + (size_t)b*MATN;
  __shared__ double vsh[T_];
  for (int i = T_-2; i >= 0; --i){
    double tau = tauar[b*T_ + i];
    if (tau != 0.0){
      for (int r = i+1+tid; r < T_; r += 256) vsh[r] = (r == i+1) ? 1.0 : A[(size_t)r*T_ + i];
      __syncthreads();
      for (int c = tid; c < T_; c += 256){
        double* Zc = Z + (size_t)c*T_;
        double w = 0.0;
        for (int r = i+1; r < T_; ++r) w += vsh[r]*Zc[r];
        w *= tau;
        for (int r = i+1; r < T_; ++r) Zc[r] -= w*vsh[r];
      }
      __syncthreads();
    }
  }
  float og = orgn[b];
  for (int j = tid; j < T_; j += 256) val32[b*T_ + j] = (float)dar[b*T_ + j] * og;
}

// ---------------------------------------------------------------------------
// K3: Group softmax (f32 op order as ref).
// ---------------------------------------------------------------------------
__global__ __launch_bounds__(256) void k_group(const double* __restrict__ Zb, const float* __restrict__ val32,
                                               const float* __restrict__ gum, float* __restrict__ grp){
  const int t = blockIdx.x, b = blockIdx.y, tid = threadIdx.x;
  const double* Z = Zb + (size_t)b*MATN;
  __shared__ float sred[256];
  float y = -3.4e38f;
  if (tid < T_){
    float vd = val32[b*T_ + (T_-1 - tid)];
    float dc = (vd <= 0.f) ? 1e-7f : vd;
    float dj = sqrtf(dc);
    float v = (float)Z[(size_t)tid*T_ + t];
    float S = v*dj;
    y = (S + gum[((size_t)b*T_ + t)*T_ + tid])/1e-5f;
  }
  sred[tid] = y; __syncthreads();
  for (int o = 128; o > 0; o >>= 1){ if (tid < o) sred[tid] = fmaxf(sred[tid], sred[tid+o]); __syncthreads(); }
  float ym = sred[0]; __syncthreads();
  float e = (tid < T_) ? expf(y - ym) : 0.f;
  sred[tid] = e; __syncthreads();
  for (int o = 128; o > 0; o >>= 1){ if (tid < o) sred[tid] += sred[tid+o]; __syncthreads(); }
  float se = sred[0];
  if (tid < T_) grp[((size_t)b*T_ + t)*T_ + tid] = e/se;
}

__global__ void k_iszero(const float* __restrict__ grp, const float* __restrict__ mx, int* __restrict__ iz){
  int g = blockIdx.x, b = blockIdx.y, tid = threadIdx.x;
  bool nz = false;
  for (int t2 = tid; t2 < T_; t2 += 64){
    float w = grp[((size_t)b*T_ + t2)*T_ + g];
    if (w != 0.f){
      double p = fabs((double)w)*(double)mx[b*T_ + t2];
      if (p > 0x1.0p-150) nz = true;
    }
  }
  unsigned long long bal = __ballot(nz);
  if (tid == 0) iz[b*T_ + g] = (bal == 0ull) ? 1 : 0;
}

__global__ void k_slots(const int* __restrict__ iz, int* __restrict__ slot, int* __restrict__ nkeep){
  int b = blockIdx.x;
  if (threadIdx.x == 0){
    int c = 0;
    for (int g = 0; g < T_; ++g){
      if (!iz[b*T_ + g]) slot[b*T_ + g] = c++;
      else slot[b*T_ + g] = -1;
    }
    nkeep[b] = c;
  }
}

__global__ __launch_bounds__(256) void k_zero(const int* __restrict__ nkeep, float* __restrict__ padded){
  int k = blockIdx.x, b = blockIdx.y, tid = threadIdx.x;
  if (k < nkeep[b]) return;
  float* dst = padded + ((size_t)b*T_ + k)*NPAIR_;
  for (int p = tid; p < NPAIR_; p += 256) dst[p] = 0.f;
}

__global__ __launch_bounds__(256) void k_fc(const float* __restrict__ grp, const float* __restrict__ X,
                                            const int* __restrict__ iz, const int* __restrict__ slot,
                                            float* __restrict__ padded){
  const int g = blockIdx.x, b = blockIdx.y, tid = threadIdx.x;
  if (iz[b*T_ + g]) return;
  __shared__ float wcol[T_];
  __shared__ int tl[T_];
  __shared__ int scnt;
  __shared__ double mm[ROI_], inv[ROI_];
  for (int t2 = tid; t2 < T_; t2 += 256) wcol[t2] = grp[((size_t)b*T_ + t2)*T_ + g];
  __syncthreads();
  if (tid == 0){
    int c = 0;
    for (int t2 = 0; t2 < T_; ++t2) if (wcol[t2] != 0.f) tl[c++] = t2;
    scnt = c;
  }
  __syncthreads();
  int cnt = scnt;
  for (int i = tid; i < ROI_; i += 256){
    double A = 0.0, Q = 0.0;
    for (int k = 0; k < cnt; ++k){
      int t2 = tl[k];
      double wx = (double)wcol[t2]*(double)X[((size_t)b*T_ + t2)*ROI_ + i];
      A += wx; Q += wx*wx;
    }
    double m2 = A/176.0;
    double var = (Q - 176.0*m2*m2)/175.0;
    double sd = sqrt(fmax(var, 0.0));
    mm[i] = m2; inv[i] = 1.0/(sd + 1e-7);
  }
  __syncthreads();
  int outrow = slot[b*T_ + g];
  float* dst = padded + ((size_t)b*T_ + outrow)*NPAIR_;
  for (int p = tid; p < NPAIR_; p += 256){
    int i = (int)(115.5 - sqrt(115.5*115.5 - 2.0*(double)p));
    if (i < 0) i = 0;
    while ((i+1)*115 - ((i+1)*i)/2 <= p) ++i;
    while (i*115 - (i*(i-1))/2 > p) --i;
    int off = i*115 - (i*(i-1))/2;
    int j = i + 1 + (p - off);
    double q = 0.0;
    for (int k = 0; k < cnt; ++k){
      int t2 = tl[k];
      double w = (double)wcol[t2];
      const float* Xr = X + ((size_t)b*T_ + t2)*ROI_;
      q += (w*(double)Xr[i])*(w*(double)Xr[j]);
    }
    double fc = (q - 176.0*mm[i]*mm[j])*inv[i]*inv[j]/175.0;
    dst[p] = (float)fc;
  }
}

// ---------------------------------------------------------------------------
extern "C" void kernel_launch(void* const* d_in, const int* in_sizes, int n_in,
                              void* d_out, int out_size, void* d_ws, size_t ws_size,
                              hipStream_t stream){
  (void)in_sizes; (void)n_in; (void)out_size; (void)ws_size;
  const float* X   = (const float*)d_in[0];
  const float* W1  = (const float*)d_in[1];
  const float* b1  = (const float*)d_in[2];
  const float* W2  = (const float*)d_in[3];
  const float* b2  = (const float*)d_in[4];
  const float* gum = (const float*)d_in[5];

  float* out    = (float*)d_out;
  float* padded = out;                          // [B, 176, 6670]
  float* gm     = out + (size_t)PAD_ELEMS;      // [B, 176, 176]
  float* grp    = gm  + (size_t)B_*T_*T_;       // [B, 176, 176]

  // Eigh scratch in the padded region (consumed BEFORE padded is written).
  double* MATS = (double*)d_out;
  const size_t MS = (size_t)MATN;
  double* A    = MATS;            // 16 mats
  double* Zv   = MATS + 16*MS;    // 16
  double* QND  = MATS + 32*MS;    // 16
  double* DELm = MATS + 48*MS;    // 16
  double* GOm  = MATS + 64*MS;    // 16
  double* aux  = MATS + 80*MS;
  const int NBT = B_*T_;
  double* dar   = aux;            double* ear = dar + NBT;  double* tauar = ear + NBT;
  float* fs     = (float*)(tauar + NBT);
  float* val32  = fs;             float* mx = val32 + NBT;  float* orgn = mx + NBT;
  // Arrays read DURING padded writes live in d_ws (survive k_zero/k_fc).
  int* iz    = (int*)d_ws;
  int* slot  = iz + NBT;
  int* nkeep = slot + NBT;

  k_gm     <<<dim3(T_, B_), 256, 0, stream>>>(X, W1, b1, W2, b2, gm);
  k_maxabs <<<dim3(T_, B_),  64, 0, stream>>>(X, mx);

  k_tridiag<<<B_, 256, 0, stream>>>(gm, A, Zv, dar, ear, tauar, orgn);
  k_leaf   <<<dim3(8, B_), 64, 0, stream>>>(Zv, dar, ear);
  k_merge  <<<dim3(4, B_), 256, 0, stream>>>(Zv, QND, DELm, GOm, dar, ear, 22);
  k_merge  <<<dim3(2, B_), 256, 0, stream>>>(Zv, QND, DELm, GOm, dar, ear, 44);
  k_merge  <<<dim3(1, B_), 256, 0, stream>>>(Zv, QND, DELm, GOm, dar, ear, 88);
  k_backt  <<<B_, 256, 0, stream>>>(A, Zv, dar, tauar, orgn, val32);

  // k_group consumes Zv/val32 BEFORE k_zero/k_fc overwrite the padded region.
  k_group  <<<dim3(T_, B_), 256, 0, stream>>>(Zv, val32, gum, grp);
  k_iszero <<<dim3(T_, B_),  64, 0, stream>>>(grp, mx, iz);
  k_slots  <<<B_,            64, 0, stream>>>(iz, slot, nkeep);
  k_zero   <<<dim3(T_, B_), 256, 0, stream>>>(nkeep, padded);
  k_fc     <<<dim3(T_, B_), 256, 0, stream>>>(grp, X, iz, slot, padded);
}

// Round 9
// 8847.337 us; speedup vs baseline: 2.1996x; 1.1209x over previous
//
#include <hip/hip_runtime.h>

// ---------------------------------------------------------------------------
// GMPool: distance-MLP -> grouping_M -> eigh (LAPACK ssyevd-faithful port) ->
// tau=1e-5 softmax Group -> per-group FC features -> packed output.
//
// R7 (PASS): f32 precision-path fidelity reproduces numpy's eigenvector signs.
// R8: dropped diagnostics; row-parallel Givens. k_merge still 2.58ms.
// R9: k_merge -> 1024 threads; secular solve wave-parallel (one root/wave,
//     lanes shuffle-reduce the f-sum); clock64 phase timers printed for
//     (b=0,mg=0) to attribute the remaining cost.
// ---------------------------------------------------------------------------

#define T_    176
#define B_    16
#define ROI_  116
#define HID_  200
#define NPAIR_ 6670
#define MATN  (T_*T_)          // 30976
#define PAD_ELEMS (B_*T_*NPAIR_)   // 75.1 MB of floats
#define EPS32F 5.9604644775390625e-8f
#define SAFMIN32F 1.17549435e-38f
#define MTH 1024

__device__ __forceinline__ double fsign(double a, double b){ return (b >= 0.0) ? fabs(a) : -fabs(a); }
__device__ __forceinline__ float fsignf_(float a, float b){ return (b >= 0.0f) ? fabsf(a) : -fabsf(a); }

__device__ __forceinline__ float slapy2f(float x, float y){
  float xa = fabsf(x), ya = fabsf(y);
  float w = fmaxf(xa, ya), z = fminf(xa, ya);
  if (z == 0.0f) return w;
  float q = z / w;
  return w * sqrtf(1.0f + q*q);
}

// LAPACK >=3.10 slartg, f32: c >= 0 always, r = sign(d, f)
__device__ __forceinline__ void lartgf_new(float f, float g, float* c, float* s, float* r){
  if (g == 0.0f){ *c = 1.0f; *s = 0.0f; *r = f; }
  else if (f == 0.0f){ *c = 0.0f; *s = (g >= 0.0f) ? 1.0f : -1.0f; *r = fabsf(g); }
  else {
    float d = sqrtf(f*f + g*g);
    *c = fabsf(f)/d;
    *r = fsignf_(d, f);
    *s = g/(*r);
  }
}

// LAPACK slaev2, f32 port
__device__ void laev2f(float a, float b, float c, float* rt1, float* rt2, float* cs1, float* sn1){
  float sm = a + c, df = a - c, adf = fabsf(df), tb = b + b, ab = fabsf(tb);
  float acmx, acmn;
  if (fabsf(a) > fabsf(c)){ acmx = a; acmn = c; } else { acmx = c; acmn = a; }
  float rt;
  if (adf > ab) rt = adf*sqrtf(1.0f + (ab/adf)*(ab/adf));
  else if (adf < ab) rt = ab*sqrtf(1.0f + (adf/ab)*(adf/ab));
  else rt = ab*sqrtf(2.0f);
  int sgn1;
  if (sm < 0.0f){ *rt1 = 0.5f*(sm - rt); sgn1 = -1; *rt2 = (acmx / *rt1)*acmn - (b / *rt1)*b; }
  else if (sm > 0.0f){ *rt1 = 0.5f*(sm + rt); sgn1 = 1; *rt2 = (acmx / *rt1)*acmn - (b / *rt1)*b; }
  else { *rt1 = 0.5f*rt; *rt2 = -0.5f*rt; sgn1 = 1; }
  float cs; int sgn2;
  if (df >= 0.0f){ cs = df + rt; sgn2 = 1; } else { cs = df - rt; sgn2 = -1; }
  float acs = fabsf(cs);
  if (acs > ab){ float ct = -tb/cs; float sn = 1.0f/sqrtf(1.0f + ct*ct); *sn1 = sn; *cs1 = ct*sn; }
  else {
    if (ab == 0.0f){ *cs1 = 1.0f; *sn1 = 0.0f; }
    else { float tn = -cs/tb; float c1 = 1.0f/sqrtf(1.0f + tn*tn); *cs1 = c1; *sn1 = tn*c1; }
  }
  if (sgn1 == sgn2){ float tn = *cs1; *cs1 = -(*sn1); *sn1 = tn; }
}

// ---------------------------------------------------------------------------
// K1: grouping_M.  block=(t,b), 256 thr.
// ---------------------------------------------------------------------------
__global__ __launch_bounds__(256) void k_gm(const float* __restrict__ X, const float* __restrict__ W1,
                                            const float* __restrict__ b1, const float* __restrict__ W2,
                                            const float* __restrict__ b2, float* __restrict__ gm){
  const int t = blockIdx.x, b = blockIdx.y, tid = threadIdx.x;
  __shared__ float4 w1p[29*200];
  __shared__ __align__(16) float dist[116];
  __shared__ float xt[116];
  __shared__ float b1s[200];
  __shared__ float w2s[200];
  __shared__ float wred[4];
  for (int li = tid; li < 29*200; li += 256){
    int j = li % 200, r4 = li / 200;
    const float* src = W1 + j*ROI_ + r4*4;
    w1p[li] = make_float4(src[0], src[1], src[2], src[3]);
  }
  for (int j = tid; j < 200; j += 256){ b1s[j] = b1[j]; w2s[j] = W2[j]; }
  if (tid < ROI_) xt[tid] = X[(size_t)(b*T_ + t)*ROI_ + tid];
  float b2v = b2[0];
  if (tid == 0) gm[(size_t)(b*T_ + t)*T_ + t] = 1.0f + 1e-7f;
  __syncthreads();
  for (int s = t + 1; s < T_; ++s){
    if (tid < ROI_){
      float xs = X[(size_t)(b*T_ + s)*ROI_ + tid];
      float df = xt[tid] - xs;
      dist[tid] = sqrtf(df*df + 1e-9f);
    }
    __syncthreads();
    float part = 0.f;
    if (tid < HID_){
      float acc = 0.f;
      const float4* dv4 = reinterpret_cast<const float4*>(dist);
      #pragma unroll
      for (int r4 = 0; r4 < 29; ++r4){
        float4 w = w1p[r4*200 + tid];
        float4 d4 = dv4[r4];
        acc += w.x*d4.x; acc += w.y*d4.y; acc += w.z*d4.z; acc += w.w*d4.w;
      }
      acc += b1s[tid];
      float h = fmaxf(acc, 0.f);
      part = w2s[tid]*h;
    }
    for (int off = 32; off > 0; off >>= 1) part += __shfl_down(part, off, 64);
    if ((tid & 63) == 0) wred[tid >> 6] = part;
    __syncthreads();
    if (tid == 0){
      float logit = wred[0] + wred[1] + wred[2] + wred[3] + b2v;
      float c = 1.0f/(1.0f + expf(-logit));
      float v = c + 1e-7f;
      gm[(size_t)(b*T_ + t)*T_ + s] = v;
      gm[(size_t)(b*T_ + s)*T_ + t] = v;
    }
    __syncthreads();
  }
}

__global__ void k_maxabs(const float* __restrict__ X, float* __restrict__ mx){
  int t = blockIdx.x, b = blockIdx.y, tid = threadIdx.x;
  float m = 0.f;
  for (int r = tid; r < ROI_; r += 64) m = fmaxf(m, fabsf(X[(size_t)(b*T_ + t)*ROI_ + r]));
  for (int off = 32; off > 0; off >>= 1) m = fmaxf(m, __shfl_down(m, off, 64));
  if (tid == 0) mx[b*T_ + t] = m;
}

// ---------------------------------------------------------------------------
// K2a: ssytd2 (lower) in f64, then f32-round d/e, sstedc scaling (f32),
// slaed0 tears (f32).
// ---------------------------------------------------------------------------
__global__ __launch_bounds__(256) void k_tridiag(const float* __restrict__ gm, double* __restrict__ Ab,
                                                 double* __restrict__ Zb, double* __restrict__ dar,
                                                 double* __restrict__ ear, double* __restrict__ tauar,
                                                 float* __restrict__ orgn){
  const int b = blockIdx.x, tid = threadIdx.x;
  double* A = Ab + (size_t)b*MATN;
  double* Z = Zb + (size_t)b*MATN;
  const float* gmb = gm + (size_t)b*MATN;
  __shared__ double vsh[T_], wsh[T_], red[256];
  for (int idx = tid; idx < MATN; idx += 256){ A[idx] = (double)gmb[idx]; Z[idx] = 0.0; }
  __syncthreads();
  for (int i = 0; i <= T_-2; ++i){
    int m = T_ - 1 - i;
    double alpha = A[(size_t)(i+1)*T_ + i];
    double part = 0.0;
    for (int r = i+2+tid; r < T_; r += 256){ double x = A[(size_t)r*T_ + i]; part += x*x; }
    red[tid] = part; __syncthreads();
    for (int o = 128; o > 0; o >>= 1){ if (tid < o) red[tid] += red[tid+o]; __syncthreads(); }
    double xnorm2 = red[0];
    __syncthreads();
    if (m == 1 || xnorm2 == 0.0){
      if (tid == 0){ tauar[b*T_ + i] = 0.0; ear[b*T_ + i] = alpha; }
      __syncthreads();
      continue;
    }
    double beta = -fsign(sqrt(alpha*alpha + xnorm2), alpha);
    double tau  = (beta - alpha)/beta;
    double sc   = 1.0/(alpha - beta);
    for (int r = i+2+tid; r < T_; r += 256) A[(size_t)r*T_ + i] *= sc;
    __syncthreads();
    for (int r = i+1+tid; r < T_; r += 256) vsh[r] = (r == i+1) ? 1.0 : A[(size_t)r*T_ + i];
    __syncthreads();
    for (int r = i+1+tid; r < T_; r += 256){
      double acc = 0.0;
      const double* Ar = A + (size_t)r*T_;
      for (int c = i+1; c < T_; ++c) acc += Ar[c]*vsh[c];
      wsh[r] = tau*acc;
    }
    __syncthreads();
    part = 0.0;
    for (int r = i+1+tid; r < T_; r += 256) part += wsh[r]*vsh[r];
    red[tid] = part; __syncthreads();
    for (int o = 128; o > 0; o >>= 1){ if (tid < o) red[tid] += red[tid+o]; __syncthreads(); }
    double a2 = -0.5*tau*red[0];
    __syncthreads();
    for (int r = i+1+tid; r < T_; r += 256) wsh[r] += a2*vsh[r];
    __syncthreads();
    for (int idx = tid; idx < m*m; idx += 256){
      int rr = i+1 + idx/m, cc = i+1 + idx%m;
      A[(size_t)rr*T_ + cc] -= vsh[rr]*wsh[cc] + wsh[rr]*vsh[cc];
    }
    if (tid == 0){ ear[b*T_ + i] = beta; tauar[b*T_ + i] = tau; }
    __syncthreads();
  }
  for (int j = tid; j < T_; j += 256) dar[b*T_ + j] = A[(size_t)j*T_ + j];
  __syncthreads();
  if (tid == 0){
    for (int j = 0; j < T_; ++j) dar[b*T_ + j] = (double)(float)dar[b*T_ + j];
    for (int j = 0; j < T_-1; ++j) ear[b*T_ + j] = (double)(float)ear[b*T_ + j];
    float og = 0.0f;
    for (int j = 0; j < T_; ++j) og = fmaxf(og, fabsf((float)dar[b*T_ + j]));
    for (int j = 0; j < T_-1; ++j) og = fmaxf(og, fabsf((float)ear[b*T_ + j]));
    for (int j = 0; j < T_; ++j) dar[b*T_ + j] = (double)(float)((float)dar[b*T_ + j]/og);
    for (int j = 0; j < T_-1; ++j) ear[b*T_ + j] = (double)(float)((float)ear[b*T_ + j]/og);
    orgn[b] = og;
    const int sp[7] = {21,43,65,87,109,131,153};
    for (int k = 0; k < 7; ++k){
      float ae = fabsf((float)ear[b*T_ + sp[k]]);
      dar[b*T_ + sp[k]]     = (double)((float)dar[b*T_ + sp[k]] - ae);
      dar[b*T_ + sp[k] + 1] = (double)((float)dar[b*T_ + sp[k] + 1] - ae);
    }
  }
}

// ---------------------------------------------------------------------------
// K2b: ssteqr('I') on 22x22 leaves, FULL f32 arithmetic. grid(8,16) x 64 thr.
// ---------------------------------------------------------------------------
__global__ __launch_bounds__(64) void k_leaf(double* __restrict__ Zb, double* __restrict__ dar,
                                             const double* __restrict__ ear){
  const int lf = blockIdx.x, b = blockIdx.y, tid = threadIdx.x;
  const int off = lf*22;
  double* Z = Zb + (size_t)b*MATN;
  __shared__ float ld_[22], le_[22];
  __shared__ float zl[22*22];
  __shared__ int perm_[22];
  for (int k = tid; k < 22; k += 64){
    ld_[k] = (float)dar[b*T_ + off + k];
    le_[k] = (k < 21) ? (float)ear[b*T_ + off + k] : 0.0f;
  }
  for (int idx = tid; idx < 484; idx += 64) zl[idx] = (idx/22 == idx%22) ? 1.0f : 0.0f;
  __syncthreads();
  const float eps = EPS32F, eps2 = EPS32F*EPS32F, safmin = SAFMIN32F;
  const int n = 22, nm1 = 21, nmaxit = 22*30;
  int jtot = 0, l1 = 0;
  while (l1 <= n-1){
    if (l1 > 0) le_[l1-1] = 0.0f;
    int msp = n-1;
    for (int mm2 = l1; mm2 < nm1; ++mm2){
      float tst = fabsf(le_[mm2]);
      if (tst == 0.0f){ msp = mm2; break; }
      if (tst <= (sqrtf(fabsf(ld_[mm2]))*sqrtf(fabsf(ld_[mm2+1])))*eps){
        le_[mm2] = 0.0f;
        msp = mm2; break;
      }
    }
    int l = l1, lend = msp;
    l1 = msp + 1;
    if (lend == l) continue;
    if (fabsf(ld_[lend]) < fabsf(ld_[l])){ int tmp = l; l = lend; lend = tmp; }
    if (lend > l){
      for (;;){ // QL
        int m2 = lend;
        if (l != lend){
          for (int k = l; k < lend; ++k){
            float tst = le_[k]*le_[k];
            if (tst <= (eps2*fabsf(ld_[k]))*fabsf(ld_[k+1]) + safmin){ m2 = k; break; }
          }
        }
        if (m2 < lend) le_[m2] = 0.0f;
        float p = ld_[l];
        if (m2 == l){ l++; if (l <= lend) continue; else break; }
        if (m2 == l+1){
          float rt1, rt2, c2, s2;
          laev2f(ld_[l], le_[l], ld_[l+1], &rt1, &rt2, &c2, &s2);
          if (tid < 22){
            float t0 = zl[tid*22 + l], t1 = zl[tid*22 + l+1];
            zl[tid*22 + l]   = c2*t0 + s2*t1;
            zl[tid*22 + l+1] = -s2*t0 + c2*t1;
          }
          ld_[l] = rt1; ld_[l+1] = rt2; le_[l] = 0.0f;
          l += 2;
          if (l <= lend) continue; else break;
        }
        if (jtot == nmaxit) break;
        jtot++;
        float g = (ld_[l+1] - p)/(2.0f*le_[l]);
        float r = slapy2f(g, 1.0f);
        g = ld_[m2] - p + le_[l]/(g + fsignf_(r, g));
        float s2 = 1.0f, c2 = 1.0f;
        p = 0.0f;
        for (int i = m2-1; i >= l; --i){
          float f2 = s2*le_[i];
          float bb = c2*le_[i];
          lartgf_new(g, f2, &c2, &s2, &r);
          if (i != m2-1) le_[i+1] = r;
          g = ld_[i+1] - p;
          r = (ld_[i] - g)*s2 + 2.0f*c2*bb;
          p = s2*r;
          ld_[i+1] = g + p;
          g = c2*r - bb;
          if (tid < 22){   // QL stores sn = -s
            float t0 = zl[tid*22 + i], t1 = zl[tid*22 + i+1];
            zl[tid*22 + i]   = c2*t0 - s2*t1;
            zl[tid*22 + i+1] = s2*t0 + c2*t1;
          }
        }
        ld_[l] -= p; le_[l] = g;
        if (l <= lend) continue; else break;
      }
    } else {
      for (;;){ // QR
        int m2 = lend;
        if (l != lend){
          for (int k = l; k > lend; --k){
            float tst = le_[k-1]*le_[k-1];
            if (tst <= (eps2*fabsf(ld_[k]))*fabsf(ld_[k-1]) + safmin){ m2 = k; break; }
          }
        }
        if (m2 > lend) le_[m2-1] = 0.0f;
        float p = ld_[l];
        if (m2 == l){ l--; if (l >= lend) continue; else break; }
        if (m2 == l-1){
          float rt1, rt2, c2, s2;
          laev2f(ld_[l-1], le_[l-1], ld_[l], &rt1, &rt2, &c2, &s2);
          if (tid < 22){
            float t0 = zl[tid*22 + l-1], t1 = zl[tid*22 + l];
            zl[tid*22 + l-1] = c2*t0 + s2*t1;
            zl[tid*22 + l]   = -s2*t0 + c2*t1;
          }
          ld_[l-1] = rt1; ld_[l] = rt2; le_[l-1] = 0.0f;
          l -= 2;
          if (l >= lend) continue; else break;
        }
        if (jtot == nmaxit) break;
        jtot++;
        float g = (ld_[l-1] - p)/(2.0f*le_[l-1]);
        float r = slapy2f(g, 1.0f);
        g = ld_[m2] - p + le_[l-1]/(g + fsignf_(r, g));
        float s2 = 1.0f, c2 = 1.0f;
        p = 0.0f;
        for (int i = m2; i <= l-1; ++i){
          float f2 = s2*le_[i];
          float bb = c2*le_[i];
          lartgf_new(g, f2, &c2, &s2, &r);
          if (i != m2) le_[i-1] = r;
          g = ld_[i] - p;
          r = (ld_[i+1] - g)*s2 + 2.0f*c2*bb;
          p = s2*r;
          ld_[i] = g + p;
          g = c2*r - bb;
          if (tid < 22){   // QR stores sn = +s
            float t0 = zl[tid*22 + i], t1 = zl[tid*22 + i+1];
            zl[tid*22 + i]   = c2*t0 + s2*t1;
            zl[tid*22 + i+1] = -s2*t0 + c2*t1;
          }
        }
        ld_[l] -= p; le_[l-1] = g;
        if (l >= lend) continue; else break;
      }
    }
  }
  __syncthreads();
  if (tid == 0){
    bool used[22]; for (int k = 0; k < 22; ++k) used[k] = false;
    for (int c = 0; c < 22; ++c){
      int best = -1; float bv = 0.0f;
      for (int k = 0; k < 22; ++k) if (!used[k] && (best < 0 || ld_[k] < bv)){ best = k; bv = ld_[k]; }
      used[best] = true; perm_[c] = best;
    }
  }
  __syncthreads();
  if (tid < 22){
    int r = tid;
    for (int c = 0; c < 22; ++c) Z[(size_t)(off + c)*T_ + (off + r)] = (double)zl[r*22 + perm_[c]];
  }
  for (int c = tid; c < 22; c += 64) dar[b*T_ + off + c] = (double)ld_[perm_[c]];
}

// ---------------------------------------------------------------------------
// K2c/d/e: one D&C merge (slaed1/2/3).  grid(nmerge,16) x 1024 thr.
// f32 deflation scan (serial, records Givens); rotations row-parallel;
// secular solve wave-parallel (one root per wave); z-hat/U/GEMM parallel.
// clock64 phase timers printed for (b=0, mg=0).
// ---------------------------------------------------------------------------
__global__ __launch_bounds__(MTH) void k_merge(double* __restrict__ Zb, double* __restrict__ QNDb,
                                               double* __restrict__ DELb, double* __restrict__ GOb,
                                               double* __restrict__ dar, const double* __restrict__ ear,
                                               int n1){
  const int b = blockIdx.y, mg = blockIdx.x, tid = threadIdx.x;
  const int wave = tid >> 6, lane = tid & 63;
  const int lo = mg*2*n1, n = 2*n1;
  double* Z   = Zb   + (size_t)b*MATN;
  double* Qnd = QNDb + (size_t)b*MATN;
  double* DEL = DELb + (size_t)b*MATN;
  double* GO  = GOb  + (size_t)b*MATN;
  double* dv  = dar + b*T_;
  __shared__ float frd[T_], frz[T_], fmd[T_], fmz[T_], fkd[T_], fkw[T_], fddf[T_], flam[T_], foval[T_];
  __shared__ double lam[T_], zh[T_], nrm[T_];
  __shared__ double rotc[T_], rots[T_];
  __shared__ int rotx[T_], roty[T_];
  __shared__ int mcol[T_], kcol[T_], dcol[T_], osrc[T_], indxp_[T_];
  __shared__ int sK, sND, sNROT;
  __shared__ double s_sumw2;
  __shared__ float s_rho;
  __shared__ unsigned long long tm[8];

  float rho0 = (float)ear[b*T_ + lo + n1 - 1];
  const float rs2f = 0.70710678118654752440f;
  for (int k = tid; k < n; k += MTH){
    frd[k] = (float)dv[lo + k];
    int row = (k < n1) ? (lo + n1 - 1) : (lo + n1);
    float zv = (float)Z[(size_t)(lo + k)*T_ + row];
    if (k >= n1 && rho0 < 0.0f) zv = -zv;
    frz[k] = zv*rs2f;
  }
  __syncthreads();
  if (tid == 0) tm[0] = clock64();
  if (tid == 0){
    float rho = fabsf(2.0f*rho0);
    s_rho = rho;
    int nrot = 0;
    int i1 = 0, i2 = n1, p = 0;
    while (i1 < n1 || i2 < n){
      bool t1;
      if (i1 >= n1) t1 = false;
      else if (i2 >= n) t1 = true;
      else t1 = (frd[i1] <= frd[i2]);
      int src = t1 ? i1++ : i2++;
      fmd[p] = frd[src]; fmz[p] = frz[src]; mcol[p] = src; p++;
    }
    float dmax = 0.0f, zmax = 0.0f;
    for (int k = 0; k < n; ++k){ dmax = fmaxf(dmax, fabsf(fmd[k])); zmax = fmaxf(zmax, fabsf(fmz[k])); }
    float tol = 8.0f*EPS32F*fmaxf(dmax, zmax);
    int K = 0, ND = 0;
    if (rho*zmax <= tol){               // full deflation
      for (int k = 0; k < n; ++k){ fddf[k] = fmd[k]; dcol[k] = mcol[k]; }
      ND = n; K = 0;
    } else {                            // slaed2 deflation scan (f32, INDXP port)
      int k2 = n;
      int j = 0, pj = -1;
      for (; j < n; ++j){
        if (rho*fabsf(fmz[j]) <= tol){ k2--; indxp_[k2] = j; }
        else { pj = j; break; }
      }
      if (pj >= 0){
        for (;;){
          j++;
          if (j >= n) break;
          int nj = j;
          if (rho*fabsf(fmz[nj]) <= tol){
            k2--; indxp_[k2] = nj;
          } else {
            float s_ = fmz[pj], c_ = fmz[nj];
            float tau_ = slapy2f(c_, s_);
            float t_ = fmd[nj] - fmd[pj];
            c_ = c_/tau_; s_ = -s_/tau_;
            if (fabsf((t_*c_)*s_) <= tol){
              fmz[nj] = tau_; fmz[pj] = 0.0f;
              rotx[nrot] = mcol[pj]; roty[nrot] = mcol[nj];
              rotc[nrot] = (double)c_; rots[nrot] = (double)s_;
              nrot++;
              float dt = fmd[pj]*(c_*c_) + fmd[nj]*(s_*s_);
              fmd[nj] = fmd[pj]*(s_*s_) + fmd[nj]*(c_*c_);
              fmd[pj] = dt;
              k2--;
              int i3 = 1;
              for (;;){
                if (k2 + i3 <= n - 1){
                  if (fmd[pj] < fmd[indxp_[k2 + i3]]){
                    indxp_[k2 + i3 - 1] = indxp_[k2 + i3];
                    indxp_[k2 + i3]     = pj;
                    i3++;
                  } else { indxp_[k2 + i3 - 1] = pj; break; }
                } else { indxp_[k2 + i3 - 1] = pj; break; }
              }
              pj = nj;
            } else {
              fkd[K] = fmd[pj]; fkw[K] = fmz[pj]; kcol[K] = mcol[pj]; K++;
              pj = nj;
            }
          }
        }
        fkd[K] = fmd[pj]; fkw[K] = fmz[pj]; kcol[K] = mcol[pj]; K++;
      }
      ND = n - K;
      for (int m2 = 0; m2 < ND; ++m2){
        int mi = indxp_[n - 1 - m2];
        fddf[m2] = fmd[mi]; dcol[m2] = mcol[mi];
      }
    }
    sK = K; sND = ND; sNROT = nrot;
    double sw = 0.0; for (int k = 0; k < K; ++k) sw += (double)fkw[k]*(double)fkw[k];
    s_sumw2 = sw;
  }
  __syncthreads();
  if (tid == 0) tm[1] = clock64();
  // apply recorded Givens rotations row-parallel
  {
    int nrot = sNROT;
    for (int r = tid; r < n; r += MTH){
      for (int q = 0; q < nrot; ++q){
        double* qx = Z + (size_t)(lo + rotx[q])*T_ + lo;
        double* qy = Z + (size_t)(lo + roty[q])*T_ + lo;
        double x = qx[r], y = qy[r];
        qx[r] = rotc[q]*x + rots[q]*y;
        qy[r] = rotc[q]*y - rots[q]*x;
      }
    }
  }
  __syncthreads();
  if (tid == 0) tm[2] = clock64();
  int K = sK, ND = sND;
  double rho_d = (double)s_rho;
  if (K > 0){
    // secular roots: wave-parallel (one root per wave; lanes split the f-sum)
    for (int j = wave; j < K; j += (MTH/64)){
      double dj = (double)fkd[j];
      double hi = (j < K-1) ? ((double)fkd[j+1] - dj) : (rho_d*s_sumw2 + 1e-300);
      if (hi < 0.0) hi = 0.0;
      double lo_t = 0.0, hi_t = hi;
      for (int it = 0; it < 70; ++it){
        double mid = 0.5*(lo_t + hi_t);
        if (mid == lo_t || mid == hi_t) break;
        double part = 0.0;
        for (int i2 = lane; i2 < K; i2 += 64){
          double dd2 = ((double)fkd[i2] - dj) - mid;
          part += (double)fkw[i2]*(double)fkw[i2]/dd2;
        }
        for (int o = 32; o > 0; o >>= 1) part += __shfl_down(part, o, 64);
        part = __shfl(part, 0, 64);
        double f = 1.0 + rho_d*part;
        if (f < 0.0) lo_t = mid; else hi_t = mid;
      }
      double tauj = 0.5*(lo_t + hi_t);
      if (tauj <= 0.0) tauj = (hi_t > 0.0) ? hi_t*0.5 : 1e-300;
      if (j < K-1){
        double hib = (double)fkd[j+1] - dj;
        if (tauj >= hib) tauj = nextafter(hib, 0.0);
      }
      if (lane == 0){ lam[j] = dj + tauj; flam[j] = (float)(dj + tauj); }
      double* Dj = DEL + (size_t)(lo + j)*T_;
      for (int i2 = lane; i2 < K; i2 += 64) Dj[i2] = ((double)fkd[i2] - dj) - tauj;
    }
    __syncthreads();
    if (tid == 0) tm[3] = clock64();
    // Gu z-hat (sequential product per i2 -> order preserved)
    for (int i2 = tid; i2 < K; i2 += MTH){
      double p = DEL[(size_t)(lo + i2)*T_ + i2];
      for (int j = 0; j < K; ++j){
        if (j == i2) continue;
        p *= DEL[(size_t)(lo + j)*T_ + i2]/((double)fkd[i2] - (double)fkd[j]);
      }
      zh[i2] = copysign(sqrt(fabs(p)), (double)fkw[i2]);
    }
    __syncthreads();
    for (int idx = tid; idx < K*K; idx += MTH){
      int j = idx/K, i2 = idx%K;
      double* pj = DEL + (size_t)(lo + j)*T_ + i2;
      *pj = zh[i2]/(*pj);
    }
    __syncthreads();
    for (int j = tid; j < K; j += MTH){
      double ss = 0.0;
      const double* Dj = DEL + (size_t)(lo + j)*T_;
      for (int i2 = 0; i2 < K; ++i2) ss += Dj[i2]*Dj[i2];
      nrm[j] = sqrt(ss);
    }
    __syncthreads();
    if (tid == 0) tm[4] = clock64();
    for (int idx = tid; idx < K*n; idx += MTH){
      int k2 = idx/n, rr = idx%n;
      Qnd[(size_t)(lo + k2)*T_ + rr] = Z[(size_t)(lo + kcol[k2])*T_ + (lo + rr)];
    }
  } else {
    if (tid == 0){ tm[3] = clock64(); tm[4] = tm[3]; }
  }
  for (int idx = tid; idx < ND*n; idx += MTH){
    int m2 = idx/n, rr = idx%n;
    GO[(size_t)(lo + K + m2)*T_ + rr] = Z[(size_t)(lo + dcol[m2])*T_ + (lo + rr)];
  }
  __syncthreads();
  if (tid == 0) tm[5] = clock64();
  if (K > 0){
    for (int idx = tid; idx < K*n; idx += MTH){
      int j = idx/n, rr = idx%n;
      double acc = 0.0;
      const double* Dj = DEL + (size_t)(lo + j)*T_;
      for (int i2 = 0; i2 < K; ++i2) acc += Qnd[(size_t)(lo + i2)*T_ + rr]*Dj[i2];
      GO[(size_t)(lo + j)*T_ + rr] = acc/nrm[j];
    }
  }
  __syncthreads();
  if (tid == 0) tm[6] = clock64();
  if (tid == 0){   // dlamrg(K, ND, stride -1): f32 comparisons, tie -> lam
    int i1 = 0, i2 = 0, p = 0;
    while (i1 < K || i2 < ND){
      bool t1;
      if (i1 >= K) t1 = false;
      else if (i2 >= ND) t1 = true;
      else t1 = (flam[i1] <= fddf[i2]);
      if (t1){ foval[p] = flam[i1]; osrc[p] = i1; i1++; }
      else { foval[p] = fddf[i2]; osrc[p] = K + i2; i2++; }
      p++;
    }
  }
  __syncthreads();
  for (int idx = tid; idx < n*n; idx += MTH){
    int p2 = idx/n, rr = idx%n;
    Z[(size_t)(lo + p2)*T_ + (lo + rr)] = GO[(size_t)(lo + osrc[p2])*T_ + rr];
  }
  for (int p2 = tid; p2 < n; p2 += MTH) dv[lo + p2] = (double)foval[p2];
  __syncthreads();
  if (tid == 0 && b == 0 && mg == 0){
    unsigned long long t7 = clock64();
    printf("[TMR] n=%d K=%d scan=%llu rot=%llu sec=%llu zhU=%llu gath=%llu gemm=%llu tail=%llu\n",
           n, sK, tm[1]-tm[0], tm[2]-tm[1], tm[3]-tm[2], tm[4]-tm[3], tm[5]-tm[4], tm[6]-tm[5], t7-tm[6]);
  }
}

// ---------------------------------------------------------------------------
// K2f: back-transform Z <- Q*Z + val32 = f32(lambda) * orgnrm
// ---------------------------------------------------------------------------
__global__ __launch_bounds__(256) void k_backt(const double* __restrict__ Ab, double* __restrict__ Zb,
                                               const double* __restrict__ dar, const double* __restrict__ tauar,
                                               const float* __restrict__ orgn, float* __restrict__ val32){
  const int b = blockIdx.x, tid = threadIdx.x;
  const double* A = Ab + (size_t)b*MATN;
  double* Z = Zb + (size_t)b*MATN;
  __shared__ double vsh[T_];
  for (int i = T_-2; i >= 0; --i){
    double tau = tauar[b*T_ + i];
    if (tau != 0.0){
      for (int r = i+1+tid; r < T_; r += 256) vsh[r] = (r == i+1) ? 1.0 : A[(size_t)r*T_ + i];
      __syncthreads();
      for (int c = tid; c < T_; c += 256){
        double* Zc = Z + (size_t)c*T_;
        double w = 0.0;
        for (int r = i+1; r < T_; ++r) w += vsh[r]*Zc[r];
        w *= tau;
        for (int r = i+1; r < T_; ++r) Zc[r] -= w*vsh[r];
      }
      __syncthreads();
    }
  }
  float og = orgn[b];
  for (int j = tid; j < T_; j += 256) val32[b*T_ + j] = (float)dar[b*T_ + j] * og;
}

// ---------------------------------------------------------------------------
// K3: Group softmax (f32 op order as ref).
// ---------------------------------------------------------------------------
__global__ __launch_bounds__(256) void k_group(const double* __restrict__ Zb, const float* __restrict__ val32,
                                               const float* __restrict__ gum, float* __restrict__ grp){
  const int t = blockIdx.x, b = blockIdx.y, tid = threadIdx.x;
  const double* Z = Zb + (size_t)b*MATN;
  __shared__ float sred[256];
  float y = -3.4e38f;
  if (tid < T_){
    float vd = val32[b*T_ + (T_-1 - tid)];
    float dc = (vd <= 0.f) ? 1e-7f : vd;
    float dj = sqrtf(dc);
    float v = (float)Z[(size_t)tid*T_ + t];
    float S = v*dj;
    y = (S + gum[((size_t)b*T_ + t)*T_ + tid])/1e-5f;
  }
  sred[tid] = y; __syncthreads();
  for (int o = 128; o > 0; o >>= 1){ if (tid < o) sred[tid] = fmaxf(sred[tid], sred[tid+o]); __syncthreads(); }
  float ym = sred[0]; __syncthreads();
  float e = (tid < T_) ? expf(y - ym) : 0.f;
  sred[tid] = e; __syncthreads();
  for (int o = 128; o > 0; o >>= 1){ if (tid < o) sred[tid] += sred[tid+o]; __syncthreads(); }
  float se = sred[0];
  if (tid < T_) grp[((size_t)b*T_ + t)*T_ + tid] = e/se;
}

__global__ void k_iszero(const float* __restrict__ grp, const float* __restrict__ mx, int* __restrict__ iz){
  int g = blockIdx.x, b = blockIdx.y, tid = threadIdx.x;
  bool nz = false;
  for (int t2 = tid; t2 < T_; t2 += 64){
    float w = grp[((size_t)b*T_ + t2)*T_ + g];
    if (w != 0.f){
      double p = fabs((double)w)*(double)mx[b*T_ + t2];
      if (p > 0x1.0p-150) nz = true;
    }
  }
  unsigned long long bal = __ballot(nz);
  if (tid == 0) iz[b*T_ + g] = (bal == 0ull) ? 1 : 0;
}

__global__ void k_slots(const int* __restrict__ iz, int* __restrict__ slot, int* __restrict__ nkeep){
  int b = blockIdx.x;
  if (threadIdx.x == 0){
    int c = 0;
    for (int g = 0; g < T_; ++g){
      if (!iz[b*T_ + g]) slot[b*T_ + g] = c++;
      else slot[b*T_ + g] = -1;
    }
    nkeep[b] = c;
  }
}

__global__ __launch_bounds__(256) void k_zero(const int* __restrict__ nkeep, float* __restrict__ padded){
  int k = blockIdx.x, b = blockIdx.y, tid = threadIdx.x;
  if (k < nkeep[b]) return;
  float* dst = padded + ((size_t)b*T_ + k)*NPAIR_;
  for (int p = tid; p < NPAIR_; p += 256) dst[p] = 0.f;
}

__global__ __launch_bounds__(256) void k_fc(const float* __restrict__ grp, const float* __restrict__ X,
                                            const int* __restrict__ iz, const int* __restrict__ slot,
                                            float* __restrict__ padded){
  const int g = blockIdx.x, b = blockIdx.y, tid = threadIdx.x;
  if (iz[b*T_ + g]) return;
  __shared__ float wcol[T_];
  __shared__ int tl[T_];
  __shared__ int scnt;
  __shared__ double mm[ROI_], inv[ROI_];
  for (int t2 = tid; t2 < T_; t2 += 256) wcol[t2] = grp[((size_t)b*T_ + t2)*T_ + g];
  __syncthreads();
  if (tid == 0){
    int c = 0;
    for (int t2 = 0; t2 < T_; ++t2) if (wcol[t2] != 0.f) tl[c++] = t2;
    scnt = c;
  }
  __syncthreads();
  int cnt = scnt;
  for (int i = tid; i < ROI_; i += 256){
    double A = 0.0, Q = 0.0;
    for (int k = 0; k < cnt; ++k){
      int t2 = tl[k];
      double wx = (double)wcol[t2]*(double)X[((size_t)b*T_ + t2)*ROI_ + i];
      A += wx; Q += wx*wx;
    }
    double m2 = A/176.0;
    double var = (Q - 176.0*m2*m2)/175.0;
    double sd = sqrt(fmax(var, 0.0));
    mm[i] = m2; inv[i] = 1.0/(sd + 1e-7);
  }
  __syncthreads();
  int outrow = slot[b*T_ + g];
  float* dst = padded + ((size_t)b*T_ + outrow)*NPAIR_;
  for (int p = tid; p < NPAIR_; p += 256){
    int i = (int)(115.5 - sqrt(115.5*115.5 - 2.0*(double)p));
    if (i < 0) i = 0;
    while ((i+1)*115 - ((i+1)*i)/2 <= p) ++i;
    while (i*115 - (i*(i-1))/2 > p) --i;
    int off = i*115 - (i*(i-1))/2;
    int j = i + 1 + (p - off);
    double q = 0.0;
    for (int k = 0; k < cnt; ++k){
      int t2 = tl[k];
      double w = (double)wcol[t2];
      const float* Xr = X + ((size_t)b*T_ + t2)*ROI_;
      q += (w*(double)Xr[i])*(w*(double)Xr[j]);
    }
    double fc = (q - 176.0*mm[i]*mm[j])*inv[i]*inv[j]/175.0;
    dst[p] = (float)fc;
  }
}

// ---------------------------------------------------------------------------
extern "C" void kernel_launch(void* const* d_in, const int* in_sizes, int n_in,
                              void* d_out, int out_size, void* d_ws, size_t ws_size,
                              hipStream_t stream){
  (void)in_sizes; (void)n_in; (void)out_size; (void)ws_size;
  const float* X   = (const float*)d_in[0];
  const float* W1  = (const float*)d_in[1];
  const float* b1  = (const float*)d_in[2];
  const float* W2  = (const float*)d_in[3];
  const float* b2  = (const float*)d_in[4];
  const float* gum = (const float*)d_in[5];

  float* out    = (float*)d_out;
  float* padded = out;                          // [B, 176, 6670]
  float* gm     = out + (size_t)PAD_ELEMS;      // [B, 176, 176]
  float* grp    = gm  + (size_t)B_*T_*T_;       // [B, 176, 176]

  // Eigh scratch in the padded region (consumed BEFORE padded is written).
  double* MATS = (double*)d_out;
  const size_t MS = (size_t)MATN;
  double* A    = MATS;            // 16 mats
  double* Zv   = MATS + 16*MS;    // 16
  double* QND  = MATS + 32*MS;    // 16
  double* DELm = MATS + 48*MS;    // 16
  double* GOm  = MATS + 64*MS;    // 16
  double* aux  = MATS + 80*MS;
  const int NBT = B_*T_;
  double* dar   = aux;            double* ear = dar + NBT;  double* tauar = ear + NBT;
  float* fs     = (float*)(tauar + NBT);
  float* val32  = fs;             float* mx = val32 + NBT;  float* orgn = mx + NBT;
  // Arrays read DURING padded writes live in d_ws (survive k_zero/k_fc).
  int* iz    = (int*)d_ws;
  int* slot  = iz + NBT;
  int* nkeep = slot + NBT;

  k_gm     <<<dim3(T_, B_), 256, 0, stream>>>(X, W1, b1, W2, b2, gm);
  k_maxabs <<<dim3(T_, B_),  64, 0, stream>>>(X, mx);

  k_tridiag<<<B_, 256, 0, stream>>>(gm, A, Zv, dar, ear, tauar, orgn);
  k_leaf   <<<dim3(8, B_), 64, 0, stream>>>(Zv, dar, ear);
  k_merge  <<<dim3(4, B_), MTH, 0, stream>>>(Zv, QND, DELm, GOm, dar, ear, 22);
  k_merge  <<<dim3(2, B_), MTH, 0, stream>>>(Zv, QND, DELm, GOm, dar, ear, 44);
  k_merge  <<<dim3(1, B_), MTH, 0, stream>>>(Zv, QND, DELm, GOm, dar, ear, 88);
  k_backt  <<<B_, 256, 0, stream>>>(A, Zv, dar, tauar, orgn, val32);

  // k_group consumes Zv/val32 BEFORE k_zero/k_fc overwrite the padded region.
  k_group  <<<dim3(T_, B_), 256, 0, stream>>>(Zv, val32, gum, grp);
  k_iszero <<<dim3(T_, B_),  64, 0, stream>>>(grp, mx, iz);
  k_slots  <<<B_,            64, 0, stream>>>(iz, slot, nkeep);
  k_zero   <<<dim3(T_, B_), 256, 0, stream>>>(nkeep, padded);
  k_fc     <<<dim3(T_, B_), 256, 0, stream>>>(grp, X, iz, slot, padded);
}

// Round 10
// 5290.046 us; speedup vs baseline: 3.6787x; 1.6724x over previous
//
#include <hip/hip_runtime.h>

// ---------------------------------------------------------------------------
// GMPool: distance-MLP -> grouping_M -> eigh (LAPACK ssyevd-faithful port) ->
// tau=1e-5 softmax Group -> per-group FC features -> packed output.
//
// R7 (PASS): f32 precision-path fidelity reproduces numpy's eigenvector signs.
// R8/R9: k_merge parallelized (row-parallel Givens, wave-parallel secular).
// R10: k_backt -> 176 blocks (16 batches x 11 col-chunks), 16 thr/column
//      shuffle-reduced dots; k_tridiag -> 1024 thr, shuffle+LDS reductions,
//      4-lane-per-row matvec; k_merge timers removed.
// f64 phases may reorder sums (1e-16 perturbation, decision-safe); the f32
// decision path (leaves + deflation scan) remains bit-exact.
// ---------------------------------------------------------------------------

#define T_    176
#define B_    16
#define ROI_  116
#define HID_  200
#define NPAIR_ 6670
#define MATN  (T_*T_)          // 30976
#define PAD_ELEMS (B_*T_*NPAIR_)   // 75.1 MB of floats
#define EPS32F 5.9604644775390625e-8f
#define SAFMIN32F 1.17549435e-38f
#define MTH 1024
#define TTH 1024

__device__ __forceinline__ double fsign(double a, double b){ return (b >= 0.0) ? fabs(a) : -fabs(a); }
__device__ __forceinline__ float fsignf_(float a, float b){ return (b >= 0.0f) ? fabsf(a) : -fabsf(a); }

__device__ __forceinline__ float slapy2f(float x, float y){
  float xa = fabsf(x), ya = fabsf(y);
  float w = fmaxf(xa, ya), z = fminf(xa, ya);
  if (z == 0.0f) return w;
  float q = z / w;
  return w * sqrtf(1.0f + q*q);
}

// LAPACK >=3.10 slartg, f32: c >= 0 always, r = sign(d, f)
__device__ __forceinline__ void lartgf_new(float f, float g, float* c, float* s, float* r){
  if (g == 0.0f){ *c = 1.0f; *s = 0.0f; *r = f; }
  else if (f == 0.0f){ *c = 0.0f; *s = (g >= 0.0f) ? 1.0f : -1.0f; *r = fabsf(g); }
  else {
    float d = sqrtf(f*f + g*g);
    *c = fabsf(f)/d;
    *r = fsignf_(d, f);
    *s = g/(*r);
  }
}

// LAPACK slaev2, f32 port
__device__ void laev2f(float a, float b, float c, float* rt1, float* rt2, float* cs1, float* sn1){
  float sm = a + c, df = a - c, adf = fabsf(df), tb = b + b, ab = fabsf(tb);
  float acmx, acmn;
  if (fabsf(a) > fabsf(c)){ acmx = a; acmn = c; } else { acmx = c; acmn = a; }
  float rt;
  if (adf > ab) rt = adf*sqrtf(1.0f + (ab/adf)*(ab/adf));
  else if (adf < ab) rt = ab*sqrtf(1.0f + (adf/ab)*(adf/ab));
  else rt = ab*sqrtf(2.0f);
  int sgn1;
  if (sm < 0.0f){ *rt1 = 0.5f*(sm - rt); sgn1 = -1; *rt2 = (acmx / *rt1)*acmn - (b / *rt1)*b; }
  else if (sm > 0.0f){ *rt1 = 0.5f*(sm + rt); sgn1 = 1; *rt2 = (acmx / *rt1)*acmn - (b / *rt1)*b; }
  else { *rt1 = 0.5f*rt; *rt2 = -0.5f*rt; sgn1 = 1; }
  float cs; int sgn2;
  if (df >= 0.0f){ cs = df + rt; sgn2 = 1; } else { cs = df - rt; sgn2 = -1; }
  float acs = fabsf(cs);
  if (acs > ab){ float ct = -tb/cs; float sn = 1.0f/sqrtf(1.0f + ct*ct); *sn1 = sn; *cs1 = ct*sn; }
  else {
    if (ab == 0.0f){ *cs1 = 1.0f; *sn1 = 0.0f; }
    else { float tn = -cs/tb; float c1 = 1.0f/sqrtf(1.0f + tn*tn); *cs1 = c1; *sn1 = tn*c1; }
  }
  if (sgn1 == sgn2){ float tn = *cs1; *cs1 = -(*sn1); *sn1 = tn; }
}

// ---------------------------------------------------------------------------
// K1: grouping_M.  block=(t,b), 256 thr.
// ---------------------------------------------------------------------------
__global__ __launch_bounds__(256) void k_gm(const float* __restrict__ X, const float* __restrict__ W1,
                                            const float* __restrict__ b1, const float* __restrict__ W2,
                                            const float* __restrict__ b2, float* __restrict__ gm){
  const int t = blockIdx.x, b = blockIdx.y, tid = threadIdx.x;
  __shared__ float4 w1p[29*200];
  __shared__ __align__(16) float dist[116];
  __shared__ float xt[116];
  __shared__ float b1s[200];
  __shared__ float w2s[200];
  __shared__ float wred[4];
  for (int li = tid; li < 29*200; li += 256){
    int j = li % 200, r4 = li / 200;
    const float* src = W1 + j*ROI_ + r4*4;
    w1p[li] = make_float4(src[0], src[1], src[2], src[3]);
  }
  for (int j = tid; j < 200; j += 256){ b1s[j] = b1[j]; w2s[j] = W2[j]; }
  if (tid < ROI_) xt[tid] = X[(size_t)(b*T_ + t)*ROI_ + tid];
  float b2v = b2[0];
  if (tid == 0) gm[(size_t)(b*T_ + t)*T_ + t] = 1.0f + 1e-7f;
  __syncthreads();
  for (int s = t + 1; s < T_; ++s){
    if (tid < ROI_){
      float xs = X[(size_t)(b*T_ + s)*ROI_ + tid];
      float df = xt[tid] - xs;
      dist[tid] = sqrtf(df*df + 1e-9f);
    }
    __syncthreads();
    float part = 0.f;
    if (tid < HID_){
      float acc = 0.f;
      const float4* dv4 = reinterpret_cast<const float4*>(dist);
      #pragma unroll
      for (int r4 = 0; r4 < 29; ++r4){
        float4 w = w1p[r4*200 + tid];
        float4 d4 = dv4[r4];
        acc += w.x*d4.x; acc += w.y*d4.y; acc += w.z*d4.z; acc += w.w*d4.w;
      }
      acc += b1s[tid];
      float h = fmaxf(acc, 0.f);
      part = w2s[tid]*h;
    }
    for (int off = 32; off > 0; off >>= 1) part += __shfl_down(part, off, 64);
    if ((tid & 63) == 0) wred[tid >> 6] = part;
    __syncthreads();
    if (tid == 0){
      float logit = wred[0] + wred[1] + wred[2] + wred[3] + b2v;
      float c = 1.0f/(1.0f + expf(-logit));
      float v = c + 1e-7f;
      gm[(size_t)(b*T_ + t)*T_ + s] = v;
      gm[(size_t)(b*T_ + s)*T_ + t] = v;
    }
    __syncthreads();
  }
}

__global__ void k_maxabs(const float* __restrict__ X, float* __restrict__ mx){
  int t = blockIdx.x, b = blockIdx.y, tid = threadIdx.x;
  float m = 0.f;
  for (int r = tid; r < ROI_; r += 64) m = fmaxf(m, fabsf(X[(size_t)(b*T_ + t)*ROI_ + r]));
  for (int off = 32; off > 0; off >>= 1) m = fmaxf(m, __shfl_down(m, off, 64));
  if (tid == 0) mx[b*T_ + t] = m;
}

// ---------------------------------------------------------------------------
// K2a: ssytd2 (lower) in f64 (1024 thr, shuffle+LDS reductions), then
// f32-round d/e, sstedc scaling (f32), slaed0 tears (f32).
// ---------------------------------------------------------------------------
__global__ __launch_bounds__(TTH) void k_tridiag(const float* __restrict__ gm, double* __restrict__ Ab,
                                                 double* __restrict__ Zb, double* __restrict__ dar,
                                                 double* __restrict__ ear, double* __restrict__ tauar,
                                                 float* __restrict__ orgn){
  const int b = blockIdx.x, tid = threadIdx.x;
  const int lane = tid & 63, wv = tid >> 6;      // 16 waves
  double* A = Ab + (size_t)b*MATN;
  double* Z = Zb + (size_t)b*MATN;
  const float* gmb = gm + (size_t)b*MATN;
  __shared__ double vsh[T_], wsh[T_], wred[16];
  __shared__ double s_res;
  for (int idx = tid; idx < MATN; idx += TTH){ A[idx] = (double)gmb[idx]; Z[idx] = 0.0; }
  __syncthreads();
  for (int i = 0; i <= T_-2; ++i){
    int m = T_ - 1 - i;
    double alpha = A[(size_t)(i+1)*T_ + i];
    // xnorm2 = sum of squares below subdiagonal
    double part = 0.0;
    for (int r = i+2+tid; r < T_; r += TTH){ double x = A[(size_t)r*T_ + i]; part += x*x; }
    for (int o = 32; o > 0; o >>= 1) part += __shfl_down(part, o, 64);
    if (lane == 0) wred[wv] = part;
    __syncthreads();
    if (tid == 0){ double s = 0.0; for (int k = 0; k < 16; ++k) s += wred[k]; s_res = s; }
    __syncthreads();
    double xnorm2 = s_res;
    if (m == 1 || xnorm2 == 0.0){
      if (tid == 0){ tauar[b*T_ + i] = 0.0; ear[b*T_ + i] = alpha; }
      __syncthreads();
      continue;
    }
    double beta = -fsign(sqrt(alpha*alpha + xnorm2), alpha);
    double tau  = (beta - alpha)/beta;
    double sc   = 1.0/(alpha - beta);
    for (int r = i+2+tid; r < T_; r += TTH) A[(size_t)r*T_ + i] *= sc;
    __syncthreads();
    for (int r = i+1+tid; r < T_; r += TTH) vsh[r] = (r == i+1) ? 1.0 : A[(size_t)r*T_ + i];
    __syncthreads();
    // matvec wsh = tau * A(i+1:,i+1:) * v : 4 sub-lanes per row (m*4 <= 700)
    if (tid < m*4){
      int r = i+1 + (tid >> 2), sub = tid & 3;
      double acc = 0.0;
      const double* Ar = A + (size_t)r*T_;
      for (int c = i+1+sub; c < T_; c += 4) acc += Ar[c]*vsh[c];
      acc += __shfl_xor(acc, 2, 4);
      acc += __shfl_xor(acc, 1, 4);
      if (sub == 0) wsh[r] = tau*acc;
    }
    __syncthreads();
    // dot(w, v)
    part = 0.0;
    for (int r = i+1+tid; r < T_; r += TTH) part += wsh[r]*vsh[r];
    for (int o = 32; o > 0; o >>= 1) part += __shfl_down(part, o, 64);
    if (lane == 0) wred[wv] = part;
    __syncthreads();
    if (tid == 0){ double s = 0.0; for (int k = 0; k < 16; ++k) s += wred[k]; s_res = s; }
    __syncthreads();
    double a2 = -0.5*tau*s_res;
    for (int r = i+1+tid; r < T_; r += TTH) wsh[r] += a2*vsh[r];
    __syncthreads();
    for (int idx = tid; idx < m*m; idx += TTH){
      int rr = i+1 + idx/m, cc = i+1 + idx%m;
      A[(size_t)rr*T_ + cc] -= vsh[rr]*wsh[cc] + wsh[rr]*vsh[cc];
    }
    if (tid == 0){ ear[b*T_ + i] = beta; tauar[b*T_ + i] = tau; }
    __syncthreads();
  }
  for (int j = tid; j < T_; j += TTH) dar[b*T_ + j] = A[(size_t)j*T_ + j];
  __syncthreads();
  if (tid == 0){
    for (int j = 0; j < T_; ++j) dar[b*T_ + j] = (double)(float)dar[b*T_ + j];
    for (int j = 0; j < T_-1; ++j) ear[b*T_ + j] = (double)(float)ear[b*T_ + j];
    float og = 0.0f;
    for (int j = 0; j < T_; ++j) og = fmaxf(og, fabsf((float)dar[b*T_ + j]));
    for (int j = 0; j < T_-1; ++j) og = fmaxf(og, fabsf((float)ear[b*T_ + j]));
    for (int j = 0; j < T_; ++j) dar[b*T_ + j] = (double)(float)((float)dar[b*T_ + j]/og);
    for (int j = 0; j < T_-1; ++j) ear[b*T_ + j] = (double)(float)((float)ear[b*T_ + j]/og);
    orgn[b] = og;
    const int sp[7] = {21,43,65,87,109,131,153};
    for (int k = 0; k < 7; ++k){
      float ae = fabsf((float)ear[b*T_ + sp[k]]);
      dar[b*T_ + sp[k]]     = (double)((float)dar[b*T_ + sp[k]] - ae);
      dar[b*T_ + sp[k] + 1] = (double)((float)dar[b*T_ + sp[k] + 1] - ae);
    }
  }
}

// ---------------------------------------------------------------------------
// K2b: ssteqr('I') on 22x22 leaves, FULL f32 arithmetic. grid(8,16) x 64 thr.
// ---------------------------------------------------------------------------
__global__ __launch_bounds__(64) void k_leaf(double* __restrict__ Zb, double* __restrict__ dar,
                                             const double* __restrict__ ear){
  const int lf = blockIdx.x, b = blockIdx.y, tid = threadIdx.x;
  const int off = lf*22;
  double* Z = Zb + (size_t)b*MATN;
  __shared__ float ld_[22], le_[22];
  __shared__ float zl[22*22];
  __shared__ int perm_[22];
  for (int k = tid; k < 22; k += 64){
    ld_[k] = (float)dar[b*T_ + off + k];
    le_[k] = (k < 21) ? (float)ear[b*T_ + off + k] : 0.0f;
  }
  for (int idx = tid; idx < 484; idx += 64) zl[idx] = (idx/22 == idx%22) ? 1.0f : 0.0f;
  __syncthreads();
  const float eps = EPS32F, eps2 = EPS32F*EPS32F, safmin = SAFMIN32F;
  const int n = 22, nm1 = 21, nmaxit = 22*30;
  int jtot = 0, l1 = 0;
  while (l1 <= n-1){
    if (l1 > 0) le_[l1-1] = 0.0f;
    int msp = n-1;
    for (int mm2 = l1; mm2 < nm1; ++mm2){
      float tst = fabsf(le_[mm2]);
      if (tst == 0.0f){ msp = mm2; break; }
      if (tst <= (sqrtf(fabsf(ld_[mm2]))*sqrtf(fabsf(ld_[mm2+1])))*eps){
        le_[mm2] = 0.0f;
        msp = mm2; break;
      }
    }
    int l = l1, lend = msp;
    l1 = msp + 1;
    if (lend == l) continue;
    if (fabsf(ld_[lend]) < fabsf(ld_[l])){ int tmp = l; l = lend; lend = tmp; }
    if (lend > l){
      for (;;){ // QL
        int m2 = lend;
        if (l != lend){
          for (int k = l; k < lend; ++k){
            float tst = le_[k]*le_[k];
            if (tst <= (eps2*fabsf(ld_[k]))*fabsf(ld_[k+1]) + safmin){ m2 = k; break; }
          }
        }
        if (m2 < lend) le_[m2] = 0.0f;
        float p = ld_[l];
        if (m2 == l){ l++; if (l <= lend) continue; else break; }
        if (m2 == l+1){
          float rt1, rt2, c2, s2;
          laev2f(ld_[l], le_[l], ld_[l+1], &rt1, &rt2, &c2, &s2);
          if (tid < 22){
            float t0 = zl[tid*22 + l], t1 = zl[tid*22 + l+1];
            zl[tid*22 + l]   = c2*t0 + s2*t1;
            zl[tid*22 + l+1] = -s2*t0 + c2*t1;
          }
          ld_[l] = rt1; ld_[l+1] = rt2; le_[l] = 0.0f;
          l += 2;
          if (l <= lend) continue; else break;
        }
        if (jtot == nmaxit) break;
        jtot++;
        float g = (ld_[l+1] - p)/(2.0f*le_[l]);
        float r = slapy2f(g, 1.0f);
        g = ld_[m2] - p + le_[l]/(g + fsignf_(r, g));
        float s2 = 1.0f, c2 = 1.0f;
        p = 0.0f;
        for (int i = m2-1; i >= l; --i){
          float f2 = s2*le_[i];
          float bb = c2*le_[i];
          lartgf_new(g, f2, &c2, &s2, &r);
          if (i != m2-1) le_[i+1] = r;
          g = ld_[i+1] - p;
          r = (ld_[i] - g)*s2 + 2.0f*c2*bb;
          p = s2*r;
          ld_[i+1] = g + p;
          g = c2*r - bb;
          if (tid < 22){   // QL stores sn = -s
            float t0 = zl[tid*22 + i], t1 = zl[tid*22 + i+1];
            zl[tid*22 + i]   = c2*t0 - s2*t1;
            zl[tid*22 + i+1] = s2*t0 + c2*t1;
          }
        }
        ld_[l] -= p; le_[l] = g;
        if (l <= lend) continue; else break;
      }
    } else {
      for (;;){ // QR
        int m2 = lend;
        if (l != lend){
          for (int k = l; k > lend; --k){
            float tst = le_[k-1]*le_[k-1];
            if (tst <= (eps2*fabsf(ld_[k]))*fabsf(ld_[k-1]) + safmin){ m2 = k; break; }
          }
        }
        if (m2 > lend) le_[m2-1] = 0.0f;
        float p = ld_[l];
        if (m2 == l){ l--; if (l >= lend) continue; else break; }
        if (m2 == l-1){
          float rt1, rt2, c2, s2;
          laev2f(ld_[l-1], le_[l-1], ld_[l], &rt1, &rt2, &c2, &s2);
          if (tid < 22){
            float t0 = zl[tid*22 + l-1], t1 = zl[tid*22 + l];
            zl[tid*22 + l-1] = c2*t0 + s2*t1;
            zl[tid*22 + l]   = -s2*t0 + c2*t1;
          }
          ld_[l-1] = rt1; ld_[l] = rt2; le_[l-1] = 0.0f;
          l -= 2;
          if (l >= lend) continue; else break;
        }
        if (jtot == nmaxit) break;
        jtot++;
        float g = (ld_[l-1] - p)/(2.0f*le_[l-1]);
        float r = slapy2f(g, 1.0f);
        g = ld_[m2] - p + le_[l-1]/(g + fsignf_(r, g));
        float s2 = 1.0f, c2 = 1.0f;
        p = 0.0f;
        for (int i = m2; i <= l-1; ++i){
          float f2 = s2*le_[i];
          float bb = c2*le_[i];
          lartgf_new(g, f2, &c2, &s2, &r);
          if (i != m2) le_[i-1] = r;
          g = ld_[i] - p;
          r = (ld_[i+1] - g)*s2 + 2.0f*c2*bb;
          p = s2*r;
          ld_[i] = g + p;
          g = c2*r - bb;
          if (tid < 22){   // QR stores sn = +s
            float t0 = zl[tid*22 + i], t1 = zl[tid*22 + i+1];
            zl[tid*22 + i]   = c2*t0 + s2*t1;
            zl[tid*22 + i+1] = -s2*t0 + c2*t1;
          }
        }
        ld_[l] -= p; le_[l-1] = g;
        if (l >= lend) continue; else break;
      }
    }
  }
  __syncthreads();
  if (tid == 0){
    bool used[22]; for (int k = 0; k < 22; ++k) used[k] = false;
    for (int c = 0; c < 22; ++c){
      int best = -1; float bv = 0.0f;
      for (int k = 0; k < 22; ++k) if (!used[k] && (best < 0 || ld_[k] < bv)){ best = k; bv = ld_[k]; }
      used[best] = true; perm_[c] = best;
    }
  }
  __syncthreads();
  if (tid < 22){
    int r = tid;
    for (int c = 0; c < 22; ++c) Z[(size_t)(off + c)*T_ + (off + r)] = (double)zl[r*22 + perm_[c]];
  }
  for (int c = tid; c < 22; c += 64) dar[b*T_ + off + c] = (double)ld_[perm_[c]];
}

// ---------------------------------------------------------------------------
// K2c/d/e: one D&C merge (slaed1/2/3).  grid(nmerge,16) x 1024 thr.
// f32 deflation scan (serial, records Givens); rotations row-parallel;
// secular solve wave-parallel; z-hat/U/GEMM parallel.
// ---------------------------------------------------------------------------
__global__ __launch_bounds__(MTH) void k_merge(double* __restrict__ Zb, double* __restrict__ QNDb,
                                               double* __restrict__ DELb, double* __restrict__ GOb,
                                               double* __restrict__ dar, const double* __restrict__ ear,
                                               int n1){
  const int b = blockIdx.y, mg = blockIdx.x, tid = threadIdx.x;
  const int wave = tid >> 6, lane = tid & 63;
  const int lo = mg*2*n1, n = 2*n1;
  double* Z   = Zb   + (size_t)b*MATN;
  double* Qnd = QNDb + (size_t)b*MATN;
  double* DEL = DELb + (size_t)b*MATN;
  double* GO  = GOb  + (size_t)b*MATN;
  double* dv  = dar + b*T_;
  __shared__ float frd[T_], frz[T_], fmd[T_], fmz[T_], fkd[T_], fkw[T_], fddf[T_], flam[T_], foval[T_];
  __shared__ double lam[T_], zh[T_], nrm[T_];
  __shared__ double rotc[T_], rots[T_];
  __shared__ int rotx[T_], roty[T_];
  __shared__ int mcol[T_], kcol[T_], dcol[T_], osrc[T_], indxp_[T_];
  __shared__ int sK, sND, sNROT;
  __shared__ double s_sumw2;
  __shared__ float s_rho;

  float rho0 = (float)ear[b*T_ + lo + n1 - 1];
  const float rs2f = 0.70710678118654752440f;
  for (int k = tid; k < n; k += MTH){
    frd[k] = (float)dv[lo + k];
    int row = (k < n1) ? (lo + n1 - 1) : (lo + n1);
    float zv = (float)Z[(size_t)(lo + k)*T_ + row];
    if (k >= n1 && rho0 < 0.0f) zv = -zv;
    frz[k] = zv*rs2f;
  }
  __syncthreads();
  if (tid == 0){
    float rho = fabsf(2.0f*rho0);
    s_rho = rho;
    int nrot = 0;
    int i1 = 0, i2 = n1, p = 0;
    while (i1 < n1 || i2 < n){
      bool t1;
      if (i1 >= n1) t1 = false;
      else if (i2 >= n) t1 = true;
      else t1 = (frd[i1] <= frd[i2]);
      int src = t1 ? i1++ : i2++;
      fmd[p] = frd[src]; fmz[p] = frz[src]; mcol[p] = src; p++;
    }
    float dmax = 0.0f, zmax = 0.0f;
    for (int k = 0; k < n; ++k){ dmax = fmaxf(dmax, fabsf(fmd[k])); zmax = fmaxf(zmax, fabsf(fmz[k])); }
    float tol = 8.0f*EPS32F*fmaxf(dmax, zmax);
    int K = 0, ND = 0;
    if (rho*zmax <= tol){               // full deflation
      for (int k = 0; k < n; ++k){ fddf[k] = fmd[k]; dcol[k] = mcol[k]; }
      ND = n; K = 0;
    } else {                            // slaed2 deflation scan (f32, INDXP port)
      int k2 = n;
      int j = 0, pj = -1;
      for (; j < n; ++j){
        if (rho*fabsf(fmz[j]) <= tol){ k2--; indxp_[k2] = j; }
        else { pj = j; break; }
      }
      if (pj >= 0){
        for (;;){
          j++;
          if (j >= n) break;
          int nj = j;
          if (rho*fabsf(fmz[nj]) <= tol){
            k2--; indxp_[k2] = nj;
          } else {
            float s_ = fmz[pj], c_ = fmz[nj];
            float tau_ = slapy2f(c_, s_);
            float t_ = fmd[nj] - fmd[pj];
            c_ = c_/tau_; s_ = -s_/tau_;
            if (fabsf((t_*c_)*s_) <= tol){
              fmz[nj] = tau_; fmz[pj] = 0.0f;
              rotx[nrot] = mcol[pj]; roty[nrot] = mcol[nj];
              rotc[nrot] = (double)c_; rots[nrot] = (double)s_;
              nrot++;
              float dt = fmd[pj]*(c_*c_) + fmd[nj]*(s_*s_);
              fmd[nj] = fmd[pj]*(s_*s_) + fmd[nj]*(c_*c_);
              fmd[pj] = dt;
              k2--;
              int i3 = 1;
              for (;;){
                if (k2 + i3 <= n - 1){
                  if (fmd[pj] < fmd[indxp_[k2 + i3]]){
                    indxp_[k2 + i3 - 1] = indxp_[k2 + i3];
                    indxp_[k2 + i3]     = pj;
                    i3++;
                  } else { indxp_[k2 + i3 - 1] = pj; break; }
                } else { indxp_[k2 + i3 - 1] = pj; break; }
              }
              pj = nj;
            } else {
              fkd[K] = fmd[pj]; fkw[K] = fmz[pj]; kcol[K] = mcol[pj]; K++;
              pj = nj;
            }
          }
        }
        fkd[K] = fmd[pj]; fkw[K] = fmz[pj]; kcol[K] = mcol[pj]; K++;
      }
      ND = n - K;
      for (int m2 = 0; m2 < ND; ++m2){
        int mi = indxp_[n - 1 - m2];
        fddf[m2] = fmd[mi]; dcol[m2] = mcol[mi];
      }
    }
    sK = K; sND = ND; sNROT = nrot;
    double sw = 0.0; for (int k = 0; k < K; ++k) sw += (double)fkw[k]*(double)fkw[k];
    s_sumw2 = sw;
  }
  __syncthreads();
  {
    int nrot = sNROT;
    for (int r = tid; r < n; r += MTH){
      for (int q = 0; q < nrot; ++q){
        double* qx = Z + (size_t)(lo + rotx[q])*T_ + lo;
        double* qy = Z + (size_t)(lo + roty[q])*T_ + lo;
        double x = qx[r], y = qy[r];
        qx[r] = rotc[q]*x + rots[q]*y;
        qy[r] = rotc[q]*y - rots[q]*x;
      }
    }
  }
  __syncthreads();
  int K = sK, ND = sND;
  double rho_d = (double)s_rho;
  if (K > 0){
    // secular roots: wave-parallel (one root per wave; lanes split the f-sum)
    for (int j = wave; j < K; j += (MTH/64)){
      double dj = (double)fkd[j];
      double hi = (j < K-1) ? ((double)fkd[j+1] - dj) : (rho_d*s_sumw2 + 1e-300);
      if (hi < 0.0) hi = 0.0;
      double lo_t = 0.0, hi_t = hi;
      for (int it = 0; it < 70; ++it){
        double mid = 0.5*(lo_t + hi_t);
        if (mid == lo_t || mid == hi_t) break;
        double part = 0.0;
        for (int i2 = lane; i2 < K; i2 += 64){
          double dd2 = ((double)fkd[i2] - dj) - mid;
          part += (double)fkw[i2]*(double)fkw[i2]/dd2;
        }
        for (int o = 32; o > 0; o >>= 1) part += __shfl_down(part, o, 64);
        part = __shfl(part, 0, 64);
        double f = 1.0 + rho_d*part;
        if (f < 0.0) lo_t = mid; else hi_t = mid;
      }
      double tauj = 0.5*(lo_t + hi_t);
      if (tauj <= 0.0) tauj = (hi_t > 0.0) ? hi_t*0.5 : 1e-300;
      if (j < K-1){
        double hib = (double)fkd[j+1] - dj;
        if (tauj >= hib) tauj = nextafter(hib, 0.0);
      }
      if (lane == 0){ lam[j] = dj + tauj; flam[j] = (float)(dj + tauj); }
      double* Dj = DEL + (size_t)(lo + j)*T_;
      for (int i2 = lane; i2 < K; i2 += 64) Dj[i2] = ((double)fkd[i2] - dj) - tauj;
    }
    __syncthreads();
    // Gu z-hat (sequential product per i2)
    for (int i2 = tid; i2 < K; i2 += MTH){
      double p = DEL[(size_t)(lo + i2)*T_ + i2];
      for (int j = 0; j < K; ++j){
        if (j == i2) continue;
        p *= DEL[(size_t)(lo + j)*T_ + i2]/((double)fkd[i2] - (double)fkd[j]);
      }
      zh[i2] = copysign(sqrt(fabs(p)), (double)fkw[i2]);
    }
    __syncthreads();
    for (int idx = tid; idx < K*K; idx += MTH){
      int j = idx/K, i2 = idx%K;
      double* pj = DEL + (size_t)(lo + j)*T_ + i2;
      *pj = zh[i2]/(*pj);
    }
    __syncthreads();
    for (int j = tid; j < K; j += MTH){
      double ss = 0.0;
      const double* Dj = DEL + (size_t)(lo + j)*T_;
      for (int i2 = 0; i2 < K; ++i2) ss += Dj[i2]*Dj[i2];
      nrm[j] = sqrt(ss);
    }
    __syncthreads();
    for (int idx = tid; idx < K*n; idx += MTH){
      int k2 = idx/n, rr = idx%n;
      Qnd[(size_t)(lo + k2)*T_ + rr] = Z[(size_t)(lo + kcol[k2])*T_ + (lo + rr)];
    }
  }
  for (int idx = tid; idx < ND*n; idx += MTH){
    int m2 = idx/n, rr = idx%n;
    GO[(size_t)(lo + K + m2)*T_ + rr] = Z[(size_t)(lo + dcol[m2])*T_ + (lo + rr)];
  }
  __syncthreads();
  if (K > 0){
    for (int idx = tid; idx < K*n; idx += MTH){
      int j = idx/n, rr = idx%n;
      double acc = 0.0;
      const double* Dj = DEL + (size_t)(lo + j)*T_;
      for (int i2 = 0; i2 < K; ++i2) acc += Qnd[(size_t)(lo + i2)*T_ + rr]*Dj[i2];
      GO[(size_t)(lo + j)*T_ + rr] = acc/nrm[j];
    }
  }
  __syncthreads();
  if (tid == 0){   // dlamrg(K, ND, stride -1): f32 comparisons, tie -> lam
    int i1 = 0, i2 = 0, p = 0;
    while (i1 < K || i2 < ND){
      bool t1;
      if (i1 >= K) t1 = false;
      else if (i2 >= ND) t1 = true;
      else t1 = (flam[i1] <= fddf[i2]);
      if (t1){ foval[p] = flam[i1]; osrc[p] = i1; i1++; }
      else { foval[p] = fddf[i2]; osrc[p] = K + i2; i2++; }
      p++;
    }
  }
  __syncthreads();
  for (int idx = tid; idx < n*n; idx += MTH){
    int p2 = idx/n, rr = idx%n;
    Z[(size_t)(lo + p2)*T_ + (lo + rr)] = GO[(size_t)(lo + osrc[p2])*T_ + rr];
  }
  for (int p2 = tid; p2 < n; p2 += MTH) dv[lo + p2] = (double)foval[p2];
}

// ---------------------------------------------------------------------------
// K2f: back-transform Z <- Q*Z. grid(B, 11) x 256: 16 columns/block,
// 16 threads per column with width-16 shuffle-reduced dots.
// ---------------------------------------------------------------------------
__global__ __launch_bounds__(256) void k_backt(const double* __restrict__ Ab, double* __restrict__ Zb,
                                               const double* __restrict__ dar, const double* __restrict__ tauar,
                                               const float* __restrict__ orgn, float* __restrict__ val32){
  const int b = blockIdx.x, chunk = blockIdx.y, tid = threadIdx.x;
  const int col_local = tid >> 4, sub = tid & 15;
  const int c = chunk*16 + col_local;
  const double* A = Ab + (size_t)b*MATN;
  double* Z = Zb + (size_t)b*MATN;
  double* Zc = Z + (size_t)c*T_;
  __shared__ double vsh[T_];
  for (int i = T_-2; i >= 0; --i){
    double tau = tauar[b*T_ + i];
    if (tau != 0.0){
      for (int r = i+1+tid; r < T_; r += 256) vsh[r] = (r == i+1) ? 1.0 : A[(size_t)r*T_ + i];
      __syncthreads();
      double part = 0.0;
      for (int r = i+1+sub; r < T_; r += 16) part += vsh[r]*Zc[r];
      part += __shfl_xor(part, 8, 16);
      part += __shfl_xor(part, 4, 16);
      part += __shfl_xor(part, 2, 16);
      part += __shfl_xor(part, 1, 16);
      double w = tau*part;
      for (int r = i+1+sub; r < T_; r += 16) Zc[r] -= w*vsh[r];
      __syncthreads();
    }
  }
  if (chunk == 0){
    float og = orgn[b];
    for (int j = tid; j < T_; j += 256) val32[b*T_ + j] = (float)dar[b*T_ + j] * og;
  }
}

// ---------------------------------------------------------------------------
// K3: Group softmax (f32 op order as ref).
// ---------------------------------------------------------------------------
__global__ __launch_bounds__(256) void k_group(const double* __restrict__ Zb, const float* __restrict__ val32,
                                               const float* __restrict__ gum, float* __restrict__ grp){
  const int t = blockIdx.x, b = blockIdx.y, tid = threadIdx.x;
  const double* Z = Zb + (size_t)b*MATN;
  __shared__ float sred[256];
  float y = -3.4e38f;
  if (tid < T_){
    float vd = val32[b*T_ + (T_-1 - tid)];
    float dc = (vd <= 0.f) ? 1e-7f : vd;
    float dj = sqrtf(dc);
    float v = (float)Z[(size_t)tid*T_ + t];
    float S = v*dj;
    y = (S + gum[((size_t)b*T_ + t)*T_ + tid])/1e-5f;
  }
  sred[tid] = y; __syncthreads();
  for (int o = 128; o > 0; o >>= 1){ if (tid < o) sred[tid] = fmaxf(sred[tid], sred[tid+o]); __syncthreads(); }
  float ym = sred[0]; __syncthreads();
  float e = (tid < T_) ? expf(y - ym) : 0.f;
  sred[tid] = e; __syncthreads();
  for (int o = 128; o > 0; o >>= 1){ if (tid < o) sred[tid] += sred[tid+o]; __syncthreads(); }
  float se = sred[0];
  if (tid < T_) grp[((size_t)b*T_ + t)*T_ + tid] = e/se;
}

__global__ void k_iszero(const float* __restrict__ grp, const float* __restrict__ mx, int* __restrict__ iz){
  int g = blockIdx.x, b = blockIdx.y, tid = threadIdx.x;
  bool nz = false;
  for (int t2 = tid; t2 < T_; t2 += 64){
    float w = grp[((size_t)b*T_ + t2)*T_ + g];
    if (w != 0.f){
      double p = fabs((double)w)*(double)mx[b*T_ + t2];
      if (p > 0x1.0p-150) nz = true;
    }
  }
  unsigned long long bal = __ballot(nz);
  if (tid == 0) iz[b*T_ + g] = (bal == 0ull) ? 1 : 0;
}

__global__ void k_slots(const int* __restrict__ iz, int* __restrict__ slot, int* __restrict__ nkeep){
  int b = blockIdx.x;
  if (threadIdx.x == 0){
    int c = 0;
    for (int g = 0; g < T_; ++g){
      if (!iz[b*T_ + g]) slot[b*T_ + g] = c++;
      else slot[b*T_ + g] = -1;
    }
    nkeep[b] = c;
  }
}

__global__ __launch_bounds__(256) void k_zero(const int* __restrict__ nkeep, float* __restrict__ padded){
  int k = blockIdx.x, b = blockIdx.y, tid = threadIdx.x;
  if (k < nkeep[b]) return;
  float* dst = padded + ((size_t)b*T_ + k)*NPAIR_;
  for (int p = tid; p < NPAIR_; p += 256) dst[p] = 0.f;
}

__global__ __launch_bounds__(256) void k_fc(const float* __restrict__ grp, const float* __restrict__ X,
                                            const int* __restrict__ iz, const int* __restrict__ slot,
                                            float* __restrict__ padded){
  const int g = blockIdx.x, b = blockIdx.y, tid = threadIdx.x;
  if (iz[b*T_ + g]) return;
  __shared__ float wcol[T_];
  __shared__ int tl[T_];
  __shared__ int scnt;
  __shared__ double mm[ROI_], inv[ROI_];
  for (int t2 = tid; t2 < T_; t2 += 256) wcol[t2] = grp[((size_t)b*T_ + t2)*T_ + g];
  __syncthreads();
  if (tid == 0){
    int c = 0;
    for (int t2 = 0; t2 < T_; ++t2) if (wcol[t2] != 0.f) tl[c++] = t2;
    scnt = c;
  }
  __syncthreads();
  int cnt = scnt;
  for (int i = tid; i < ROI_; i += 256){
    double A = 0.0, Q = 0.0;
    for (int k = 0; k < cnt; ++k){
      int t2 = tl[k];
      double wx = (double)wcol[t2]*(double)X[((size_t)b*T_ + t2)*ROI_ + i];
      A += wx; Q += wx*wx;
    }
    double m2 = A/176.0;
    double var = (Q - 176.0*m2*m2)/175.0;
    double sd = sqrt(fmax(var, 0.0));
    mm[i] = m2; inv[i] = 1.0/(sd + 1e-7);
  }
  __syncthreads();
  int outrow = slot[b*T_ + g];
  float* dst = padded + ((size_t)b*T_ + outrow)*NPAIR_;
  for (int p = tid; p < NPAIR_; p += 256){
    int i = (int)(115.5 - sqrt(115.5*115.5 - 2.0*(double)p));
    if (i < 0) i = 0;
    while ((i+1)*115 - ((i+1)*i)/2 <= p) ++i;
    while (i*115 - (i*(i-1))/2 > p) --i;
    int off = i*115 - (i*(i-1))/2;
    int j = i + 1 + (p - off);
    double q = 0.0;
    for (int k = 0; k < cnt; ++k){
      int t2 = tl[k];
      double w = (double)wcol[t2];
      const float* Xr = X + ((size_t)b*T_ + t2)*ROI_;
      q += (w*(double)Xr[i])*(w*(double)Xr[j]);
    }
    double fc = (q - 176.0*mm[i]*mm[j])*inv[i]*inv[j]/175.0;
    dst[p] = (float)fc;
  }
}

// ---------------------------------------------------------------------------
extern "C" void kernel_launch(void* const* d_in, const int* in_sizes, int n_in,
                              void* d_out, int out_size, void* d_ws, size_t ws_size,
                              hipStream_t stream){
  (void)in_sizes; (void)n_in; (void)out_size; (void)ws_size;
  const float* X   = (const float*)d_in[0];
  const float* W1  = (const float*)d_in[1];
  const float* b1  = (const float*)d_in[2];
  const float* W2  = (const float*)d_in[3];
  const float* b2  = (const float*)d_in[4];
  const float* gum = (const float*)d_in[5];

  float* out    = (float*)d_out;
  float* padded = out;                          // [B, 176, 6670]
  float* gm     = out + (size_t)PAD_ELEMS;      // [B, 176, 176]
  float* grp    = gm  + (size_t)B_*T_*T_;       // [B, 176, 176]

  // Eigh scratch in the padded region (consumed BEFORE padded is written).
  double* MATS = (double*)d_out;
  const size_t MS = (size_t)MATN;
  double* A    = MATS;            // 16 mats
  double* Zv   = MATS + 16*MS;    // 16
  double* QND  = MATS + 32*MS;    // 16
  double* DELm = MATS + 48*MS;    // 16
  double* GOm  = MATS + 64*MS;    // 16
  double* aux  = MATS + 80*MS;
  const int NBT = B_*T_;
  double* dar   = aux;            double* ear = dar + NBT;  double* tauar = ear + NBT;
  float* fs     = (float*)(tauar + NBT);
  float* val32  = fs;             float* mx = val32 + NBT;  float* orgn = mx + NBT;
  // Arrays read DURING padded writes live in d_ws (survive k_zero/k_fc).
  int* iz    = (int*)d_ws;
  int* slot  = iz + NBT;
  int* nkeep = slot + NBT;

  k_gm     <<<dim3(T_, B_), 256, 0, stream>>>(X, W1, b1, W2, b2, gm);
  k_maxabs <<<dim3(T_, B_),  64, 0, stream>>>(X, mx);

  k_tridiag<<<B_, TTH, 0, stream>>>(gm, A, Zv, dar, ear, tauar, orgn);
  k_leaf   <<<dim3(8, B_), 64, 0, stream>>>(Zv, dar, ear);
  k_merge  <<<dim3(4, B_), MTH, 0, stream>>>(Zv, QND, DELm, GOm, dar, ear, 22);
  k_merge  <<<dim3(2, B_), MTH, 0, stream>>>(Zv, QND, DELm, GOm, dar, ear, 44);
  k_merge  <<<dim3(1, B_), MTH, 0, stream>>>(Zv, QND, DELm, GOm, dar, ear, 88);
  k_backt  <<<dim3(B_, 11), 256, 0, stream>>>(A, Zv, dar, tauar, orgn, val32);

  // k_group consumes Zv/val32 BEFORE k_zero/k_fc overwrite the padded region.
  k_group  <<<dim3(T_, B_), 256, 0, stream>>>(Zv, val32, gum, grp);
  k_iszero <<<dim3(T_, B_),  64, 0, stream>>>(grp, mx, iz);
  k_slots  <<<B_,            64, 0, stream>>>(iz, slot, nkeep);
  k_zero   <<<dim3(T_, B_), 256, 0, stream>>>(nkeep, padded);
  k_fc     <<<dim3(T_, B_), 256, 0, stream>>>(grp, X, iz, slot, padded);
}

// Round 11
// 4117.375 us; speedup vs baseline: 4.7264x; 1.2848x over previous
//
#include <hip/hip_runtime.h>

// ---------------------------------------------------------------------------
// GMPool: distance-MLP -> grouping_M -> eigh (LAPACK ssyevd-faithful port) ->
// tau=1e-5 softmax Group -> per-group FC features -> packed output.
//
// R7 (PASS): f32 precision-path fidelity reproduces numpy's eigenvector signs.
// R8-R10: merge/backt/tridiag parallelization. Final merge still 1.41ms with
// no attribution (printf invisible on pass).
// R11: k_merge SPLIT into per-phase kernels (rocprof = the timer):
//   k_mscan (serial f32 scan, 1 wave) -> k_mrot (Givens) -> k_msec1
//   (wave-per-root bisection, 4x blocks) -> k_msec2 (zhat/U/nrm/Qnd) ->
//   k_mgemm (n^2 items over 256 blocks) -> k_mperm (dlamrg + writeback).
// State in global scratch at MATS+82*MS (~630KB). All phase arithmetic is
// bit-identical to R10 (same per-value op order).
// ---------------------------------------------------------------------------

#define T_    176
#define B_    16
#define ROI_  116
#define HID_  200
#define NPAIR_ 6670
#define MATN  (T_*T_)          // 30976
#define PAD_ELEMS (B_*T_*NPAIR_)   // 75.1 MB of floats
#define EPS32F 5.9604644775390625e-8f
#define SAFMIN32F 1.17549435e-38f
#define TTH 1024
#define SL 11264               // 64*176, per-array slot stride

__device__ __forceinline__ double fsign(double a, double b){ return (b >= 0.0) ? fabs(a) : -fabs(a); }
__device__ __forceinline__ float fsignf_(float a, float b){ return (b >= 0.0f) ? fabsf(a) : -fabsf(a); }

__device__ __forceinline__ float slapy2f(float x, float y){
  float xa = fabsf(x), ya = fabsf(y);
  float w = fmaxf(xa, ya), z = fminf(xa, ya);
  if (z == 0.0f) return w;
  float q = z / w;
  return w * sqrtf(1.0f + q*q);
}

// LAPACK >=3.10 slartg, f32
__device__ __forceinline__ void lartgf_new(float f, float g, float* c, float* s, float* r){
  if (g == 0.0f){ *c = 1.0f; *s = 0.0f; *r = f; }
  else if (f == 0.0f){ *c = 0.0f; *s = (g >= 0.0f) ? 1.0f : -1.0f; *r = fabsf(g); }
  else {
    float d = sqrtf(f*f + g*g);
    *c = fabsf(f)/d;
    *r = fsignf_(d, f);
    *s = g/(*r);
  }
}

// LAPACK slaev2, f32 port
__device__ void laev2f(float a, float b, float c, float* rt1, float* rt2, float* cs1, float* sn1){
  float sm = a + c, df = a - c, adf = fabsf(df), tb = b + b, ab = fabsf(tb);
  float acmx, acmn;
  if (fabsf(a) > fabsf(c)){ acmx = a; acmn = c; } else { acmx = c; acmn = a; }
  float rt;
  if (adf > ab) rt = adf*sqrtf(1.0f + (ab/adf)*(ab/adf));
  else if (adf < ab) rt = ab*sqrtf(1.0f + (adf/ab)*(adf/ab));
  else rt = ab*sqrtf(2.0f);
  int sgn1;
  if (sm < 0.0f){ *rt1 = 0.5f*(sm - rt); sgn1 = -1; *rt2 = (acmx / *rt1)*acmn - (b / *rt1)*b; }
  else if (sm > 0.0f){ *rt1 = 0.5f*(sm + rt); sgn1 = 1; *rt2 = (acmx / *rt1)*acmn - (b / *rt1)*b; }
  else { *rt1 = 0.5f*rt; *rt2 = -0.5f*rt; sgn1 = 1; }
  float cs; int sgn2;
  if (df >= 0.0f){ cs = df + rt; sgn2 = 1; } else { cs = df - rt; sgn2 = -1; }
  float acs = fabsf(cs);
  if (acs > ab){ float ct = -tb/cs; float sn = 1.0f/sqrtf(1.0f + ct*ct); *sn1 = sn; *cs1 = ct*sn; }
  else {
    if (ab == 0.0f){ *cs1 = 1.0f; *sn1 = 0.0f; }
    else { float tn = -cs/tb; float c1 = 1.0f/sqrtf(1.0f + tn*tn); *cs1 = c1; *sn1 = tn*c1; }
  }
  if (sgn1 == sgn2){ float tn = *cs1; *cs1 = -(*sn1); *sn1 = tn; }
}

// merge-state accessors (slot s = b*4+mg), base MST = MATS + 82*MATN
struct MSt {
  double *rotc, *rots, *nrm, *sumw2;
  float *kd, *kw, *ddf, *lamf, *rho;
  int *kcol, *dcol, *rotx, *roty, *knd;   // knd[s*4+{0,1,2}] = K, ND, NROT
};
__device__ __forceinline__ MSt mstate(double* MST, int s){
  MSt m;
  m.rotc = MST + (size_t)s*176;
  m.rots = MST + SL + (size_t)s*176;
  m.nrm  = MST + 2*SL + (size_t)s*176;
  m.sumw2= MST + 3*SL + s;
  float* fb = (float*)(MST + 3*SL + 64);
  m.kd  = fb + (size_t)s*176;
  m.kw  = fb + SL + (size_t)s*176;
  m.ddf = fb + 2*SL + (size_t)s*176;
  m.lamf= fb + 3*SL + (size_t)s*176;
  m.rho = fb + 4*SL + s;
  int* ib = (int*)(fb + 4*SL + 64);
  m.kcol = ib + (size_t)s*176;
  m.dcol = ib + SL + (size_t)s*176;
  m.rotx = ib + 2*SL + (size_t)s*176;
  m.roty = ib + 3*SL + (size_t)s*176;
  m.knd  = ib + 4*SL + s*4;
  return m;
}

// ---------------------------------------------------------------------------
// K1: grouping_M.  block=(t,b), 256 thr.
// ---------------------------------------------------------------------------
__global__ __launch_bounds__(256) void k_gm(const float* __restrict__ X, const float* __restrict__ W1,
                                            const float* __restrict__ b1, const float* __restrict__ W2,
                                            const float* __restrict__ b2, float* __restrict__ gm){
  const int t = blockIdx.x, b = blockIdx.y, tid = threadIdx.x;
  __shared__ float4 w1p[29*200];
  __shared__ __align__(16) float dist[116];
  __shared__ float xt[116];
  __shared__ float b1s[200];
  __shared__ float w2s[200];
  __shared__ float wred[4];
  for (int li = tid; li < 29*200; li += 256){
    int j = li % 200, r4 = li / 200;
    const float* src = W1 + j*ROI_ + r4*4;
    w1p[li] = make_float4(src[0], src[1], src[2], src[3]);
  }
  for (int j = tid; j < 200; j += 256){ b1s[j] = b1[j]; w2s[j] = W2[j]; }
  if (tid < ROI_) xt[tid] = X[(size_t)(b*T_ + t)*ROI_ + tid];
  float b2v = b2[0];
  if (tid == 0) gm[(size_t)(b*T_ + t)*T_ + t] = 1.0f + 1e-7f;
  __syncthreads();
  for (int s = t + 1; s < T_; ++s){
    if (tid < ROI_){
      float xs = X[(size_t)(b*T_ + s)*ROI_ + tid];
      float df = xt[tid] - xs;
      dist[tid] = sqrtf(df*df + 1e-9f);
    }
    __syncthreads();
    float part = 0.f;
    if (tid < HID_){
      float acc = 0.f;
      const float4* dv4 = reinterpret_cast<const float4*>(dist);
      #pragma unroll
      for (int r4 = 0; r4 < 29; ++r4){
        float4 w = w1p[r4*200 + tid];
        float4 d4 = dv4[r4];
        acc += w.x*d4.x; acc += w.y*d4.y; acc += w.z*d4.z; acc += w.w*d4.w;
      }
      acc += b1s[tid];
      float h = fmaxf(acc, 0.f);
      part = w2s[tid]*h;
    }
    for (int off = 32; off > 0; off >>= 1) part += __shfl_down(part, off, 64);
    if ((tid & 63) == 0) wred[tid >> 6] = part;
    __syncthreads();
    if (tid == 0){
      float logit = wred[0] + wred[1] + wred[2] + wred[3] + b2v;
      float c = 1.0f/(1.0f + expf(-logit));
      float v = c + 1e-7f;
      gm[(size_t)(b*T_ + t)*T_ + s] = v;
      gm[(size_t)(b*T_ + s)*T_ + t] = v;
    }
    __syncthreads();
  }
}

__global__ void k_maxabs(const float* __restrict__ X, float* __restrict__ mx){
  int t = blockIdx.x, b = blockIdx.y, tid = threadIdx.x;
  float m = 0.f;
  for (int r = tid; r < ROI_; r += 64) m = fmaxf(m, fabsf(X[(size_t)(b*T_ + t)*ROI_ + r]));
  for (int off = 32; off > 0; off >>= 1) m = fmaxf(m, __shfl_down(m, off, 64));
  if (tid == 0) mx[b*T_ + t] = m;
}

// ---------------------------------------------------------------------------
// K2a: ssytd2 (lower) in f64 (1024 thr), then f32 rounding/scaling/tears.
// ---------------------------------------------------------------------------
__global__ __launch_bounds__(TTH) void k_tridiag(const float* __restrict__ gm, double* __restrict__ Ab,
                                                 double* __restrict__ Zb, double* __restrict__ dar,
                                                 double* __restrict__ ear, double* __restrict__ tauar,
                                                 float* __restrict__ orgn){
  const int b = blockIdx.x, tid = threadIdx.x;
  const int lane = tid & 63, wv = tid >> 6;
  double* A = Ab + (size_t)b*MATN;
  double* Z = Zb + (size_t)b*MATN;
  const float* gmb = gm + (size_t)b*MATN;
  __shared__ double vsh[T_], wsh[T_], wred[16];
  __shared__ double s_res;
  for (int idx = tid; idx < MATN; idx += TTH){ A[idx] = (double)gmb[idx]; Z[idx] = 0.0; }
  __syncthreads();
  for (int i = 0; i <= T_-2; ++i){
    int m = T_ - 1 - i;
    double alpha = A[(size_t)(i+1)*T_ + i];
    double part = 0.0;
    for (int r = i+2+tid; r < T_; r += TTH){ double x = A[(size_t)r*T_ + i]; part += x*x; }
    for (int o = 32; o > 0; o >>= 1) part += __shfl_down(part, o, 64);
    if (lane == 0) wred[wv] = part;
    __syncthreads();
    if (tid == 0){ double s = 0.0; for (int k = 0; k < 16; ++k) s += wred[k]; s_res = s; }
    __syncthreads();
    double xnorm2 = s_res;
    if (m == 1 || xnorm2 == 0.0){
      if (tid == 0){ tauar[b*T_ + i] = 0.0; ear[b*T_ + i] = alpha; }
      __syncthreads();
      continue;
    }
    double beta = -fsign(sqrt(alpha*alpha + xnorm2), alpha);
    double tau  = (beta - alpha)/beta;
    double sc   = 1.0/(alpha - beta);
    for (int r = i+2+tid; r < T_; r += TTH) A[(size_t)r*T_ + i] *= sc;
    __syncthreads();
    for (int r = i+1+tid; r < T_; r += TTH) vsh[r] = (r == i+1) ? 1.0 : A[(size_t)r*T_ + i];
    __syncthreads();
    if (tid < m*4){
      int r = i+1 + (tid >> 2), sub = tid & 3;
      double acc = 0.0;
      const double* Ar = A + (size_t)r*T_;
      for (int c = i+1+sub; c < T_; c += 4) acc += Ar[c]*vsh[c];
      acc += __shfl_xor(acc, 2, 4);
      acc += __shfl_xor(acc, 1, 4);
      if (sub == 0) wsh[r] = tau*acc;
    }
    __syncthreads();
    part = 0.0;
    for (int r = i+1+tid; r < T_; r += TTH) part += wsh[r]*vsh[r];
    for (int o = 32; o > 0; o >>= 1) part += __shfl_down(part, o, 64);
    if (lane == 0) wred[wv] = part;
    __syncthreads();
    if (tid == 0){ double s = 0.0; for (int k = 0; k < 16; ++k) s += wred[k]; s_res = s; }
    __syncthreads();
    double a2 = -0.5*tau*s_res;
    for (int r = i+1+tid; r < T_; r += TTH) wsh[r] += a2*vsh[r];
    __syncthreads();
    for (int idx = tid; idx < m*m; idx += TTH){
      int rr = i+1 + idx/m, cc = i+1 + idx%m;
      A[(size_t)rr*T_ + cc] -= vsh[rr]*wsh[cc] + wsh[rr]*vsh[cc];
    }
    if (tid == 0){ ear[b*T_ + i] = beta; tauar[b*T_ + i] = tau; }
    __syncthreads();
  }
  for (int j = tid; j < T_; j += TTH) dar[b*T_ + j] = A[(size_t)j*T_ + j];
  __syncthreads();
  if (tid == 0){
    for (int j = 0; j < T_; ++j) dar[b*T_ + j] = (double)(float)dar[b*T_ + j];
    for (int j = 0; j < T_-1; ++j) ear[b*T_ + j] = (double)(float)ear[b*T_ + j];
    float og = 0.0f;
    for (int j = 0; j < T_; ++j) og = fmaxf(og, fabsf((float)dar[b*T_ + j]));
    for (int j = 0; j < T_-1; ++j) og = fmaxf(og, fabsf((float)ear[b*T_ + j]));
    for (int j = 0; j < T_; ++j) dar[b*T_ + j] = (double)(float)((float)dar[b*T_ + j]/og);
    for (int j = 0; j < T_-1; ++j) ear[b*T_ + j] = (double)(float)((float)ear[b*T_ + j]/og);
    orgn[b] = og;
    const int sp[7] = {21,43,65,87,109,131,153};
    for (int k = 0; k < 7; ++k){
      float ae = fabsf((float)ear[b*T_ + sp[k]]);
      dar[b*T_ + sp[k]]     = (double)((float)dar[b*T_ + sp[k]] - ae);
      dar[b*T_ + sp[k] + 1] = (double)((float)dar[b*T_ + sp[k] + 1] - ae);
    }
  }
}

// ---------------------------------------------------------------------------
// K2b: ssteqr('I') on 22x22 leaves, FULL f32 arithmetic. grid(8,16) x 64 thr.
// ---------------------------------------------------------------------------
__global__ __launch_bounds__(64) void k_leaf(double* __restrict__ Zb, double* __restrict__ dar,
                                             const double* __restrict__ ear){
  const int lf = blockIdx.x, b = blockIdx.y, tid = threadIdx.x;
  const int off = lf*22;
  double* Z = Zb + (size_t)b*MATN;
  __shared__ float ld_[22], le_[22];
  __shared__ float zl[22*22];
  __shared__ int perm_[22];
  for (int k = tid; k < 22; k += 64){
    ld_[k] = (float)dar[b*T_ + off + k];
    le_[k] = (k < 21) ? (float)ear[b*T_ + off + k] : 0.0f;
  }
  for (int idx = tid; idx < 484; idx += 64) zl[idx] = (idx/22 == idx%22) ? 1.0f : 0.0f;
  __syncthreads();
  const float eps = EPS32F, eps2 = EPS32F*EPS32F, safmin = SAFMIN32F;
  const int n = 22, nm1 = 21, nmaxit = 22*30;
  int jtot = 0, l1 = 0;
  while (l1 <= n-1){
    if (l1 > 0) le_[l1-1] = 0.0f;
    int msp = n-1;
    for (int mm2 = l1; mm2 < nm1; ++mm2){
      float tst = fabsf(le_[mm2]);
      if (tst == 0.0f){ msp = mm2; break; }
      if (tst <= (sqrtf(fabsf(ld_[mm2]))*sqrtf(fabsf(ld_[mm2+1])))*eps){
        le_[mm2] = 0.0f;
        msp = mm2; break;
      }
    }
    int l = l1, lend = msp;
    l1 = msp + 1;
    if (lend == l) continue;
    if (fabsf(ld_[lend]) < fabsf(ld_[l])){ int tmp = l; l = lend; lend = tmp; }
    if (lend > l){
      for (;;){ // QL
        int m2 = lend;
        if (l != lend){
          for (int k = l; k < lend; ++k){
            float tst = le_[k]*le_[k];
            if (tst <= (eps2*fabsf(ld_[k]))*fabsf(ld_[k+1]) + safmin){ m2 = k; break; }
          }
        }
        if (m2 < lend) le_[m2] = 0.0f;
        float p = ld_[l];
        if (m2 == l){ l++; if (l <= lend) continue; else break; }
        if (m2 == l+1){
          float rt1, rt2, c2, s2;
          laev2f(ld_[l], le_[l], ld_[l+1], &rt1, &rt2, &c2, &s2);
          if (tid < 22){
            float t0 = zl[tid*22 + l], t1 = zl[tid*22 + l+1];
            zl[tid*22 + l]   = c2*t0 + s2*t1;
            zl[tid*22 + l+1] = -s2*t0 + c2*t1;
          }
          ld_[l] = rt1; ld_[l+1] = rt2; le_[l] = 0.0f;
          l += 2;
          if (l <= lend) continue; else break;
        }
        if (jtot == nmaxit) break;
        jtot++;
        float g = (ld_[l+1] - p)/(2.0f*le_[l]);
        float r = slapy2f(g, 1.0f);
        g = ld_[m2] - p + le_[l]/(g + fsignf_(r, g));
        float s2 = 1.0f, c2 = 1.0f;
        p = 0.0f;
        for (int i = m2-1; i >= l; --i){
          float f2 = s2*le_[i];
          float bb = c2*le_[i];
          lartgf_new(g, f2, &c2, &s2, &r);
          if (i != m2-1) le_[i+1] = r;
          g = ld_[i+1] - p;
          r = (ld_[i] - g)*s2 + 2.0f*c2*bb;
          p = s2*r;
          ld_[i+1] = g + p;
          g = c2*r - bb;
          if (tid < 22){
            float t0 = zl[tid*22 + i], t1 = zl[tid*22 + i+1];
            zl[tid*22 + i]   = c2*t0 - s2*t1;
            zl[tid*22 + i+1] = s2*t0 + c2*t1;
          }
        }
        ld_[l] -= p; le_[l] = g;
        if (l <= lend) continue; else break;
      }
    } else {
      for (;;){ // QR
        int m2 = lend;
        if (l != lend){
          for (int k = l; k > lend; --k){
            float tst = le_[k-1]*le_[k-1];
            if (tst <= (eps2*fabsf(ld_[k]))*fabsf(ld_[k-1]) + safmin){ m2 = k; break; }
          }
        }
        if (m2 > lend) le_[m2-1] = 0.0f;
        float p = ld_[l];
        if (m2 == l){ l--; if (l >= lend) continue; else break; }
        if (m2 == l-1){
          float rt1, rt2, c2, s2;
          laev2f(ld_[l-1], le_[l-1], ld_[l], &rt1, &rt2, &c2, &s2);
          if (tid < 22){
            float t0 = zl[tid*22 + l-1], t1 = zl[tid*22 + l];
            zl[tid*22 + l-1] = c2*t0 + s2*t1;
            zl[tid*22 + l]   = -s2*t0 + c2*t1;
          }
          ld_[l-1] = rt1; ld_[l] = rt2; le_[l-1] = 0.0f;
          l -= 2;
          if (l >= lend) continue; else break;
        }
        if (jtot == nmaxit) break;
        jtot++;
        float g = (ld_[l-1] - p)/(2.0f*le_[l-1]);
        float r = slapy2f(g, 1.0f);
        g = ld_[m2] - p + le_[l-1]/(g + fsignf_(r, g));
        float s2 = 1.0f, c2 = 1.0f;
        p = 0.0f;
        for (int i = m2; i <= l-1; ++i){
          float f2 = s2*le_[i];
          float bb = c2*le_[i];
          lartgf_new(g, f2, &c2, &s2, &r);
          if (i != m2) le_[i-1] = r;
          g = ld_[i] - p;
          r = (ld_[i+1] - g)*s2 + 2.0f*c2*bb;
          p = s2*r;
          ld_[i] = g + p;
          g = c2*r - bb;
          if (tid < 22){
            float t0 = zl[tid*22 + i], t1 = zl[tid*22 + i+1];
            zl[tid*22 + i]   = c2*t0 + s2*t1;
            zl[tid*22 + i+1] = -s2*t0 + c2*t1;
          }
        }
        ld_[l] -= p; le_[l-1] = g;
        if (l >= lend) continue; else break;
      }
    }
  }
  __syncthreads();
  if (tid == 0){
    bool used[22]; for (int k = 0; k < 22; ++k) used[k] = false;
    for (int c = 0; c < 22; ++c){
      int best = -1; float bv = 0.0f;
      for (int k = 0; k < 22; ++k) if (!used[k] && (best < 0 || ld_[k] < bv)){ best = k; bv = ld_[k]; }
      used[best] = true; perm_[c] = best;
    }
  }
  __syncthreads();
  if (tid < 22){
    int r = tid;
    for (int c = 0; c < 22; ++c) Z[(size_t)(off + c)*T_ + (off + r)] = (double)zl[r*22 + perm_[c]];
  }
  for (int c = tid; c < 22; c += 64) dar[b*T_ + off + c] = (double)ld_[perm_[c]];
}

// ---------------------------------------------------------------------------
// MERGE PHASE 1: serial f32 slaed2 scan (bit-exact decision path).
// grid(nmerge, B) x 64.
// ---------------------------------------------------------------------------
__global__ __launch_bounds__(64) void k_mscan(const double* __restrict__ Zb, const double* __restrict__ dar,
                                              const double* __restrict__ ear, double* __restrict__ MST, int n1){
  const int b = blockIdx.y, mg = blockIdx.x, tid = threadIdx.x;
  const int lo = mg*2*n1, n = 2*n1, s = b*4 + mg;
  const double* Z = Zb + (size_t)b*MATN;
  const double* dv = dar + b*T_;
  __shared__ float frd[T_], frz[T_], fmd[T_], fmz[T_];
  __shared__ float skd[T_], skw[T_], sddf[T_];
  __shared__ int mcolS[T_], indxpS[T_], skcol[T_], sdcol[T_], srx[T_], sry[T_];
  __shared__ double src_[T_], srs_[T_];
  __shared__ int sK, sND, sNR;
  __shared__ double ssw;
  float rho0 = (float)ear[b*T_ + lo + n1 - 1];
  const float rs2f = 0.70710678118654752440f;
  for (int k = tid; k < n; k += 64){
    frd[k] = (float)dv[lo + k];
    int row = (k < n1) ? (lo + n1 - 1) : (lo + n1);
    float zv = (float)Z[(size_t)(lo + k)*T_ + row];
    if (k >= n1 && rho0 < 0.0f) zv = -zv;
    frz[k] = zv*rs2f;
  }
  __syncthreads();
  if (tid == 0){
    float rho = fabsf(2.0f*rho0);
    int nrot = 0;
    int i1 = 0, i2 = n1, p = 0;
    while (i1 < n1 || i2 < n){
      bool t1;
      if (i1 >= n1) t1 = false;
      else if (i2 >= n) t1 = true;
      else t1 = (frd[i1] <= frd[i2]);
      int src = t1 ? i1++ : i2++;
      fmd[p] = frd[src]; fmz[p] = frz[src]; mcolS[p] = src; p++;
    }
    float dmax = 0.0f, zmax = 0.0f;
    for (int k = 0; k < n; ++k){ dmax = fmaxf(dmax, fabsf(fmd[k])); zmax = fmaxf(zmax, fabsf(fmz[k])); }
    float tol = 8.0f*EPS32F*fmaxf(dmax, zmax);
    int K = 0, ND = 0;
    if (rho*zmax <= tol){
      for (int k = 0; k < n; ++k){ sddf[k] = fmd[k]; sdcol[k] = mcolS[k]; }
      ND = n; K = 0;
    } else {
      int k2 = n;
      int j = 0, pj = -1;
      for (; j < n; ++j){
        if (rho*fabsf(fmz[j]) <= tol){ k2--; indxpS[k2] = j; }
        else { pj = j; break; }
      }
      if (pj >= 0){
        for (;;){
          j++;
          if (j >= n) break;
          int nj = j;
          if (rho*fabsf(fmz[nj]) <= tol){
            k2--; indxpS[k2] = nj;
          } else {
            float s_ = fmz[pj], c_ = fmz[nj];
            float tau_ = slapy2f(c_, s_);
            float t_ = fmd[nj] - fmd[pj];
            c_ = c_/tau_; s_ = -s_/tau_;
            if (fabsf((t_*c_)*s_) <= tol){
              fmz[nj] = tau_; fmz[pj] = 0.0f;
              srx[nrot] = mcolS[pj]; sry[nrot] = mcolS[nj];
              src_[nrot] = (double)c_; srs_[nrot] = (double)s_;
              nrot++;
              float dt = fmd[pj]*(c_*c_) + fmd[nj]*(s_*s_);
              fmd[nj] = fmd[pj]*(s_*s_) + fmd[nj]*(c_*c_);
              fmd[pj] = dt;
              k2--;
              int i3 = 1;
              for (;;){
                if (k2 + i3 <= n - 1){
                  if (fmd[pj] < fmd[indxpS[k2 + i3]]){
                    indxpS[k2 + i3 - 1] = indxpS[k2 + i3];
                    indxpS[k2 + i3]     = pj;
                    i3++;
                  } else { indxpS[k2 + i3 - 1] = pj; break; }
                } else { indxpS[k2 + i3 - 1] = pj; break; }
              }
              pj = nj;
            } else {
              skd[K] = fmd[pj]; skw[K] = fmz[pj]; skcol[K] = mcolS[pj]; K++;
              pj = nj;
            }
          }
        }
        skd[K] = fmd[pj]; skw[K] = fmz[pj]; skcol[K] = mcolS[pj]; K++;
      }
      ND = n - K;
      for (int m2 = 0; m2 < ND; ++m2){
        int mi = indxpS[n - 1 - m2];
        sddf[m2] = fmd[mi]; sdcol[m2] = mcolS[mi];
      }
    }
    sK = K; sND = ND; sNR = nrot;
    double sw = 0.0; for (int k = 0; k < K; ++k) sw += (double)skw[k]*(double)skw[k];
    ssw = sw;
  }
  __syncthreads();
  MSt m = mstate(MST, s);
  for (int k = tid; k < n; k += 64){
    m.kd[k] = skd[k]; m.kw[k] = skw[k]; m.ddf[k] = sddf[k];
    m.kcol[k] = skcol[k]; m.dcol[k] = sdcol[k];
    m.rotx[k] = srx[k]; m.roty[k] = sry[k];
    m.rotc[k] = src_[k]; m.rots[k] = srs_[k];
  }
  if (tid == 0){
    m.knd[0] = sK; m.knd[1] = sND; m.knd[2] = sNR;
    *m.sumw2 = ssw; *m.rho = fabsf(2.0f*rho0);
  }
}

// MERGE PHASE 2: Givens rotations row-parallel (recorded order per row).
__global__ __launch_bounds__(256) void k_mrot(double* __restrict__ Zb, double* __restrict__ MST, int n1){
  const int b = blockIdx.y, mg = blockIdx.x, tid = threadIdx.x;
  const int lo = mg*2*n1, n = 2*n1, s = b*4 + mg;
  MSt m = mstate(MST, s);
  __shared__ int rx[T_], ry[T_];
  __shared__ double rc[T_], rs[T_];
  int nrot = m.knd[2];
  if (nrot == 0) return;
  for (int q = tid; q < nrot; q += 256){ rx[q] = m.rotx[q]; ry[q] = m.roty[q]; rc[q] = m.rotc[q]; rs[q] = m.rots[q]; }
  __syncthreads();
  double* Z = Zb + (size_t)b*MATN;
  for (int r = tid; r < n; r += 256){
    for (int q = 0; q < nrot; ++q){
      double* qx = Z + (size_t)(lo + rx[q])*T_ + lo;
      double* qy = Z + (size_t)(lo + ry[q])*T_ + lo;
      double x = qx[r], y = qy[r];
      qx[r] = rc[q]*x + rs[q]*y;
      qy[r] = rc[q]*y - rs[q]*x;
    }
  }
}

// MERGE PHASE 3: secular roots, wave-per-root, chunked over SC block groups.
__global__ __launch_bounds__(1024) void k_msec1(double* __restrict__ DELb, double* __restrict__ MST,
                                                int n1, int SC){
  const int b = blockIdx.y, bx = blockIdx.x, tid = threadIdx.x;
  const int mg = bx / SC, ch = bx % SC;
  const int lo = mg*2*n1, s = b*4 + mg;
  const int lane = tid & 63;
  MSt m = mstate(MST, s);
  int K = m.knd[0];
  if (K == 0) return;
  double* DEL = DELb + (size_t)b*MATN;
  __shared__ float fkd[T_], fkw[T_];
  for (int k = tid; k < K; k += 1024){ fkd[k] = m.kd[k]; fkw[k] = m.kw[k]; }
  __syncthreads();
  double rho_d = (double)(*m.rho);
  double sumw2 = *m.sumw2;
  int w = ch*16 + (tid >> 6);
  for (int j = w; j < K; j += SC*16){
    double dj = (double)fkd[j];
    double hi = (j < K-1) ? ((double)fkd[j+1] - dj) : (rho_d*sumw2 + 1e-300);
    if (hi < 0.0) hi = 0.0;
    double lo_t = 0.0, hi_t = hi;
    for (int it = 0; it < 70; ++it){
      double mid = 0.5*(lo_t + hi_t);
      if (mid == lo_t || mid == hi_t) break;
      double part = 0.0;
      for (int i2 = lane; i2 < K; i2 += 64){
        double dd2 = ((double)fkd[i2] - dj) - mid;
        part += (double)fkw[i2]*(double)fkw[i2]/dd2;
      }
      for (int o = 32; o > 0; o >>= 1) part += __shfl_down(part, o, 64);
      part = __shfl(part, 0, 64);
      double f = 1.0 + rho_d*part;
      if (f < 0.0) lo_t = mid; else hi_t = mid;
    }
    double tauj = 0.5*(lo_t + hi_t);
    if (tauj <= 0.0) tauj = (hi_t > 0.0) ? hi_t*0.5 : 1e-300;
    if (j < K-1){
      double hib = (double)fkd[j+1] - dj;
      if (tauj >= hib) tauj = nextafter(hib, 0.0);
    }
    if (lane == 0) m.lamf[j] = (float)(dj + tauj);
    double* Dj = DEL + (size_t)(lo + j)*T_;
    for (int i2 = lane; i2 < K; i2 += 64) Dj[i2] = ((double)fkd[i2] - dj) - tauj;
  }
}

// MERGE PHASE 4: Gu z-hat, U in place, norms, Qnd gather.
__global__ __launch_bounds__(1024) void k_msec2(const double* __restrict__ Zb, double* __restrict__ QNDb,
                                                double* __restrict__ DELb, double* __restrict__ MST, int n1){
  const int b = blockIdx.y, mg = blockIdx.x, tid = threadIdx.x;
  const int lo = mg*2*n1, n = 2*n1, s = b*4 + mg;
  MSt m = mstate(MST, s);
  int K = m.knd[0];
  if (K == 0) return;
  const double* Z = Zb + (size_t)b*MATN;
  double* Qnd = QNDb + (size_t)b*MATN;
  double* DEL = DELb + (size_t)b*MATN;
  __shared__ float fkd[T_], fkw[T_];
  __shared__ double zh[T_];
  __shared__ int kcolS[T_];
  for (int k = tid; k < K; k += 1024){ fkd[k] = m.kd[k]; fkw[k] = m.kw[k]; kcolS[k] = m.kcol[k]; }
  __syncthreads();
  for (int i2 = tid; i2 < K; i2 += 1024){
    double p = DEL[(size_t)(lo + i2)*T_ + i2];
    for (int j = 0; j < K; ++j){
      if (j == i2) continue;
      p *= DEL[(size_t)(lo + j)*T_ + i2]/((double)fkd[i2] - (double)fkd[j]);
    }
    zh[i2] = copysign(sqrt(fabs(p)), (double)fkw[i2]);
  }
  __syncthreads();
  for (int idx = tid; idx < K*K; idx += 1024){
    int j = idx/K, i2 = idx%K;
    double* pj = DEL + (size_t)(lo + j)*T_ + i2;
    *pj = zh[i2]/(*pj);
  }
  __syncthreads();
  for (int j = tid; j < K; j += 1024){
    double ss = 0.0;
    const double* Dj = DEL + (size_t)(lo + j)*T_;
    for (int i2 = 0; i2 < K; ++i2) ss += Dj[i2]*Dj[i2];
    m.nrm[j] = sqrt(ss);
  }
  for (int idx = tid; idx < K*n; idx += 1024){
    int k2 = idx/n, rr = idx%n;
    Qnd[(size_t)(lo + k2)*T_ + rr] = Z[(size_t)(lo + kcolS[k2])*T_ + (lo + rr)];
  }
}

// MERGE PHASE 5: GO = [Qnd*U/nrm | deflated Z columns], n*n items chunked.
__global__ __launch_bounds__(1024) void k_mgemm(const double* __restrict__ Zb, const double* __restrict__ QNDb,
                                                const double* __restrict__ DELb, double* __restrict__ GOb,
                                                double* __restrict__ MST, int n1, int CH){
  const int b = blockIdx.y, bx = blockIdx.x, tid = threadIdx.x;
  const int mg = bx / CH, ch = bx % CH;
  const int lo = mg*2*n1, n = 2*n1, s = b*4 + mg;
  MSt m = mstate(MST, s);
  int K = m.knd[0];
  const double* Z = Zb + (size_t)b*MATN;
  const double* Qnd = QNDb + (size_t)b*MATN;
  const double* DEL = DELb + (size_t)b*MATN;
  double* GO = GOb + (size_t)b*MATN;
  for (int idx = ch*1024 + tid; idx < n*n; idx += CH*1024){
    int p = idx/n, rr = idx%n;
    if (p < K){
      double acc = 0.0;
      const double* Dj = DEL + (size_t)(lo + p)*T_;
      for (int i2 = 0; i2 < K; ++i2) acc += Qnd[(size_t)(lo + i2)*T_ + rr]*Dj[i2];
      GO[(size_t)(lo + p)*T_ + rr] = acc/m.nrm[p];
    } else {
      int m2 = p - K;
      GO[(size_t)(lo + p)*T_ + rr] = Z[(size_t)(lo + m.dcol[m2])*T_ + (lo + rr)];
    }
  }
}

// MERGE PHASE 6: dlamrg(K,ND,-1) + permuted writeback + dv.
__global__ __launch_bounds__(256) void k_mperm(double* __restrict__ Zb, const double* __restrict__ GOb,
                                               double* __restrict__ dar, double* __restrict__ MST, int n1){
  const int b = blockIdx.y, mg = blockIdx.x, tid = threadIdx.x;
  const int lo = mg*2*n1, n = 2*n1, s = b*4 + mg;
  MSt m = mstate(MST, s);
  double* Z = Zb + (size_t)b*MATN;
  const double* GO = GOb + (size_t)b*MATN;
  double* dv = dar + b*T_;
  __shared__ float foval[T_];
  __shared__ int osrc[T_];
  if (tid == 0){
    int K = m.knd[0], ND = m.knd[1];
    int i1 = 0, i2 = 0, p = 0;
    while (i1 < K || i2 < ND){
      bool t1;
      if (i1 >= K) t1 = false;
      else if (i2 >= ND) t1 = true;
      else t1 = (m.lamf[i1] <= m.ddf[i2]);
      if (t1){ foval[p] = m.lamf[i1]; osrc[p] = i1; i1++; }
      else { foval[p] = m.ddf[i2]; osrc[p] = K + i2; i2++; }
      p++;
    }
  }
  __syncthreads();
  for (int idx = tid; idx < n*n; idx += 256){
    int p2 = idx/n, rr = idx%n;
    Z[(size_t)(lo + p2)*T_ + (lo + rr)] = GO[(size_t)(lo + osrc[p2])*T_ + rr];
  }
  for (int p2 = tid; p2 < n; p2 += 256) dv[lo + p2] = (double)foval[p2];
}

// ---------------------------------------------------------------------------
// K2f: back-transform. grid(B, 11) x 256.
// ---------------------------------------------------------------------------
__global__ __launch_bounds__(256) void k_backt(const double* __restrict__ Ab, double* __restrict__ Zb,
                                               const double* __restrict__ dar, const double* __restrict__ tauar,
                                               const float* __restrict__ orgn, float* __restrict__ val32){
  const int b = blockIdx.x, chunk = blockIdx.y, tid = threadIdx.x;
  const int col_local = tid >> 4, sub = tid & 15;
  const int c = chunk*16 + col_local;
  const double* A = Ab + (size_t)b*MATN;
  double* Z = Zb + (size_t)b*MATN;
  double* Zc = Z + (size_t)c*T_;
  __shared__ double vsh[T_];
  for (int i = T_-2; i >= 0; --i){
    double tau = tauar[b*T_ + i];
    if (tau != 0.0){
      for (int r = i+1+tid; r < T_; r += 256) vsh[r] = (r == i+1) ? 1.0 : A[(size_t)r*T_ + i];
      __syncthreads();
      double part = 0.0;
      for (int r = i+1+sub; r < T_; r += 16) part += vsh[r]*Zc[r];
      part += __shfl_xor(part, 8, 16);
      part += __shfl_xor(part, 4, 16);
      part += __shfl_xor(part, 2, 16);
      part += __shfl_xor(part, 1, 16);
      double w = tau*part;
      for (int r = i+1+sub; r < T_; r += 16) Zc[r] -= w*vsh[r];
      __syncthreads();
    }
  }
  if (chunk == 0){
    float og = orgn[b];
    for (int j = tid; j < T_; j += 256) val32[b*T_ + j] = (float)dar[b*T_ + j] * og;
  }
}

// ---------------------------------------------------------------------------
// K3: Group softmax (f32 op order as ref).
// ---------------------------------------------------------------------------
__global__ __launch_bounds__(256) void k_group(const double* __restrict__ Zb, const float* __restrict__ val32,
                                               const float* __restrict__ gum, float* __restrict__ grp){
  const int t = blockIdx.x, b = blockIdx.y, tid = threadIdx.x;
  const double* Z = Zb + (size_t)b*MATN;
  __shared__ float sred[256];
  float y = -3.4e38f;
  if (tid < T_){
    float vd = val32[b*T_ + (T_-1 - tid)];
    float dc = (vd <= 0.f) ? 1e-7f : vd;
    float dj = sqrtf(dc);
    float v = (float)Z[(size_t)tid*T_ + t];
    float S = v*dj;
    y = (S + gum[((size_t)b*T_ + t)*T_ + tid])/1e-5f;
  }
  sred[tid] = y; __syncthreads();
  for (int o = 128; o > 0; o >>= 1){ if (tid < o) sred[tid] = fmaxf(sred[tid], sred[tid+o]); __syncthreads(); }
  float ym = sred[0]; __syncthreads();
  float e = (tid < T_) ? expf(y - ym) : 0.f;
  sred[tid] = e; __syncthreads();
  for (int o = 128; o > 0; o >>= 1){ if (tid < o) sred[tid] += sred[tid+o]; __syncthreads(); }
  float se = sred[0];
  if (tid < T_) grp[((size_t)b*T_ + t)*T_ + tid] = e/se;
}

__global__ void k_iszero(const float* __restrict__ grp, const float* __restrict__ mx, int* __restrict__ iz){
  int g = blockIdx.x, b = blockIdx.y, tid = threadIdx.x;
  bool nz = false;
  for (int t2 = tid; t2 < T_; t2 += 64){
    float w = grp[((size_t)b*T_ + t2)*T_ + g];
    if (w != 0.f){
      double p = fabs((double)w)*(double)mx[b*T_ + t2];
      if (p > 0x1.0p-150) nz = true;
    }
  }
  unsigned long long bal = __ballot(nz);
  if (tid == 0) iz[b*T_ + g] = (bal == 0ull) ? 1 : 0;
}

__global__ void k_slots(const int* __restrict__ iz, int* __restrict__ slot, int* __restrict__ nkeep){
  int b = blockIdx.x;
  if (threadIdx.x == 0){
    int c = 0;
    for (int g = 0; g < T_; ++g){
      if (!iz[b*T_ + g]) slot[b*T_ + g] = c++;
      else slot[b*T_ + g] = -1;
    }
    nkeep[b] = c;
  }
}

__global__ __launch_bounds__(256) void k_zero(const int* __restrict__ nkeep, float* __restrict__ padded){
  int k = blockIdx.x, b = blockIdx.y, tid = threadIdx.x;
  if (k < nkeep[b]) return;
  float* dst = padded + ((size_t)b*T_ + k)*NPAIR_;
  for (int p = tid; p < NPAIR_; p += 256) dst[p] = 0.f;
}

__global__ __launch_bounds__(256) void k_fc(const float* __restrict__ grp, const float* __restrict__ X,
                                            const int* __restrict__ iz, const int* __restrict__ slot,
                                            float* __restrict__ padded){
  const int g = blockIdx.x, b = blockIdx.y, tid = threadIdx.x;
  if (iz[b*T_ + g]) return;
  __shared__ float wcol[T_];
  __shared__ int tl[T_];
  __shared__ int scnt;
  __shared__ double mm[ROI_], inv[ROI_];
  for (int t2 = tid; t2 < T_; t2 += 256) wcol[t2] = grp[((size_t)b*T_ + t2)*T_ + g];
  __syncthreads();
  if (tid == 0){
    int c = 0;
    for (int t2 = 0; t2 < T_; ++t2) if (wcol[t2] != 0.f) tl[c++] = t2;
    scnt = c;
  }
  __syncthreads();
  int cnt = scnt;
  for (int i = tid; i < ROI_; i += 256){
    double A = 0.0, Q = 0.0;
    for (int k = 0; k < cnt; ++k){
      int t2 = tl[k];
      double wx = (double)wcol[t2]*(double)X[((size_t)b*T_ + t2)*ROI_ + i];
      A += wx; Q += wx*wx;
    }
    double m2 = A/176.0;
    double var = (Q - 176.0*m2*m2)/175.0;
    double sd = sqrt(fmax(var, 0.0));
    mm[i] = m2; inv[i] = 1.0/(sd + 1e-7);
  }
  __syncthreads();
  int outrow = slot[b*T_ + g];
  float* dst = padded + ((size_t)b*T_ + outrow)*NPAIR_;
  for (int p = tid; p < NPAIR_; p += 256){
    int i = (int)(115.5 - sqrt(115.5*115.5 - 2.0*(double)p));
    if (i < 0) i = 0;
    while ((i+1)*115 - ((i+1)*i)/2 <= p) ++i;
    while (i*115 - (i*(i-1))/2 > p) --i;
    int off = i*115 - (i*(i-1))/2;
    int j = i + 1 + (p - off);
    double q = 0.0;
    for (int k = 0; k < cnt; ++k){
      int t2 = tl[k];
      double w = (double)wcol[t2];
      const float* Xr = X + ((size_t)b*T_ + t2)*ROI_;
      q += (w*(double)Xr[i])*(w*(double)Xr[j]);
    }
    double fc = (q - 176.0*mm[i]*mm[j])*inv[i]*inv[j]/175.0;
    dst[p] = (float)fc;
  }
}

// ---------------------------------------------------------------------------
extern "C" void kernel_launch(void* const* d_in, const int* in_sizes, int n_in,
                              void* d_out, int out_size, void* d_ws, size_t ws_size,
                              hipStream_t stream){
  (void)in_sizes; (void)n_in; (void)out_size; (void)ws_size;
  const float* X   = (const float*)d_in[0];
  const float* W1  = (const float*)d_in[1];
  const float* b1  = (const float*)d_in[2];
  const float* W2  = (const float*)d_in[3];
  const float* b2  = (const float*)d_in[4];
  const float* gum = (const float*)d_in[5];

  float* out    = (float*)d_out;
  float* padded = out;                          // [B, 176, 6670]
  float* gm     = out + (size_t)PAD_ELEMS;      // [B, 176, 176]
  float* grp    = gm  + (size_t)B_*T_*T_;       // [B, 176, 176]

  // Eigh scratch in the padded region (consumed BEFORE padded is written).
  double* MATS = (double*)d_out;
  const size_t MS = (size_t)MATN;
  double* A    = MATS;            // 16 mats
  double* Zv   = MATS + 16*MS;    // 16
  double* QND  = MATS + 32*MS;    // 16
  double* DELm = MATS + 48*MS;    // 16
  double* GOm  = MATS + 64*MS;    // 16
  double* aux  = MATS + 80*MS;
  double* MST  = MATS + 82*MS;    // merge state (~630KB)
  const int NBT = B_*T_;
  double* dar   = aux;            double* ear = dar + NBT;  double* tauar = ear + NBT;
  float* fs     = (float*)(tauar + NBT);
  float* val32  = fs;             float* mx = val32 + NBT;  float* orgn = mx + NBT;
  // Arrays read DURING padded writes live in d_ws (survive k_zero/k_fc).
  int* iz    = (int*)d_ws;
  int* slot  = iz + NBT;
  int* nkeep = slot + NBT;

  k_gm     <<<dim3(T_, B_), 256, 0, stream>>>(X, W1, b1, W2, b2, gm);
  k_maxabs <<<dim3(T_, B_),  64, 0, stream>>>(X, mx);

  k_tridiag<<<B_, TTH, 0, stream>>>(gm, A, Zv, dar, ear, tauar, orgn);
  k_leaf   <<<dim3(8, B_), 64, 0, stream>>>(Zv, dar, ear);

  const int n1s[3]    = {22, 44, 88};
  const int nmerges[3]= {4, 2, 1};
  const int chs[3]    = {4, 8, 16};
  for (int lv = 0; lv < 3; ++lv){
    int n1 = n1s[lv], nm = nmerges[lv], CH = chs[lv];
    k_mscan <<<dim3(nm, B_),      64, 0, stream>>>(Zv, dar, ear, MST, n1);
    k_mrot  <<<dim3(nm, B_),     256, 0, stream>>>(Zv, MST, n1);
    k_msec1 <<<dim3(nm*4, B_),  1024, 0, stream>>>(DELm, MST, n1, 4);
    k_msec2 <<<dim3(nm, B_),    1024, 0, stream>>>(Zv, QND, DELm, MST, n1);
    k_mgemm <<<dim3(nm*CH, B_), 1024, 0, stream>>>(Zv, QND, DELm, GOm, MST, n1, CH);
    k_mperm <<<dim3(nm, B_),     256, 0, stream>>>(Zv, GOm, dar, MST, n1);
  }

  k_backt  <<<dim3(B_, 11), 256, 0, stream>>>(A, Zv, dar, tauar, orgn, val32);

  // k_group consumes Zv/val32 BEFORE k_zero/k_fc overwrite the padded region.
  k_group  <<<dim3(T_, B_), 256, 0, stream>>>(Zv, val32, gum, grp);
  k_iszero <<<dim3(T_, B_),  64, 0, stream>>>(grp, mx, iz);
  k_slots  <<<B_,            64, 0, stream>>>(iz, slot, nkeep);
  k_zero   <<<dim3(T_, B_), 256, 0, stream>>>(nkeep, padded);
  k_fc     <<<dim3(T_, B_), 256, 0, stream>>>(grp, X, iz, slot, padded);
}